// Round 2
// baseline (4330.624 us; speedup 1.0000x reference)
//
#include <hip/hip_runtime.h>
#include <hip/hip_bf16.h>
#include <math.h>

#define NTN 60000
#define NCN 30000
#define NED 200000
// H=8, D=32, HID=256, FIN=64

typedef unsigned short u16;

static __device__ __forceinline__ float bf2f(u16 u) {
    return __uint_as_float(((unsigned)u) << 16);
}
static __device__ __forceinline__ u16 f2bf(float f) {
    unsigned u = __float_as_uint(f);
    unsigned r = (u + 0x7fffu + ((u >> 16) & 1u)) >> 16;  // RNE
    return (u16)r;
}

// ------------------------- fill -------------------------
__global__ void fill_u32(unsigned* __restrict__ p, unsigned v, int n) {
    int i = blockIdx.x * blockDim.x + threadIdx.x;
    int stride = gridDim.x * blockDim.x;
    for (; i < n; i += stride) p[i] = v;
}

// --------------------- weight fusion ---------------------
// Wkf[c, h*32+e] = p[h]/sqrt(32) * sum_d Wk[c,h*32+d]*ar[h,d,e];  Wvf with mr, no scale.
__global__ __launch_bounds__(256) void fuse_weights(
    const float* __restrict__ Wk, const float* __restrict__ bk,
    const float* __restrict__ Wv, const float* __restrict__ bv,
    const float* __restrict__ ar, const float* __restrict__ mr,
    const float* __restrict__ pr,
    float* __restrict__ Wkf, float* __restrict__ bkf,
    float* __restrict__ Wvf, float* __restrict__ bvf)
{
    __shared__ float kw[256], vw[256];
    const int c = blockIdx.x, tid = threadIdx.x;
    kw[tid] = Wk[c * 256 + tid];
    vw[tid] = Wv[c * 256 + tid];
    __syncthreads();
    const int h = tid >> 5, e = tid & 31;
    const float s = pr[h] * 0.17677669529663687f;  // 1/sqrt(32)
    float ak = 0.f, av = 0.f;
#pragma unroll 8
    for (int d = 0; d < 32; ++d) {
        ak += kw[h * 32 + d] * ar[h * 1024 + d * 32 + e];
        av += vw[h * 32 + d] * mr[h * 1024 + d * 32 + e];
    }
    Wkf[c * 256 + tid] = ak * s;
    Wvf[c * 256 + tid] = av;
    if (c == 0) {
        float bka = 0.f, bva = 0.f;
#pragma unroll 8
        for (int d = 0; d < 32; ++d) {
            bka += bk[h * 32 + d] * ar[h * 1024 + d * 32 + e];
            bva += bv[h * 32 + d] * mr[h * 1024 + d * 32 + e];
        }
        bkf[tid] = bka * s;
        bvf[tid] = bva;
    }
}

// ------------------------- GEMM -------------------------
// C[M,N] = epi(A[M,K] @ W[K,N] + bias)
// EPI: 0=none, 1=relu, 2=skip-blend (beta*o + (1-beta)*xres), 3=leakyrelu(0.2)
// ABF: A is bf16; OBF: C (and xres) are bf16.
template <int EPI, bool ABF, bool OBF>
__global__ __launch_bounds__(256) void gemm_t(
    const void* __restrict__ Av, const float* __restrict__ W,
    const float* __restrict__ bias, void* __restrict__ Cv,
    int M, int N, int K,
    const void* __restrict__ xresv, const float* __restrict__ skipPtr)
{
    __shared__ float As[16][68];   // [k][m]
    __shared__ float Bs[16][64];   // [k][n]
    const int tid = threadIdx.x;
    const int tx = tid & 15, ty = tid >> 4;
    const int m0 = blockIdx.x * 64, n0 = blockIdx.y * 64;
    const int arow = tid >> 2, akq = (tid & 3) * 4;
    const int brow = tid >> 4, bcol = (tid & 15) * 4;
    float acc[4][4] = {};

    for (int k0 = 0; k0 < K; k0 += 16) {
        __syncthreads();
        float a0 = 0.f, a1 = 0.f, a2 = 0.f, a3 = 0.f;
        if (m0 + arow < M) {
            if (ABF) {
                const ushort4 v = *(const ushort4*)((const u16*)Av + (size_t)(m0 + arow) * K + k0 + akq);
                a0 = bf2f(v.x); a1 = bf2f(v.y); a2 = bf2f(v.z); a3 = bf2f(v.w);
            } else {
                const float4 v = *(const float4*)((const float*)Av + (size_t)(m0 + arow) * K + k0 + akq);
                a0 = v.x; a1 = v.y; a2 = v.z; a3 = v.w;
            }
        }
        As[akq + 0][arow] = a0;
        As[akq + 1][arow] = a1;
        As[akq + 2][arow] = a2;
        As[akq + 3][arow] = a3;
        *(float4*)&Bs[brow][bcol] = *(const float4*)&W[(size_t)(k0 + brow) * N + n0 + bcol];
        __syncthreads();
#pragma unroll
        for (int kk = 0; kk < 16; ++kk) {
            float4 a4 = *(const float4*)&As[kk][ty * 4];
            float4 b4 = *(const float4*)&Bs[kk][tx * 4];
            float a[4] = {a4.x, a4.y, a4.z, a4.w};
            float b[4] = {b4.x, b4.y, b4.z, b4.w};
#pragma unroll
            for (int i = 0; i < 4; ++i)
#pragma unroll
                for (int j = 0; j < 4; ++j) acc[i][j] += a[i] * b[j];
        }
    }

    float beta = 0.f;
    if (EPI == 2) beta = 1.f / (1.f + expf(-skipPtr[0]));
#pragma unroll
    for (int i = 0; i < 4; ++i) {
        int m = m0 + ty * 4 + i;
        if (m >= M) continue;
        float vals[4];
        ushort4 xr4;
        if (EPI == 2) xr4 = *(const ushort4*)((const u16*)xresv + (size_t)m * N + n0 + tx * 4);
        const u16* xrp = (const u16*)&xr4;
#pragma unroll
        for (int j = 0; j < 4; ++j) {
            int n = n0 + tx * 4 + j;
            float c = acc[i][j] + bias[n];
            if (EPI == 1) c = fmaxf(c, 0.f);
            if (EPI == 2) c = beta * c + (1.f - beta) * bf2f(xrp[j]);
            if (EPI == 3) c = (c > 0.f) ? c : 0.2f * c;
            vals[j] = c;
        }
        if (OBF) {
            ushort4 o;
            o.x = f2bf(vals[0]); o.y = f2bf(vals[1]); o.z = f2bf(vals[2]); o.w = f2bf(vals[3]);
            *(ushort4*)((u16*)Cv + (size_t)m * N + n0 + tx * 4) = o;
        } else {
            float4 o;
            o.x = vals[0]; o.y = vals[1]; o.z = vals[2]; o.w = vals[3];
            *(float4*)((float*)Cv + (size_t)m * N + n0 + tx * 4) = o;
        }
    }
}

// ------------------------- edge kernels -------------------------
// wave per edge: lane -> (h = lane>>3, d0 = (lane&7)*4). q/kr already include p_rel/sqrt(D).
__global__ __launch_bounds__(256) void edge_alpha(
    const u16* __restrict__ q, const u16* __restrict__ kr,
    const int* __restrict__ si, const int* __restrict__ di,
    float* __restrict__ alpha, unsigned* __restrict__ mbuf, int E)
{
    int e = blockIdx.x * 4 + (threadIdx.x >> 6);
    if (e >= E) return;
    int lane = threadIdx.x & 63;
    int h = lane >> 3, d0 = (lane & 7) * 4;
    int s = si[e], dn = di[e];
    const ushort4 qv = *(const ushort4*)&q[(size_t)dn * 256 + h * 32 + d0];
    const ushort4 kv = *(const ushort4*)&kr[(size_t)s * 256 + h * 32 + d0];
    float p = bf2f(qv.x) * bf2f(kv.x) + bf2f(qv.y) * bf2f(kv.y)
            + bf2f(qv.z) * bf2f(kv.z) + bf2f(qv.w) * bf2f(kv.w);
    p += __shfl_xor(p, 1);
    p += __shfl_xor(p, 2);
    p += __shfl_xor(p, 4);
    if ((lane & 7) == 0) {
        alpha[(size_t)e * 8 + h] = p;
        unsigned u = __float_as_uint(p);
        u = (u & 0x80000000u) ? ~u : (u | 0x80000000u); // monotonic encoding
        atomicMax(&mbuf[dn * 8 + h], u);
    }
}

__global__ void edge_exp(
    const int* __restrict__ di, float* __restrict__ alpha,
    const unsigned* __restrict__ mbuf, float* __restrict__ ssum, int EH)
{
    int idx = blockIdx.x * blockDim.x + threadIdx.x;
    if (idx >= EH) return;
    int e = idx >> 3, h = idx & 7;
    int dn = di[e];
    unsigned u = mbuf[dn * 8 + h];
    float m = (u & 0x80000000u) ? __uint_as_float(u & 0x7fffffffu) : __uint_as_float(~u);
    float ex = expf(alpha[idx] - m);
    alpha[idx] = ex;
    unsafeAtomicAdd(&ssum[dn * 8 + h], ex);
}

__global__ __launch_bounds__(256) void edge_scatter(
    const u16* __restrict__ vr, const int* __restrict__ si, const int* __restrict__ di,
    const float* __restrict__ ex, const float* __restrict__ ssum,
    float* __restrict__ agg, int E)
{
    int e = blockIdx.x * 4 + (threadIdx.x >> 6);
    if (e >= E) return;
    int lane = threadIdx.x & 63;
    int h = lane >> 3, d0 = (lane & 7) * 4;
    int s = si[e], dn = di[e];
    float w = ex[(size_t)e * 8 + h] / (ssum[dn * 8 + h] + 1e-16f);
    const ushort4 vv = *(const ushort4*)&vr[(size_t)s * 256 + h * 32 + d0];
    float* base = &agg[((size_t)dn * 8 + h) * 32 + d0];
    unsafeAtomicAdd(base + 0, w * bf2f(vv.x));
    unsafeAtomicAdd(base + 1, w * bf2f(vv.y));
    unsafeAtomicAdd(base + 2, w * bf2f(vv.z));
    unsafeAtomicAdd(base + 3, w * bf2f(vv.w));
}

// ------------------------- misc elementwise -------------------------
__global__ void gelu_inplace(float* __restrict__ p, int n4) {
    int i = blockIdx.x * blockDim.x + threadIdx.x;
    int stride = gridDim.x * blockDim.x;
    for (; i < n4; i += stride) {
        float4 v = ((float4*)p)[i];
        v.x = 0.5f * v.x * (1.f + erff(v.x * 0.70710678118654752f));
        v.y = 0.5f * v.y * (1.f + erff(v.y * 0.70710678118654752f));
        v.z = 0.5f * v.z * (1.f + erff(v.z * 0.70710678118654752f));
        v.w = 0.5f * v.w * (1.f + erff(v.w * 0.70710678118654752f));
        ((float4*)p)[i] = v;
    }
}

__global__ __launch_bounds__(256) void norm_rows(float* __restrict__ y, int M) {
    int row = blockIdx.x * 4 + (threadIdx.x >> 6);
    int lane = threadIdx.x & 63;
    if (row >= M) return;
    float v = y[(size_t)row * 64 + lane];
    float s = v * v;
#pragma unroll
    for (int off = 1; off < 64; off <<= 1) s += __shfl_xor(s, off);
    float n = sqrtf(s);
    y[(size_t)row * 64 + lane] = v / fmaxf(n, 1e-12f);
}

// ------------------------- launch -------------------------
extern "C" void kernel_launch(void* const* d_in, const int* in_sizes, int n_in,
                              void* d_out, int out_size, void* d_ws, size_t ws_size,
                              hipStream_t stream)
{
    const float* x_trans = (const float*)d_in[0];
    const float* x_cc    = (const float*)d_in[1];
    const int* src_c2t   = (const int*)d_in[2];
    const int* dst_c2t   = (const int*)d_in[3];
    const int* src_t2c   = (const int*)d_in[4];
    const int* dst_t2c   = (const int*)d_in[5];
    const float* W_in = (const float*)d_in[6];
    const float* b_in = (const float*)d_in[7];
    const float* Wk   = (const float*)d_in[8];
    const float* bk   = (const float*)d_in[9];
    const float* Wq   = (const float*)d_in[10];
    const float* bq   = (const float*)d_in[11];
    const float* Wv   = (const float*)d_in[12];
    const float* bv   = (const float*)d_in[13];
    const float* Wa   = (const float*)d_in[14];
    const float* ba   = (const float*)d_in[15];
    const float* a_rel = (const float*)d_in[16];
    const float* m_rel = (const float*)d_in[17];
    const float* p_rel = (const float*)d_in[18];
    const float* skip  = (const float*)d_in[19];
    const float* W_out = (const float*)d_in[20];
    const float* b_out = (const float*)d_in[21];

    // ---------- workspace layout (~199 MB total) ----------
    char* w = (char*)d_ws;
    auto alloc = [&](size_t bytes) { char* p = w; w += (bytes + 255) & ~(size_t)255; return p; };
    u16* xs0   = (u16*)alloc((size_t)NTN * 256 * 2);       // 30.72 MB
    u16* xs1   = (u16*)alloc((size_t)NCN * 256 * 2);       // 15.36 MB
    u16* arena = (u16*)alloc((size_t)(NTN + 2 * NTN) * 256 * 2 / 2 * 1 + (size_t)38400000 * 2 - (size_t)38400000 * 2 + (size_t)76800000); // 76.8 MB
    float* agg   = (float*)alloc((size_t)NTN * 256 * 4);   // 61.44 MB
    float* alphab = (float*)alloc((size_t)NED * 8 * 4);    // 6.4 MB
    unsigned* mbuf = (unsigned*)alloc((size_t)NTN * 8 * 4);
    float* ssum  = (float*)alloc((size_t)NTN * 8 * 4);
    float* Wf    = (float*)alloc((size_t)4 * 2 * 65536 * 4); // fused Wk',Wv' per (l,t)
    float* bf    = (float*)alloc((size_t)4 * 2 * 256 * 4);
    (void)ws_size; (void)in_sizes; (void)n_in; (void)out_size;

    auto fill = [&](void* p, unsigned v, int n) {
        fill_u32<<<1024, 256, 0, stream>>>((unsigned*)p, v, n);
    };

    // ---------- fused weights (relation transform folded into Wk/Wv) ----------
    // source type t participates in relation r = (t==1) ? 0 : 1
    for (int l = 0; l < 2; ++l)
        for (int t = 0; t < 2; ++t) {
            int r = (t == 1) ? 0 : 1;
            int lt = l * 2 + t, lr = l * 2 + r;
            fuse_weights<<<256, 256, 0, stream>>>(
                Wk + (size_t)lt * 65536, bk + (size_t)lt * 256,
                Wv + (size_t)lt * 65536, bv + (size_t)lt * 256,
                a_rel + (size_t)lr * 8192, m_rel + (size_t)lr * 8192, p_rel + (size_t)lr * 8,
                Wf + (size_t)(lt * 2 + 0) * 65536, bf + (size_t)(lt * 2 + 0) * 256,
                Wf + (size_t)(lt * 2 + 1) * 65536, bf + (size_t)(lt * 2 + 1) * 256);
        }

    // ---------- input projections + relu ----------
    {
        dim3 g0((NTN + 63) / 64, 4);
        gemm_t<1, false, true><<<g0, 256, 0, stream>>>(x_trans, W_in, b_in, xs0, NTN, 256, 64, nullptr, nullptr);
        dim3 g1((NCN + 63) / 64, 4);
        gemm_t<1, false, true><<<g1, 256, 0, stream>>>(x_cc, W_in + 64 * 256, b_in + 256, xs1, NCN, 256, 64, nullptr, nullptr);
    }

    for (int l = 0; l < 2; ++l) {
        // arena slots (elements):
        // r0 phase: q0@0 (NTN*256), kr1@15360000, vr1@23040000   (type-1 sources, 30000)
        // r1 phase: kr0@0, vr0@15360000, q1@30720000             (type-0 sources, 60000)
        u16* q0  = arena;
        u16* kr1 = arena + 15360000;
        u16* vr1 = arena + 23040000;
        u16* kr0 = arena;
        u16* vr0 = arena + 15360000;
        u16* q1  = arena + 30720000;

        dim3 gT((NTN + 63) / 64, 4), gC((NCN + 63) / 64, 4);
        size_t lt0 = (size_t)(l * 2 + 0), lt1 = (size_t)(l * 2 + 1);

        // step 1: relation-0 operands (q of type0, fused k/v of type1)
        gemm_t<0, true, true><<<gT, 256, 0, stream>>>(xs0, Wq + lt0 * 65536, bq + lt0 * 256, q0, NTN, 256, 256, nullptr, nullptr);
        gemm_t<0, true, true><<<gC, 256, 0, stream>>>(xs1, Wf + (lt1 * 2 + 0) * 65536, bf + (lt1 * 2 + 0) * 256, kr1, NCN, 256, 256, nullptr, nullptr);
        gemm_t<0, true, true><<<gC, 256, 0, stream>>>(xs1, Wf + (lt1 * 2 + 1) * 65536, bf + (lt1 * 2 + 1) * 256, vr1, NCN, 256, 256, nullptr, nullptr);

        // step 2: edge phase relation 0 (cc -> trans), dst = type0 (NTN)
        fill(mbuf, 0, NTN * 8);
        fill(ssum, 0, NTN * 8);
        fill(agg, 0, NTN * 256);
        edge_alpha<<<NED / 4, 256, 0, stream>>>(q0, kr1, src_c2t, dst_c2t, alphab, mbuf, NED);
        edge_exp<<<(NED * 8 + 255) / 256, 256, 0, stream>>>(dst_c2t, alphab, mbuf, ssum, NED * 8);
        edge_scatter<<<NED / 4, 256, 0, stream>>>(vr1, src_c2t, dst_c2t, alphab, ssum, agg, NED);

        // step 3: relation-1 operands (from OLD xs0/xs1, before xs0 update)
        gemm_t<0, true, true><<<gT, 256, 0, stream>>>(xs0, Wf + (lt0 * 2 + 0) * 65536, bf + (lt0 * 2 + 0) * 256, kr0, NTN, 256, 256, nullptr, nullptr);
        gemm_t<0, true, true><<<gT, 256, 0, stream>>>(xs0, Wf + (lt0 * 2 + 1) * 65536, bf + (lt0 * 2 + 1) * 256, vr0, NTN, 256, 256, nullptr, nullptr);
        gemm_t<0, true, true><<<gC, 256, 0, stream>>>(xs1, Wq + lt1 * 65536, bq + lt1 * 256, q1, NCN, 256, 256, nullptr, nullptr);

        // step 4: update xs0 = blend(gelu(agg) @ Wa + ba, xs0)
        gelu_inplace<<<1024, 256, 0, stream>>>(agg, NTN * 256 / 4);
        gemm_t<2, false, true><<<gT, 256, 0, stream>>>(agg, Wa + lt0 * 65536, ba + lt0 * 256, xs0, NTN, 256, 256, xs0, skip + l * 2 + 0);

        // step 5: edge phase relation 1 (trans -> cc), dst = type1 (NCN)
        fill(mbuf, 0, NCN * 8);
        fill(ssum, 0, NCN * 8);
        fill(agg, 0, NCN * 256);
        edge_alpha<<<NED / 4, 256, 0, stream>>>(q1, kr0, src_t2c, dst_t2c, alphab, mbuf, NED);
        edge_exp<<<(NED * 8 + 255) / 256, 256, 0, stream>>>(dst_t2c, alphab, mbuf, ssum, NED * 8);
        edge_scatter<<<NED / 4, 256, 0, stream>>>(vr0, src_t2c, dst_t2c, alphab, ssum, agg, NED);

        // step 6: update xs1
        gelu_inplace<<<1024, 256, 0, stream>>>(agg, NCN * 256 / 4);
        gemm_t<2, false, true><<<gC, 256, 0, stream>>>(agg, Wa + lt1 * 65536, ba + lt1 * 256, xs1, NCN, 256, 256, xs1, skip + l * 2 + 1);
    }

    // ---------- final projection + leakyrelu + row L2 normalize ----------
    {
        float* y = (float*)d_out;
        dim3 g((NTN + 63) / 64, 1);
        gemm_t<3, true, false><<<g, 256, 0, stream>>>(xs0, W_out, b_out, y, NTN, 64, 256, nullptr, nullptr);
        norm_rows<<<NTN / 4, 256, 0, stream>>>(y, NTN);
    }
}

// Round 3
// 1614.790 us; speedup vs baseline: 2.6819x; 2.6819x over previous
//
#include <hip/hip_runtime.h>
#include <hip/hip_bf16.h>
#include <math.h>

#define NTN 60000
#define NCN 30000
#define NED 200000
// H=8, D=32, HID=256, FIN=64

typedef unsigned short u16;

static __device__ __forceinline__ float bf2f(u16 u) {
    return __uint_as_float(((unsigned)u) << 16);
}
static __device__ __forceinline__ u16 f2bf(float f) {
    unsigned u = __float_as_uint(f);
    unsigned r = (u + 0x7fffu + ((u >> 16) & 1u)) >> 16;  // RNE
    return (u16)r;
}

// ------------------------- fill -------------------------
__global__ void fill_u32(unsigned* __restrict__ p, unsigned v, int n) {
    int i = blockIdx.x * blockDim.x + threadIdx.x;
    int stride = gridDim.x * blockDim.x;
    for (; i < n; i += stride) p[i] = v;
}

// --------------------- weight fusion ---------------------
// Wkf[c, h*32+e] = p[h]/sqrt(32) * sum_d Wk[c,h*32+d]*ar[h,d,e];  Wvf with mr, no scale.
__global__ __launch_bounds__(256) void fuse_weights(
    const float* __restrict__ Wk, const float* __restrict__ bk,
    const float* __restrict__ Wv, const float* __restrict__ bv,
    const float* __restrict__ ar, const float* __restrict__ mr,
    const float* __restrict__ pr,
    float* __restrict__ Wkf, float* __restrict__ bkf,
    float* __restrict__ Wvf, float* __restrict__ bvf)
{
    __shared__ float kw[256], vw[256];
    const int c = blockIdx.x, tid = threadIdx.x;
    kw[tid] = Wk[c * 256 + tid];
    vw[tid] = Wv[c * 256 + tid];
    __syncthreads();
    const int h = tid >> 5, e = tid & 31;
    const float s = pr[h] * 0.17677669529663687f;  // 1/sqrt(32)
    float ak = 0.f, av = 0.f;
#pragma unroll 8
    for (int d = 0; d < 32; ++d) {
        ak += kw[h * 32 + d] * ar[h * 1024 + d * 32 + e];
        av += vw[h * 32 + d] * mr[h * 1024 + d * 32 + e];
    }
    Wkf[c * 256 + tid] = ak * s;
    Wvf[c * 256 + tid] = av;
    if (c == 0) {
        float bka = 0.f, bva = 0.f;
#pragma unroll 8
        for (int d = 0; d < 32; ++d) {
            bka += bk[h * 32 + d] * ar[h * 1024 + d * 32 + e];
            bva += bv[h * 32 + d] * mr[h * 1024 + d * 32 + e];
        }
        bkf[tid] = bka * s;
        bvf[tid] = bva;
    }
}

// ------------------------- GEMM -------------------------
// C[M,N] = epi(A[M,K] @ W[K,N] + bias)
// EPI: 0=none, 1=relu, 2=skip-blend (beta*o + (1-beta)*xres), 3=leakyrelu(0.2)
// ABF: A is bf16; OBF: C (and xres) are bf16.
template <int EPI, bool ABF, bool OBF>
__global__ __launch_bounds__(256) void gemm_t(
    const void* __restrict__ Av, const float* __restrict__ W,
    const float* __restrict__ bias, void* __restrict__ Cv,
    int M, int N, int K,
    const void* __restrict__ xresv, const float* __restrict__ skipPtr)
{
    __shared__ float As[16][68];   // [k][m]
    __shared__ float Bs[16][64];   // [k][n]
    const int tid = threadIdx.x;
    const int tx = tid & 15, ty = tid >> 4;
    const int m0 = blockIdx.x * 64, n0 = blockIdx.y * 64;
    const int arow = tid >> 2, akq = (tid & 3) * 4;
    const int brow = tid >> 4, bcol = (tid & 15) * 4;
    float acc[4][4] = {};

    for (int k0 = 0; k0 < K; k0 += 16) {
        __syncthreads();
        float a0 = 0.f, a1 = 0.f, a2 = 0.f, a3 = 0.f;
        if (m0 + arow < M) {
            if (ABF) {
                const ushort4 v = *(const ushort4*)((const u16*)Av + (size_t)(m0 + arow) * K + k0 + akq);
                a0 = bf2f(v.x); a1 = bf2f(v.y); a2 = bf2f(v.z); a3 = bf2f(v.w);
            } else {
                const float4 v = *(const float4*)((const float*)Av + (size_t)(m0 + arow) * K + k0 + akq);
                a0 = v.x; a1 = v.y; a2 = v.z; a3 = v.w;
            }
        }
        As[akq + 0][arow] = a0;
        As[akq + 1][arow] = a1;
        As[akq + 2][arow] = a2;
        As[akq + 3][arow] = a3;
        *(float4*)&Bs[brow][bcol] = *(const float4*)&W[(size_t)(k0 + brow) * N + n0 + bcol];
        __syncthreads();
#pragma unroll
        for (int kk = 0; kk < 16; ++kk) {
            float4 a4 = *(const float4*)&As[kk][ty * 4];
            float4 b4 = *(const float4*)&Bs[kk][tx * 4];
            float a[4] = {a4.x, a4.y, a4.z, a4.w};
            float b[4] = {b4.x, b4.y, b4.z, b4.w};
#pragma unroll
            for (int i = 0; i < 4; ++i)
#pragma unroll
                for (int j = 0; j < 4; ++j) acc[i][j] += a[i] * b[j];
        }
    }

    float beta = 0.f;
    if (EPI == 2) beta = 1.f / (1.f + expf(-skipPtr[0]));
#pragma unroll
    for (int i = 0; i < 4; ++i) {
        int m = m0 + ty * 4 + i;
        if (m >= M) continue;
        float vals[4];
        ushort4 xr4;
        if (EPI == 2) xr4 = *(const ushort4*)((const u16*)xresv + (size_t)m * N + n0 + tx * 4);
        const u16* xrp = (const u16*)&xr4;
#pragma unroll
        for (int j = 0; j < 4; ++j) {
            int n = n0 + tx * 4 + j;
            float c = acc[i][j] + bias[n];
            if (EPI == 1) c = fmaxf(c, 0.f);
            if (EPI == 2) c = beta * c + (1.f - beta) * bf2f(xrp[j]);
            if (EPI == 3) c = (c > 0.f) ? c : 0.2f * c;
            vals[j] = c;
        }
        if (OBF) {
            ushort4 o;
            o.x = f2bf(vals[0]); o.y = f2bf(vals[1]); o.z = f2bf(vals[2]); o.w = f2bf(vals[3]);
            *(ushort4*)((u16*)Cv + (size_t)m * N + n0 + tx * 4) = o;
        } else {
            float4 o;
            o.x = vals[0]; o.y = vals[1]; o.z = vals[2]; o.w = vals[3];
            *(float4*)((float*)Cv + (size_t)m * N + n0 + tx * 4) = o;
        }
    }
}

// ------------------------- CSR build -------------------------
__global__ void hist_kernel(const int* __restrict__ di, unsigned* __restrict__ counts, int E) {
    int e = blockIdx.x * blockDim.x + threadIdx.x;
    if (e < E) atomicAdd(&counts[di[e]], 1u);
}

__global__ __launch_bounds__(256) void scan_blocks(
    const unsigned* __restrict__ counts, unsigned* __restrict__ pref,
    unsigned* __restrict__ bsum, int N)
{
    __shared__ unsigned tmp[256];
    int i = blockIdx.x * 256 + threadIdx.x;
    unsigned v = (i < N) ? counts[i] : 0u;
    tmp[threadIdx.x] = v;
    __syncthreads();
    for (int off = 1; off < 256; off <<= 1) {
        unsigned t = (threadIdx.x >= off) ? tmp[threadIdx.x - off] : 0u;
        __syncthreads();
        tmp[threadIdx.x] += t;
        __syncthreads();
    }
    if (i < N) pref[i] = tmp[threadIdx.x] - v;  // exclusive
    if (threadIdx.x == 255) bsum[blockIdx.x] = tmp[255];
}

__global__ __launch_bounds__(256) void scan_top(unsigned* __restrict__ bsum, int NB) {
    __shared__ unsigned tmp[256];
    unsigned v = (threadIdx.x < NB) ? bsum[threadIdx.x] : 0u;
    tmp[threadIdx.x] = v;
    __syncthreads();
    for (int off = 1; off < 256; off <<= 1) {
        unsigned t = (threadIdx.x >= off) ? tmp[threadIdx.x - off] : 0u;
        __syncthreads();
        tmp[threadIdx.x] += t;
        __syncthreads();
    }
    if (threadIdx.x < NB) bsum[threadIdx.x] = tmp[threadIdx.x] - v;  // exclusive
}

__global__ void scan_add(unsigned* __restrict__ pref, const unsigned* __restrict__ bsum,
                         unsigned* __restrict__ cursor, int N) {
    int i = blockIdx.x * 256 + threadIdx.x;
    if (i < N) {
        unsigned s = pref[i] + bsum[blockIdx.x];
        pref[i] = s;
        cursor[i] = s;
    }
}

__global__ void place_kernel(const int* __restrict__ di, unsigned* __restrict__ cursor,
                             unsigned* __restrict__ eid, int E) {
    int e = blockIdx.x * blockDim.x + threadIdx.x;
    if (e < E) {
        unsigned p = atomicAdd(&cursor[di[e]], 1u);
        eid[p] = (unsigned)e;
    }
}

// ------------------------- fused edge gather -------------------------
// One wave per dst node. lane -> (h = lane>>3, d-quad = lane&7); row offset = lane*4.
// Online softmax over incoming edges; epilogue = gelu; writes bf16 agg row.
__global__ __launch_bounds__(256) void edge_gather(
    const u16* __restrict__ q, const u16* __restrict__ kr, const u16* __restrict__ vr,
    const int* __restrict__ si, const unsigned* __restrict__ rowstart,
    const unsigned* __restrict__ counts, const unsigned* __restrict__ eid,
    u16* __restrict__ agg, int Ndst)
{
    int n = blockIdx.x * 4 + (threadIdx.x >> 6);
    if (n >= Ndst) return;
    int lane = threadIdx.x & 63;
    unsigned start = rowstart[n], deg = counts[n];

    const ushort4 qv = *(const ushort4*)&q[(size_t)n * 256 + lane * 4];
    float q0 = bf2f(qv.x), q1 = bf2f(qv.y), q2 = bf2f(qv.z), q3 = bf2f(qv.w);

    float m = -INFINITY, s = 0.f;
    float a0 = 0.f, a1 = 0.f, a2 = 0.f, a3 = 0.f;
    for (unsigned j = 0; j < deg; ++j) {
        int e = (int)eid[start + j];
        int src = si[e];
        const ushort4 kv = *(const ushort4*)&kr[(size_t)src * 256 + lane * 4];
        float p = q0 * bf2f(kv.x) + q1 * bf2f(kv.y) + q2 * bf2f(kv.z) + q3 * bf2f(kv.w);
        p += __shfl_xor(p, 1);
        p += __shfl_xor(p, 2);
        p += __shfl_xor(p, 4);
        const ushort4 vv = *(const ushort4*)&vr[(size_t)src * 256 + lane * 4];
        float mn = fmaxf(m, p);
        float scale = __expf(m - mn);   // 0 on first iteration (m = -inf)
        float w = __expf(p - mn);
        s = s * scale + w;
        a0 = a0 * scale + w * bf2f(vv.x);
        a1 = a1 * scale + w * bf2f(vv.y);
        a2 = a2 * scale + w * bf2f(vv.z);
        a3 = a3 * scale + w * bf2f(vv.w);
        m = mn;
    }
    float inv = 1.f / (s + 1e-16f);
    float o[4] = {a0 * inv, a1 * inv, a2 * inv, a3 * inv};
    ushort4 ov;
    u16* op = (u16*)&ov;
#pragma unroll
    for (int j = 0; j < 4; ++j) {
        float x = o[j];
        float g = 0.5f * x * (1.f + erff(x * 0.70710678118654752f));
        op[j] = f2bf(g);
    }
    *(ushort4*)&agg[(size_t)n * 256 + lane * 4] = ov;
}

// ------------------------- misc -------------------------
__global__ __launch_bounds__(256) void norm_rows(float* __restrict__ y, int M) {
    int row = blockIdx.x * 4 + (threadIdx.x >> 6);
    int lane = threadIdx.x & 63;
    if (row >= M) return;
    float v = y[(size_t)row * 64 + lane];
    float s = v * v;
#pragma unroll
    for (int off = 1; off < 64; off <<= 1) s += __shfl_xor(s, off);
    float n = sqrtf(s);
    y[(size_t)row * 64 + lane] = v / fmaxf(n, 1e-12f);
}

// ------------------------- launch -------------------------
extern "C" void kernel_launch(void* const* d_in, const int* in_sizes, int n_in,
                              void* d_out, int out_size, void* d_ws, size_t ws_size,
                              hipStream_t stream)
{
    const float* x_trans = (const float*)d_in[0];
    const float* x_cc    = (const float*)d_in[1];
    const int* src_c2t   = (const int*)d_in[2];
    const int* dst_c2t   = (const int*)d_in[3];
    const int* src_t2c   = (const int*)d_in[4];
    const int* dst_t2c   = (const int*)d_in[5];
    const float* W_in = (const float*)d_in[6];
    const float* b_in = (const float*)d_in[7];
    const float* Wk   = (const float*)d_in[8];
    const float* bk   = (const float*)d_in[9];
    const float* Wq   = (const float*)d_in[10];
    const float* bq   = (const float*)d_in[11];
    const float* Wv   = (const float*)d_in[12];
    const float* bv   = (const float*)d_in[13];
    const float* Wa   = (const float*)d_in[14];
    const float* ba   = (const float*)d_in[15];
    const float* a_rel = (const float*)d_in[16];
    const float* m_rel = (const float*)d_in[17];
    const float* p_rel = (const float*)d_in[18];
    const float* skip  = (const float*)d_in[19];
    const float* W_out = (const float*)d_in[20];
    const float* b_out = (const float*)d_in[21];

    // ---------- workspace layout ----------
    char* w = (char*)d_ws;
    auto alloc = [&](size_t bytes) { char* p = w; w += (bytes + 255) & ~(size_t)255; return p; };
    u16* xs0   = (u16*)alloc((size_t)NTN * 256 * 2);       // 30.72 MB
    u16* xs1   = (u16*)alloc((size_t)NCN * 256 * 2);       // 15.36 MB
    u16* arena = (u16*)alloc((size_t)76800000);            // 76.8 MB (38.4M u16 elements)
    u16* agg   = (u16*)alloc((size_t)NTN * 256 * 2);       // 30.72 MB (bf16, gelu'd)
    float* Wf  = (float*)alloc((size_t)4 * 2 * 65536 * 4); // 2 MB fused Wk',Wv' per (l,t)
    float* bfb = (float*)alloc((size_t)4 * 2 * 256 * 4);
    // CSR for relation 0 (dst = type0, NTN) and relation 1 (dst = type1, NCN)
    unsigned* countsT   = (unsigned*)alloc((size_t)NTN * 4);
    unsigned* rowstartT = (unsigned*)alloc((size_t)NTN * 4);
    unsigned* cursorT   = (unsigned*)alloc((size_t)NTN * 4);
    unsigned* eidT      = (unsigned*)alloc((size_t)NED * 4);
    unsigned* countsC   = (unsigned*)alloc((size_t)NCN * 4);
    unsigned* rowstartC = (unsigned*)alloc((size_t)NCN * 4);
    unsigned* cursorC   = (unsigned*)alloc((size_t)NCN * 4);
    unsigned* eidC      = (unsigned*)alloc((size_t)NED * 4);
    unsigned* bsum      = (unsigned*)alloc((size_t)256 * 4);
    (void)ws_size; (void)in_sizes; (void)n_in; (void)out_size;

    // ---------- CSR builds (edge lists shared by both layers) ----------
    {
        const int EB = (NED + 255) / 256;
        // relation 0: dst_c2t -> type0 (NTN)
        int NBt = (NTN + 255) / 256;
        fill_u32<<<256, 256, 0, stream>>>(countsT, 0u, NTN);
        hist_kernel<<<EB, 256, 0, stream>>>(dst_c2t, countsT, NED);
        scan_blocks<<<NBt, 256, 0, stream>>>(countsT, rowstartT, bsum, NTN);
        scan_top<<<1, 256, 0, stream>>>(bsum, NBt);
        scan_add<<<NBt, 256, 0, stream>>>(rowstartT, bsum, cursorT, NTN);
        place_kernel<<<EB, 256, 0, stream>>>(dst_c2t, cursorT, eidT, NED);
        // relation 1: dst_t2c -> type1 (NCN)
        int NBc = (NCN + 255) / 256;
        fill_u32<<<256, 256, 0, stream>>>(countsC, 0u, NCN);
        hist_kernel<<<EB, 256, 0, stream>>>(dst_t2c, countsC, NED);
        scan_blocks<<<NBc, 256, 0, stream>>>(countsC, rowstartC, bsum, NCN);
        scan_top<<<1, 256, 0, stream>>>(bsum, NBc);
        scan_add<<<NBc, 256, 0, stream>>>(rowstartC, bsum, cursorC, NCN);
        place_kernel<<<EB, 256, 0, stream>>>(dst_t2c, cursorC, eidC, NED);
    }

    // ---------- fused weights (relation transform folded into Wk/Wv) ----------
    // source type t participates in relation r = (t==1) ? 0 : 1
    for (int l = 0; l < 2; ++l)
        for (int t = 0; t < 2; ++t) {
            int r = (t == 1) ? 0 : 1;
            int lt = l * 2 + t, lr = l * 2 + r;
            fuse_weights<<<256, 256, 0, stream>>>(
                Wk + (size_t)lt * 65536, bk + (size_t)lt * 256,
                Wv + (size_t)lt * 65536, bv + (size_t)lt * 256,
                a_rel + (size_t)lr * 8192, m_rel + (size_t)lr * 8192, p_rel + (size_t)lr * 8,
                Wf + (size_t)(lt * 2 + 0) * 65536, bfb + (size_t)(lt * 2 + 0) * 256,
                Wf + (size_t)(lt * 2 + 1) * 65536, bfb + (size_t)(lt * 2 + 1) * 256);
        }

    // ---------- input projections + relu ----------
    {
        dim3 g0((NTN + 63) / 64, 4);
        gemm_t<1, false, true><<<g0, 256, 0, stream>>>(x_trans, W_in, b_in, xs0, NTN, 256, 64, nullptr, nullptr);
        dim3 g1((NCN + 63) / 64, 4);
        gemm_t<1, false, true><<<g1, 256, 0, stream>>>(x_cc, W_in + 64 * 256, b_in + 256, xs1, NCN, 256, 64, nullptr, nullptr);
    }

    for (int l = 0; l < 2; ++l) {
        // arena slots (u16 elements):
        // r0 phase: q0@0 (NTN*256), kr1@15360000, vr1@23040000   (type-1 sources)
        // r1 phase: kr0@0, vr0@15360000, q1@30720000             (type-0 sources)
        u16* q0  = arena;
        u16* kr1 = arena + 15360000;
        u16* vr1 = arena + 23040000;
        u16* kr0 = arena;
        u16* vr0 = arena + 15360000;
        u16* q1  = arena + 30720000;

        dim3 gT((NTN + 63) / 64, 4), gC((NCN + 63) / 64, 4);
        size_t lt0 = (size_t)(l * 2 + 0), lt1 = (size_t)(l * 2 + 1);

        // step 1: relation-0 operands (q of type0, fused k/v of type1)
        gemm_t<0, true, true><<<gT, 256, 0, stream>>>(xs0, Wq + lt0 * 65536, bq + lt0 * 256, q0, NTN, 256, 256, nullptr, nullptr);
        gemm_t<0, true, true><<<gC, 256, 0, stream>>>(xs1, Wf + (lt1 * 2 + 0) * 65536, bfb + (lt1 * 2 + 0) * 256, kr1, NCN, 256, 256, nullptr, nullptr);
        gemm_t<0, true, true><<<gC, 256, 0, stream>>>(xs1, Wf + (lt1 * 2 + 1) * 65536, bfb + (lt1 * 2 + 1) * 256, vr1, NCN, 256, 256, nullptr, nullptr);

        // step 2: fused edge phase relation 0 (cc -> trans), dst = type0
        edge_gather<<<(NTN + 3) / 4, 256, 0, stream>>>(q0, kr1, vr1, src_c2t,
                                                       rowstartT, countsT, eidT, agg, NTN);

        // step 3: relation-1 operands (from OLD xs0/xs1, before xs0 update)
        gemm_t<0, true, true><<<gT, 256, 0, stream>>>(xs0, Wf + (lt0 * 2 + 0) * 65536, bfb + (lt0 * 2 + 0) * 256, kr0, NTN, 256, 256, nullptr, nullptr);
        gemm_t<0, true, true><<<gT, 256, 0, stream>>>(xs0, Wf + (lt0 * 2 + 1) * 65536, bfb + (lt0 * 2 + 1) * 256, vr0, NTN, 256, 256, nullptr, nullptr);
        gemm_t<0, true, true><<<gC, 256, 0, stream>>>(xs1, Wq + lt1 * 65536, bq + lt1 * 256, q1, NCN, 256, 256, nullptr, nullptr);

        // step 4: update xs0 = blend(agg @ Wa + ba, xs0)   (agg already gelu'd, bf16)
        gemm_t<2, true, true><<<gT, 256, 0, stream>>>(agg, Wa + lt0 * 65536, ba + lt0 * 256, xs0, NTN, 256, 256, xs0, skip + l * 2 + 0);

        // step 5: fused edge phase relation 1 (trans -> cc), dst = type1
        edge_gather<<<(NCN + 3) / 4, 256, 0, stream>>>(q1, kr0, vr0, src_t2c,
                                                       rowstartC, countsC, eidC, agg, NCN);

        // step 6: update xs1
        gemm_t<2, true, true><<<gC, 256, 0, stream>>>(agg, Wa + lt1 * 65536, ba + lt1 * 256, xs1, NCN, 256, 256, xs1, skip + l * 2 + 1);
    }

    // ---------- final projection + leakyrelu + row L2 normalize ----------
    {
        float* y = (float*)d_out;
        dim3 g((NTN + 63) / 64, 1);
        gemm_t<3, true, false><<<g, 256, 0, stream>>>(xs0, W_out, b_out, y, NTN, 64, 256, nullptr, nullptr);
        norm_rows<<<NTN / 4, 256, 0, stream>>>(y, NTN);
    }
}

// Round 4
// 807.341 us; speedup vs baseline: 5.3641x; 2.0001x over previous
//
#include <hip/hip_runtime.h>
#include <hip/hip_bf16.h>
#include <math.h>

#define NTN 60000
#define NCN 30000
#define NED 200000
// H=8, D=32, HID=256, FIN=64

typedef unsigned short u16;
typedef __attribute__((ext_vector_type(8))) u16 u16x8;
typedef __attribute__((ext_vector_type(8))) __bf16 bf16x8;
typedef __attribute__((ext_vector_type(4))) float f32x4;

static __device__ __forceinline__ float bf2f(u16 u) {
    return __uint_as_float(((unsigned)u) << 16);
}
static __device__ __forceinline__ u16 f2bf(float f) {
    unsigned u = __float_as_uint(f);
    unsigned r = (u + 0x7fffu + ((u >> 16) & 1u)) >> 16;  // RNE
    return (u16)r;
}

// ------------------------- fill -------------------------
__global__ void fill_u32(unsigned* __restrict__ p, unsigned v, int n) {
    int i = blockIdx.x * blockDim.x + threadIdx.x;
    int stride = gridDim.x * blockDim.x;
    for (; i < n; i += stride) p[i] = v;
}

// ------------------------- conversions -------------------------
__global__ void f32_to_bf16(const float* __restrict__ in, u16* __restrict__ out, int n4) {
    int i = blockIdx.x * blockDim.x + threadIdx.x;
    int stride = gridDim.x * blockDim.x;
    for (; i < n4; i += stride) {
        float4 v = ((const float4*)in)[i];
        ushort4 o;
        o.x = f2bf(v.x); o.y = f2bf(v.y); o.z = f2bf(v.z); o.w = f2bf(v.w);
        ((ushort4*)out)[i] = o;
    }
}

// out[n][k] = bf16(in[k][n]); coalesced reads across n.
__global__ void convT(const float* __restrict__ in, u16* __restrict__ out, int K, int N) {
    int idx = blockIdx.x * blockDim.x + threadIdx.x;
    int total = N * (K >> 2);
    if (idx >= total) return;
    int k4 = idx / N, n = idx - k4 * N;
    int k = k4 * 4;
    ushort4 o;
    o.x = f2bf(in[(size_t)(k + 0) * N + n]);
    o.y = f2bf(in[(size_t)(k + 1) * N + n]);
    o.z = f2bf(in[(size_t)(k + 2) * N + n]);
    o.w = f2bf(in[(size_t)(k + 3) * N + n]);
    *(ushort4*)(out + (size_t)n * K + k) = o;
}

// --------------------- weight fusion ---------------------
// Wkf[c, h*32+e] = p[h]/sqrt(32) * sum_d Wk[c,h*32+d]*ar[h,d,e];  Wvf with mr, no scale.
__global__ __launch_bounds__(256) void fuse_weights(
    const float* __restrict__ Wk, const float* __restrict__ bk,
    const float* __restrict__ Wv, const float* __restrict__ bv,
    const float* __restrict__ ar, const float* __restrict__ mr,
    const float* __restrict__ pr,
    float* __restrict__ Wkf, float* __restrict__ bkf,
    float* __restrict__ Wvf, float* __restrict__ bvf)
{
    __shared__ float kw[256], vw[256];
    const int c = blockIdx.x, tid = threadIdx.x;
    kw[tid] = Wk[c * 256 + tid];
    vw[tid] = Wv[c * 256 + tid];
    __syncthreads();
    const int h = tid >> 5, e = tid & 31;
    const float s = pr[h] * 0.17677669529663687f;  // 1/sqrt(32)
    float ak = 0.f, av = 0.f;
#pragma unroll 8
    for (int d = 0; d < 32; ++d) {
        ak += kw[h * 32 + d] * ar[h * 1024 + d * 32 + e];
        av += vw[h * 32 + d] * mr[h * 1024 + d * 32 + e];
    }
    Wkf[c * 256 + tid] = ak * s;
    Wvf[c * 256 + tid] = av;
    if (c == 0) {
        float bka = 0.f, bva = 0.f;
#pragma unroll 8
        for (int d = 0; d < 32; ++d) {
            bka += bk[h * 32 + d] * ar[h * 1024 + d * 32 + e];
            bva += bv[h * 32 + d] * mr[h * 1024 + d * 32 + e];
        }
        bkf[tid] = bka * s;
        bvf[tid] = bva;
    }
}

// ------------------------- MFMA GEMM -------------------------
// C[M, Ncols] = epi(A[M,K](bf16) @ WT[Ncols,K]^T(bf16) + bias), Ncols = gridDim.y*BN.
// 128 x BN tile, BK=64, 4 waves (2x2), mfma_f32_16x16x32_bf16.
// LDS: linear dest for global_load_lds; XOR slot swizzle applied on the
// pre-swizzled global source AND the ds_read side (rule #21 both-sides).
// EPI: 0=none, 1=relu, 2=skip-blend, 3=leakyrelu(0.2). OBF: bf16 output.
template <int EPI, int BN, bool OBF>
__global__ __launch_bounds__(256) void gemm_mfma(
    const u16* __restrict__ A, const u16* __restrict__ WT,
    const float* __restrict__ bias, void* __restrict__ Cv,
    int M, int K, int ldC,
    const u16* __restrict__ xres, const float* __restrict__ skipPtr)
{
    __shared__ u16 As[128 * 64];
    __shared__ u16 Bs[BN * 64];
    const int tid = threadIdx.x;
    const int wave = tid >> 6, lane = tid & 63;
    const int m0 = blockIdx.x * 128, n0 = blockIdx.y * BN;
    const int wm = (wave >> 1) * 64, wn = (wave & 1) * (BN / 2);
    constexpr int NF = BN / 32;  // n-frags per wave
    f32x4 acc[4][NF];
#pragma unroll
    for (int i = 0; i < 4; ++i)
#pragma unroll
        for (int j = 0; j < NF; ++j) acc[i][j] = (f32x4){0.f, 0.f, 0.f, 0.f};

    const int sr = lane >> 3;   // row within 8-row staging group
    const int sl = lane & 7;    // linear 16B slot

    for (int k0 = 0; k0 < K; k0 += 64) {
        if (k0) __syncthreads();
        // stage A rows [wave*32, wave*32+32)
#pragma unroll
        for (int i = 0; i < 4; ++i) {
            int rb = wave * 32 + i * 8;
            int r = rb + sr;
            int gr = m0 + r; gr = gr < M ? gr : M - 1;
            const u16* gp = A + (size_t)gr * K + k0 + ((sl ^ sr) << 3);
            __builtin_amdgcn_global_load_lds(
                (const __attribute__((address_space(1))) void*)gp,
                (__attribute__((address_space(3))) void*)(As + rb * 64), 16, 0, 0);
        }
        // stage B (WT) rows [wave*(BN/4), +BN/4)
#pragma unroll
        for (int i = 0; i < NF; ++i) {
            int rb = wave * (BN / 4) + i * 8;
            int r = rb + sr;
            const u16* gp = WT + (size_t)(n0 + r) * K + k0 + ((sl ^ sr) << 3);
            __builtin_amdgcn_global_load_lds(
                (const __attribute__((address_space(1))) void*)gp,
                (__attribute__((address_space(3))) void*)(Bs + rb * 64), 16, 0, 0);
        }
        asm volatile("s_waitcnt vmcnt(0)" ::: "memory");
        __syncthreads();
#pragma unroll
        for (int kx = 0; kx < 2; ++kx) {
            bf16x8 af[4], bfr[NF];
#pragma unroll
            for (int mf = 0; mf < 4; ++mf) {
                int r = wm + mf * 16 + (lane & 15);
                int slot = (lane >> 4) + kx * 4;
                af[mf] = __builtin_bit_cast(bf16x8,
                    *(const u16x8*)(As + r * 64 + ((slot ^ (r & 7)) << 3)));
            }
#pragma unroll
            for (int nf = 0; nf < NF; ++nf) {
                int r = wn + nf * 16 + (lane & 15);
                int slot = (lane >> 4) + kx * 4;
                bfr[nf] = __builtin_bit_cast(bf16x8,
                    *(const u16x8*)(Bs + r * 64 + ((slot ^ (r & 7)) << 3)));
            }
#pragma unroll
            for (int mf = 0; mf < 4; ++mf)
#pragma unroll
                for (int nf = 0; nf < NF; ++nf)
                    acc[mf][nf] = __builtin_amdgcn_mfma_f32_16x16x32_bf16(
                        af[mf], bfr[nf], acc[mf][nf], 0, 0, 0);
        }
    }

    float beta = 0.f;
    if (EPI == 2) beta = 1.f / (1.f + expf(-skipPtr[0]));
#pragma unroll
    for (int nf = 0; nf < NF; ++nf) {
        int gcol = n0 + wn + nf * 16 + (lane & 15);
        float bs = bias[gcol];
#pragma unroll
        for (int mf = 0; mf < 4; ++mf) {
#pragma unroll
            for (int j = 0; j < 4; ++j) {
                int grow = m0 + wm + mf * 16 + (lane >> 4) * 4 + j;
                if (grow >= M) continue;
                float c = acc[mf][nf][j] + bs;
                if (EPI == 1) c = fmaxf(c, 0.f);
                if (EPI == 2) c = beta * c + (1.f - beta) * bf2f(xres[(size_t)grow * ldC + gcol]);
                if (EPI == 3) c = (c > 0.f) ? c : 0.2f * c;
                if (OBF) ((u16*)Cv)[(size_t)grow * ldC + gcol] = f2bf(c);
                else     ((float*)Cv)[(size_t)grow * ldC + gcol] = c;
            }
        }
    }
}

// ------------------------- CSR build -------------------------
__global__ void hist_kernel(const int* __restrict__ di, unsigned* __restrict__ counts, int E) {
    int e = blockIdx.x * blockDim.x + threadIdx.x;
    if (e < E) atomicAdd(&counts[di[e]], 1u);
}

__global__ __launch_bounds__(256) void scan_blocks(
    const unsigned* __restrict__ counts, unsigned* __restrict__ pref,
    unsigned* __restrict__ bsum, int N)
{
    __shared__ unsigned tmp[256];
    int i = blockIdx.x * 256 + threadIdx.x;
    unsigned v = (i < N) ? counts[i] : 0u;
    tmp[threadIdx.x] = v;
    __syncthreads();
    for (int off = 1; off < 256; off <<= 1) {
        unsigned t = (threadIdx.x >= off) ? tmp[threadIdx.x - off] : 0u;
        __syncthreads();
        tmp[threadIdx.x] += t;
        __syncthreads();
    }
    if (i < N) pref[i] = tmp[threadIdx.x] - v;  // exclusive
    if (threadIdx.x == 255) bsum[blockIdx.x] = tmp[255];
}

__global__ __launch_bounds__(256) void scan_top(unsigned* __restrict__ bsum, int NB) {
    __shared__ unsigned tmp[256];
    unsigned v = (threadIdx.x < NB) ? bsum[threadIdx.x] : 0u;
    tmp[threadIdx.x] = v;
    __syncthreads();
    for (int off = 1; off < 256; off <<= 1) {
        unsigned t = (threadIdx.x >= off) ? tmp[threadIdx.x - off] : 0u;
        __syncthreads();
        tmp[threadIdx.x] += t;
        __syncthreads();
    }
    if (threadIdx.x < NB) bsum[threadIdx.x] = tmp[threadIdx.x] - v;  // exclusive
}

__global__ void scan_add(unsigned* __restrict__ pref, const unsigned* __restrict__ bsum,
                         unsigned* __restrict__ cursor, int N) {
    int i = blockIdx.x * 256 + threadIdx.x;
    if (i < N) {
        unsigned s = pref[i] + bsum[blockIdx.x];
        pref[i] = s;
        cursor[i] = s;
    }
}

__global__ void place_kernel(const int* __restrict__ di, unsigned* __restrict__ cursor,
                             unsigned* __restrict__ eid, int E) {
    int e = blockIdx.x * blockDim.x + threadIdx.x;
    if (e < E) {
        unsigned p = atomicAdd(&cursor[di[e]], 1u);
        eid[p] = (unsigned)e;
    }
}

// ------------------------- fused edge gather -------------------------
// One wave per dst node. lane -> row offset lane*4 within 256-wide rows.
// Online softmax over incoming edges; epilogue = gelu; writes bf16 agg row.
__global__ __launch_bounds__(256) void edge_gather(
    const u16* __restrict__ q, const u16* __restrict__ kr, const u16* __restrict__ vr, int ldkv,
    const int* __restrict__ si, const unsigned* __restrict__ rowstart,
    const unsigned* __restrict__ counts, const unsigned* __restrict__ eid,
    u16* __restrict__ agg, int Ndst)
{
    int n = blockIdx.x * 4 + (threadIdx.x >> 6);
    if (n >= Ndst) return;
    int lane = threadIdx.x & 63;
    unsigned start = rowstart[n], deg = counts[n];

    const ushort4 qv = *(const ushort4*)&q[(size_t)n * 256 + lane * 4];
    float q0 = bf2f(qv.x), q1 = bf2f(qv.y), q2 = bf2f(qv.z), q3 = bf2f(qv.w);

    float m = -INFINITY, s = 0.f;
    float a0 = 0.f, a1 = 0.f, a2 = 0.f, a3 = 0.f;
    for (unsigned j = 0; j < deg; ++j) {
        int e = (int)eid[start + j];
        int src = si[e];
        const ushort4 kv = *(const ushort4*)&kr[(size_t)src * ldkv + lane * 4];
        float p = q0 * bf2f(kv.x) + q1 * bf2f(kv.y) + q2 * bf2f(kv.z) + q3 * bf2f(kv.w);
        p += __shfl_xor(p, 1);
        p += __shfl_xor(p, 2);
        p += __shfl_xor(p, 4);
        const ushort4 vv = *(const ushort4*)&vr[(size_t)src * ldkv + lane * 4];
        float mn = fmaxf(m, p);
        float scale = __expf(m - mn);   // 0 on first iteration (m = -inf)
        float w = __expf(p - mn);
        s = s * scale + w;
        a0 = a0 * scale + w * bf2f(vv.x);
        a1 = a1 * scale + w * bf2f(vv.y);
        a2 = a2 * scale + w * bf2f(vv.z);
        a3 = a3 * scale + w * bf2f(vv.w);
        m = mn;
    }
    float inv = 1.f / (s + 1e-16f);
    float o[4] = {a0 * inv, a1 * inv, a2 * inv, a3 * inv};
    ushort4 ov;
    u16* op = (u16*)&ov;
#pragma unroll
    for (int j = 0; j < 4; ++j) {
        float x = o[j];
        float g = 0.5f * x * (1.f + erff(x * 0.70710678118654752f));
        op[j] = f2bf(g);
    }
    *(ushort4*)&agg[(size_t)n * 256 + lane * 4] = ov;
}

// ------------------------- misc -------------------------
__global__ __launch_bounds__(256) void norm_rows(float* __restrict__ y, int M) {
    int row = blockIdx.x * 4 + (threadIdx.x >> 6);
    int lane = threadIdx.x & 63;
    if (row >= M) return;
    float v = y[(size_t)row * 64 + lane];
    float s = v * v;
#pragma unroll
    for (int off = 1; off < 64; off <<= 1) s += __shfl_xor(s, off);
    float n = sqrtf(s);
    y[(size_t)row * 64 + lane] = v / fmaxf(n, 1e-12f);
}

// ------------------------- launch -------------------------
extern "C" void kernel_launch(void* const* d_in, const int* in_sizes, int n_in,
                              void* d_out, int out_size, void* d_ws, size_t ws_size,
                              hipStream_t stream)
{
    const float* x_trans = (const float*)d_in[0];
    const float* x_cc    = (const float*)d_in[1];
    const int* src_c2t   = (const int*)d_in[2];
    const int* dst_c2t   = (const int*)d_in[3];
    const int* src_t2c   = (const int*)d_in[4];
    const int* dst_t2c   = (const int*)d_in[5];
    const float* W_in = (const float*)d_in[6];
    const float* b_in = (const float*)d_in[7];
    const float* Wk   = (const float*)d_in[8];
    const float* bk   = (const float*)d_in[9];
    const float* Wq   = (const float*)d_in[10];
    const float* bq   = (const float*)d_in[11];
    const float* Wv   = (const float*)d_in[12];
    const float* bv   = (const float*)d_in[13];
    const float* Wa   = (const float*)d_in[14];
    const float* ba   = (const float*)d_in[15];
    const float* a_rel = (const float*)d_in[16];
    const float* m_rel = (const float*)d_in[17];
    const float* p_rel = (const float*)d_in[18];
    const float* skip  = (const float*)d_in[19];
    const float* W_out = (const float*)d_in[20];
    const float* b_out = (const float*)d_in[21];

    // ---------- workspace layout (~186 MB) ----------
    char* w = (char*)d_ws;
    auto alloc = [&](size_t bytes) { char* p = w; w += (bytes + 255) & ~(size_t)255; return p; };
    u16* xs0  = (u16*)alloc((size_t)NTN * 256 * 2);   // 30.7 MB
    u16* xs1  = (u16*)alloc((size_t)NCN * 256 * 2);   // 15.4 MB
    u16* xin0 = (u16*)alloc((size_t)NTN * 64 * 2);    //  7.7 MB
    u16* xin1 = (u16*)alloc((size_t)NCN * 64 * 2);    //  3.8 MB
    u16* qb   = (u16*)alloc((size_t)NTN * 256 * 2);   // 30.7 MB
    u16* kvb  = (u16*)alloc((size_t)NTN * 512 * 2);   // 61.4 MB (cat kr|vr, ld 512)
    u16* agg  = (u16*)alloc((size_t)NTN * 256 * 2);   // 30.7 MB
    u16* WinT = (u16*)alloc((size_t)2 * 16384 * 2);   // [256][64] per type
    u16* WqT  = (u16*)alloc((size_t)4 * 65536 * 2);   // [256][256] per lt
    u16* WaT  = (u16*)alloc((size_t)4 * 65536 * 2);
    u16* WkvT = (u16*)alloc((size_t)4 * 131072 * 2);  // [512][256] per lt (kf rows 0..255)
    u16* WoutT= (u16*)alloc((size_t)16384 * 2);       // [64][256]
    float* Wf2 = (float*)alloc((size_t)2 * 65536 * 4); // fuse staging (f32)
    float* bfb = (float*)alloc((size_t)4 * 512 * 4);   // cat bias per lt (f32)
    unsigned* countsT   = (unsigned*)alloc((size_t)NTN * 4);
    unsigned* rowstartT = (unsigned*)alloc((size_t)NTN * 4);
    unsigned* cursorT   = (unsigned*)alloc((size_t)NTN * 4);
    unsigned* eidT      = (unsigned*)alloc((size_t)NED * 4);
    unsigned* countsC   = (unsigned*)alloc((size_t)NCN * 4);
    unsigned* rowstartC = (unsigned*)alloc((size_t)NCN * 4);
    unsigned* cursorC   = (unsigned*)alloc((size_t)NCN * 4);
    unsigned* eidC      = (unsigned*)alloc((size_t)NED * 4);
    unsigned* bsum      = (unsigned*)alloc((size_t)256 * 4);
    (void)ws_size; (void)in_sizes; (void)n_in; (void)out_size;

    // ---------- CSR builds (shared by both layers) ----------
    {
        const int EB = (NED + 255) / 256;
        int NBt = (NTN + 255) / 256;
        fill_u32<<<256, 256, 0, stream>>>(countsT, 0u, NTN);
        hist_kernel<<<EB, 256, 0, stream>>>(dst_c2t, countsT, NED);
        scan_blocks<<<NBt, 256, 0, stream>>>(countsT, rowstartT, bsum, NTN);
        scan_top<<<1, 256, 0, stream>>>(bsum, NBt);
        scan_add<<<NBt, 256, 0, stream>>>(rowstartT, bsum, cursorT, NTN);
        place_kernel<<<EB, 256, 0, stream>>>(dst_c2t, cursorT, eidT, NED);
        int NBc = (NCN + 255) / 256;
        fill_u32<<<256, 256, 0, stream>>>(countsC, 0u, NCN);
        hist_kernel<<<EB, 256, 0, stream>>>(dst_t2c, countsC, NED);
        scan_blocks<<<NBc, 256, 0, stream>>>(countsC, rowstartC, bsum, NCN);
        scan_top<<<1, 256, 0, stream>>>(bsum, NBc);
        scan_add<<<NBc, 256, 0, stream>>>(rowstartC, bsum, cursorC, NCN);
        place_kernel<<<EB, 256, 0, stream>>>(dst_t2c, cursorC, eidC, NED);
    }

    // ---------- weight prep: fuse + convert/transpose to bf16 ----------
    for (int l = 0; l < 2; ++l)
        for (int t = 0; t < 2; ++t) {
            int r = (t == 1) ? 0 : 1;           // relation where type t is the SOURCE
            int lt = l * 2 + t, lr = l * 2 + r;
            fuse_weights<<<256, 256, 0, stream>>>(
                Wk + (size_t)lt * 65536, bk + (size_t)lt * 256,
                Wv + (size_t)lt * 65536, bv + (size_t)lt * 256,
                a_rel + (size_t)lr * 8192, m_rel + (size_t)lr * 8192, p_rel + (size_t)lr * 8,
                Wf2, bfb + lt * 512, Wf2 + 65536, bfb + lt * 512 + 256);
            convT<<<64, 256, 0, stream>>>(Wf2,         WkvT + (size_t)lt * 131072,          256, 256);
            convT<<<64, 256, 0, stream>>>(Wf2 + 65536, WkvT + (size_t)lt * 131072 + 65536,  256, 256);
            convT<<<64, 256, 0, stream>>>(Wq + (size_t)lt * 65536, WqT + (size_t)lt * 65536, 256, 256);
            convT<<<64, 256, 0, stream>>>(Wa + (size_t)lt * 65536, WaT + (size_t)lt * 65536, 256, 256);
        }
    convT<<<16, 256, 0, stream>>>(W_in,         WinT,         64, 256);
    convT<<<16, 256, 0, stream>>>(W_in + 16384, WinT + 16384, 64, 256);
    convT<<<16, 256, 0, stream>>>(W_out, WoutT, 256, 64);
    f32_to_bf16<<<1024, 256, 0, stream>>>(x_trans, xin0, NTN * 64 / 4);
    f32_to_bf16<<<1024, 256, 0, stream>>>(x_cc,    xin1, NCN * 64 / 4);

    const int GT = (NTN + 127) / 128, GC = (NCN + 127) / 128;

    // ---------- input projections + relu ----------
    gemm_mfma<1, 128, true><<<dim3(GT, 2), 256, 0, stream>>>(xin0, WinT, b_in, xs0, NTN, 64, 256, nullptr, nullptr);
    gemm_mfma<1, 128, true><<<dim3(GC, 2), 256, 0, stream>>>(xin1, WinT + 16384, b_in + 256, xs1, NCN, 64, 256, nullptr, nullptr);

    for (int l = 0; l < 2; ++l) {
        size_t lt0 = (size_t)(l * 2 + 0), lt1 = (size_t)(l * 2 + 1);

        // step 1: relation-0 operands (q of type0; fused k|v cat of type1)
        gemm_mfma<0, 128, true><<<dim3(GT, 2), 256, 0, stream>>>(xs0, WqT + lt0 * 65536, bq + lt0 * 256, qb, NTN, 256, 256, nullptr, nullptr);
        gemm_mfma<0, 128, true><<<dim3(GC, 4), 256, 0, stream>>>(xs1, WkvT + lt1 * 131072, bfb + lt1 * 512, kvb, NCN, 256, 512, nullptr, nullptr);

        // step 2: edge phase relation 0 (cc -> trans), dst = type0
        edge_gather<<<(NTN + 3) / 4, 256, 0, stream>>>(qb, kvb, kvb + 256, 512, src_c2t,
                                                       rowstartT, countsT, eidT, agg, NTN);

        // step 3: relation-1 operands (from OLD xs0/xs1, before xs0 update)
        gemm_mfma<0, 128, true><<<dim3(GT, 4), 256, 0, stream>>>(xs0, WkvT + lt0 * 131072, bfb + lt0 * 512, kvb, NTN, 256, 512, nullptr, nullptr);
        gemm_mfma<0, 128, true><<<dim3(GC, 2), 256, 0, stream>>>(xs1, WqT + lt1 * 65536, bq + lt1 * 256, qb, NCN, 256, 256, nullptr, nullptr);

        // step 4: xs0 = blend(agg @ Wa + ba, xs0)   (agg already gelu'd, bf16)
        gemm_mfma<2, 128, true><<<dim3(GT, 2), 256, 0, stream>>>(agg, WaT + lt0 * 65536, ba + lt0 * 256, xs0, NTN, 256, 256, xs0, skip + l * 2 + 0);

        // step 5: edge phase relation 1 (trans -> cc), dst = type1
        edge_gather<<<(NCN + 3) / 4, 256, 0, stream>>>(qb, kvb, kvb + 256, 512, src_t2c,
                                                       rowstartC, countsC, eidC, agg, NCN);

        // step 6: xs1 update
        gemm_mfma<2, 128, true><<<dim3(GC, 2), 256, 0, stream>>>(agg, WaT + lt1 * 65536, ba + lt1 * 256, xs1, NCN, 256, 256, xs1, skip + l * 2 + 1);
    }

    // ---------- final projection + leakyrelu + row L2 normalize ----------
    {
        float* y = (float*)d_out;
        gemm_mfma<3, 64, false><<<dim3(GT, 1), 256, 0, stream>>>(xs0, WoutT, b_out, y, NTN, 256, 64, nullptr, nullptr);
        norm_rows<<<NTN / 4, 256, 0, stream>>>(y, NTN);
    }
}

// Round 5
// 671.298 us; speedup vs baseline: 6.4511x; 1.2027x over previous
//
#include <hip/hip_runtime.h>
#include <hip/hip_bf16.h>
#include <math.h>

#define NTN 60000
#define NCN 30000
#define NED 200000
// H=8, D=32, HID=256, FIN=64

typedef unsigned short u16;
typedef __attribute__((ext_vector_type(8))) u16 u16x8;
typedef __attribute__((ext_vector_type(8))) __bf16 bf16x8;
typedef __attribute__((ext_vector_type(4))) float f32x4;

static __device__ __forceinline__ float bf2f(u16 u) {
    return __uint_as_float(((unsigned)u) << 16);
}
static __device__ __forceinline__ u16 f2bf(float f) {
    unsigned u = __float_as_uint(f);
    unsigned r = (u + 0x7fffu + ((u >> 16) & 1u)) >> 16;  // RNE
    return (u16)r;
}

// ------------------------- fill -------------------------
__global__ void fill_u32(unsigned* __restrict__ p, unsigned v, int n) {
    int i = blockIdx.x * blockDim.x + threadIdx.x;
    int stride = gridDim.x * blockDim.x;
    for (; i < n; i += stride) p[i] = v;
}

// ------------------------- conversions -------------------------
__global__ void f32_to_bf16(const float* __restrict__ in, u16* __restrict__ out, int n4) {
    int i = blockIdx.x * blockDim.x + threadIdx.x;
    int stride = gridDim.x * blockDim.x;
    for (; i < n4; i += stride) {
        float4 v = ((const float4*)in)[i];
        ushort4 o;
        o.x = f2bf(v.x); o.y = f2bf(v.y); o.z = f2bf(v.z); o.w = f2bf(v.w);
        ((ushort4*)out)[i] = o;
    }
}

// out[n][k] = bf16(in[k][n]); coalesced reads across n.
__global__ void convT(const float* __restrict__ in, u16* __restrict__ out, int K, int N) {
    int idx = blockIdx.x * blockDim.x + threadIdx.x;
    int total = N * (K >> 2);
    if (idx >= total) return;
    int k4 = idx / N, n = idx - k4 * N;
    int k = k4 * 4;
    ushort4 o;
    o.x = f2bf(in[(size_t)(k + 0) * N + n]);
    o.y = f2bf(in[(size_t)(k + 1) * N + n]);
    o.z = f2bf(in[(size_t)(k + 2) * N + n]);
    o.w = f2bf(in[(size_t)(k + 3) * N + n]);
    *(ushort4*)(out + (size_t)n * K + k) = o;
}

// --------------------- weight fusion ---------------------
__global__ __launch_bounds__(256) void fuse_weights(
    const float* __restrict__ Wk, const float* __restrict__ bk,
    const float* __restrict__ Wv, const float* __restrict__ bv,
    const float* __restrict__ ar, const float* __restrict__ mr,
    const float* __restrict__ pr,
    float* __restrict__ Wkf, float* __restrict__ bkf,
    float* __restrict__ Wvf, float* __restrict__ bvf)
{
    __shared__ float kw[256], vw[256];
    const int c = blockIdx.x, tid = threadIdx.x;
    kw[tid] = Wk[c * 256 + tid];
    vw[tid] = Wv[c * 256 + tid];
    __syncthreads();
    const int h = tid >> 5, e = tid & 31;
    const float s = pr[h] * 0.17677669529663687f;  // 1/sqrt(32)
    float ak = 0.f, av = 0.f;
#pragma unroll 8
    for (int d = 0; d < 32; ++d) {
        ak += kw[h * 32 + d] * ar[h * 1024 + d * 32 + e];
        av += vw[h * 32 + d] * mr[h * 1024 + d * 32 + e];
    }
    Wkf[c * 256 + tid] = ak * s;
    Wvf[c * 256 + tid] = av;
    if (c == 0) {
        float bka = 0.f, bva = 0.f;
#pragma unroll 8
        for (int d = 0; d < 32; ++d) {
            bka += bk[h * 32 + d] * ar[h * 1024 + d * 32 + e];
            bva += bv[h * 32 + d] * mr[h * 1024 + d * 32 + e];
        }
        bkf[tid] = bka * s;
        bvf[tid] = bva;
    }
}

// ------------------------- MFMA GEMM -------------------------
// C[M, NY*BN] = epi(A[M,K](bf16) @ WT[.,K]^T(bf16) + bias).
// 128 x BN tile, BK=64, 4 waves (2x2), double-buffered LDS with counted vmcnt.
// 1D grid: bijective XCD swizzle, then y-inner decode (A-tile L2 locality).
// EPI: 0=none, 1=relu, 2=skip-blend, 3=leakyrelu(0.2). OBF: bf16 out + LDS-coalesced store.
template <int EPI, int BN, bool OBF>
__global__ __launch_bounds__(256) void gemm_mfma(
    const u16* __restrict__ A, const u16* __restrict__ WT,
    const float* __restrict__ bias, void* __restrict__ Cv,
    int M, int K, int ldC, int NY,
    const u16* __restrict__ xres, const float* __restrict__ skipPtr)
{
    constexpr int ASZ = 128 * 64;
    constexpr int BSZ = BN * 64;
    constexpr int NF = BN / 32;          // n-frags per wave
    __shared__ u16 smem[2 * (ASZ + BSZ)];
    u16* As0 = smem;            u16* Bs0 = smem + ASZ;
    u16* As1 = smem + ASZ + BSZ; u16* Bs1 = As1 + ASZ;

    // bijective XCD swizzle (m204), then y-inner decode
    const int nwg = gridDim.x;
    const int bid = blockIdx.x;
    const int q8 = nwg >> 3, r8 = nwg & 7;
    const int xcd = bid & 7, pos = bid >> 3;
    const int lbid = (xcd < r8) ? xcd * (q8 + 1) + pos
                                : r8 * (q8 + 1) + (xcd - r8) * q8 + pos;
    const int bx = lbid / NY, by = lbid - bx * NY;
    const int m0 = bx * 128, n0 = by * BN;

    const int tid = threadIdx.x;
    const int wave = tid >> 6, lane = tid & 63;
    const int wm = (wave >> 1) * 64, wn = (wave & 1) * (BN / 2);
    f32x4 acc[4][NF];
#pragma unroll
    for (int i = 0; i < 4; ++i)
#pragma unroll
        for (int j = 0; j < NF; ++j) acc[i][j] = (f32x4){0.f, 0.f, 0.f, 0.f};

    const int sr = lane >> 3;   // row within 8-row staging group
    const int sl = lane & 7;    // linear 16B slot

    auto stage = [&](int k0, u16* Ad, u16* Bd) {
#pragma unroll
        for (int i = 0; i < 4; ++i) {
            int rb = wave * 32 + i * 8;
            int r = rb + sr;
            int gr = m0 + r; gr = gr < M ? gr : M - 1;
            const u16* gp = A + (size_t)gr * K + k0 + ((sl ^ sr) << 3);
            __builtin_amdgcn_global_load_lds(
                (const __attribute__((address_space(1))) void*)gp,
                (__attribute__((address_space(3))) void*)(Ad + rb * 64), 16, 0, 0);
        }
#pragma unroll
        for (int i = 0; i < NF; ++i) {
            int rb = wave * (BN / 4) + i * 8;
            int r = rb + sr;
            const u16* gp = WT + (size_t)(n0 + r) * K + k0 + ((sl ^ sr) << 3);
            __builtin_amdgcn_global_load_lds(
                (const __attribute__((address_space(1))) void*)gp,
                (__attribute__((address_space(3))) void*)(Bd + rb * 64), 16, 0, 0);
        }
    };

    auto compute = [&](const u16* Ab, const u16* Bb) {
#pragma unroll
        for (int kx = 0; kx < 2; ++kx) {
            bf16x8 af[4], bfr[NF];
#pragma unroll
            for (int mf = 0; mf < 4; ++mf) {
                int r = wm + mf * 16 + (lane & 15);
                int slot = (lane >> 4) + kx * 4;
                af[mf] = __builtin_bit_cast(bf16x8,
                    *(const u16x8*)(Ab + r * 64 + ((slot ^ (r & 7)) << 3)));
            }
#pragma unroll
            for (int nf = 0; nf < NF; ++nf) {
                int r = wn + nf * 16 + (lane & 15);
                int slot = (lane >> 4) + kx * 4;
                bfr[nf] = __builtin_bit_cast(bf16x8,
                    *(const u16x8*)(Bb + r * 64 + ((slot ^ (r & 7)) << 3)));
            }
#pragma unroll
            for (int mf = 0; mf < 4; ++mf)
#pragma unroll
                for (int nf = 0; nf < NF; ++nf)
                    acc[mf][nf] = __builtin_amdgcn_mfma_f32_16x16x32_bf16(
                        af[mf], bfr[nf], acc[mf][nf], 0, 0, 0);
        }
    };

    const int nt = K >> 6;
    stage(0, As0, Bs0);
    for (int t = 0; t < nt; ++t) {
        const bool pb = t & 1;
        if (t + 1 < nt) {
            stage((t + 1) << 6, pb ? As0 : As1, pb ? Bs0 : Bs1);
            __builtin_amdgcn_sched_barrier(0);
            if constexpr (BN == 128) asm volatile("s_waitcnt vmcnt(8)" ::: "memory");
            else                     asm volatile("s_waitcnt vmcnt(6)" ::: "memory");
        } else {
            asm volatile("s_waitcnt vmcnt(0)" ::: "memory");
        }
        __builtin_amdgcn_s_barrier();
        __builtin_amdgcn_sched_barrier(0);
        compute(pb ? As1 : As0, pb ? Bs1 : Bs0);
        __builtin_amdgcn_sched_barrier(0);
        __builtin_amdgcn_s_barrier();
    }

    float beta = 0.f;
    if (EPI == 2) beta = 1.f / (1.f + expf(-skipPtr[0]));

    if constexpr (OBF) {
        // register epilogue -> padded LDS C-tile (aliases staging bufs; all reads retired)
        constexpr int CLD = BN + 8;
        u16* Ct = smem;
#pragma unroll
        for (int nf = 0; nf < NF; ++nf) {
            int col = wn + nf * 16 + (lane & 15);
            int gcol = n0 + col;
            float bs = bias[gcol];
#pragma unroll
            for (int mf = 0; mf < 4; ++mf) {
#pragma unroll
                for (int j = 0; j < 4; ++j) {
                    int row = wm + mf * 16 + (lane >> 4) * 4 + j;
                    int grow = m0 + row;
                    int gr2 = grow < M ? grow : 0;
                    float c = acc[mf][nf][j] + bs;
                    if (EPI == 1) c = fmaxf(c, 0.f);
                    if (EPI == 2) c = beta * c + (1.f - beta) * bf2f(xres[(size_t)gr2 * ldC + gcol]);
                    if (EPI == 3) c = (c > 0.f) ? c : 0.2f * c;
                    Ct[row * CLD + col] = f2bf(c);
                }
            }
        }
        __builtin_amdgcn_s_barrier();
        // coalesced write: 2 threads per row, BN/2 u16 each
        int row = tid >> 1, c0 = (tid & 1) * (BN / 2);
        int grow = m0 + row;
        if (grow < M) {
            u16* dst = (u16*)Cv + (size_t)grow * ldC + n0 + c0;
            const u16* src = Ct + row * CLD + c0;
#pragma unroll
            for (int i = 0; i < BN / 16; ++i)
                *(u16x8*)(dst + i * 8) = *(const u16x8*)(src + i * 8);
        }
    } else {
#pragma unroll
        for (int nf = 0; nf < NF; ++nf) {
            int gcol = n0 + wn + nf * 16 + (lane & 15);
            float bs = bias[gcol];
#pragma unroll
            for (int mf = 0; mf < 4; ++mf) {
#pragma unroll
                for (int j = 0; j < 4; ++j) {
                    int grow = m0 + wm + mf * 16 + (lane >> 4) * 4 + j;
                    if (grow >= M) continue;
                    float c = acc[mf][nf][j] + bs;
                    if (EPI == 1) c = fmaxf(c, 0.f);
                    if (EPI == 3) c = (c > 0.f) ? c : 0.2f * c;
                    ((float*)Cv)[(size_t)grow * ldC + gcol] = c;
                }
            }
        }
    }
}

// ------------------------- CSR build -------------------------
__global__ void hist_kernel(const int* __restrict__ di, unsigned* __restrict__ counts, int E) {
    int e = blockIdx.x * blockDim.x + threadIdx.x;
    if (e < E) atomicAdd(&counts[di[e]], 1u);
}

__global__ __launch_bounds__(256) void scan_blocks(
    const unsigned* __restrict__ counts, unsigned* __restrict__ pref,
    unsigned* __restrict__ bsum, int N)
{
    __shared__ unsigned tmp[256];
    int i = blockIdx.x * 256 + threadIdx.x;
    unsigned v = (i < N) ? counts[i] : 0u;
    tmp[threadIdx.x] = v;
    __syncthreads();
    for (int off = 1; off < 256; off <<= 1) {
        unsigned t = (threadIdx.x >= off) ? tmp[threadIdx.x - off] : 0u;
        __syncthreads();
        tmp[threadIdx.x] += t;
        __syncthreads();
    }
    if (i < N) pref[i] = tmp[threadIdx.x] - v;  // exclusive
    if (threadIdx.x == 255) bsum[blockIdx.x] = tmp[255];
}

__global__ __launch_bounds__(256) void scan_top(unsigned* __restrict__ bsum, int NB) {
    __shared__ unsigned tmp[256];
    unsigned v = (threadIdx.x < NB) ? bsum[threadIdx.x] : 0u;
    tmp[threadIdx.x] = v;
    __syncthreads();
    for (int off = 1; off < 256; off <<= 1) {
        unsigned t = (threadIdx.x >= off) ? tmp[threadIdx.x - off] : 0u;
        __syncthreads();
        tmp[threadIdx.x] += t;
        __syncthreads();
    }
    if (threadIdx.x < NB) bsum[threadIdx.x] = tmp[threadIdx.x] - v;  // exclusive
}

__global__ void scan_add(unsigned* __restrict__ pref, const unsigned* __restrict__ bsum,
                         unsigned* __restrict__ cursor, int N) {
    int i = blockIdx.x * 256 + threadIdx.x;
    if (i < N) {
        unsigned s = pref[i] + bsum[blockIdx.x];
        pref[i] = s;
        cursor[i] = s;
    }
}

__global__ void place_kernel(const int* __restrict__ di, unsigned* __restrict__ cursor,
                             unsigned* __restrict__ eid, int E) {
    int e = blockIdx.x * blockDim.x + threadIdx.x;
    if (e < E) {
        unsigned p = atomicAdd(&cursor[di[e]], 1u);
        eid[p] = (unsigned)e;
    }
}

// ------------------------- fused edge gather -------------------------
__global__ __launch_bounds__(256) void edge_gather(
    const u16* __restrict__ q, const u16* __restrict__ kr, const u16* __restrict__ vr, int ldkv,
    const int* __restrict__ si, const unsigned* __restrict__ rowstart,
    const unsigned* __restrict__ counts, const unsigned* __restrict__ eid,
    u16* __restrict__ agg, int Ndst)
{
    int n = blockIdx.x * 4 + (threadIdx.x >> 6);
    if (n >= Ndst) return;
    int lane = threadIdx.x & 63;
    unsigned start = rowstart[n], deg = counts[n];

    const ushort4 qv = *(const ushort4*)&q[(size_t)n * 256 + lane * 4];
    float q0 = bf2f(qv.x), q1 = bf2f(qv.y), q2 = bf2f(qv.z), q3 = bf2f(qv.w);

    float m = -INFINITY, s = 0.f;
    float a0 = 0.f, a1 = 0.f, a2 = 0.f, a3 = 0.f;
    for (unsigned j = 0; j < deg; ++j) {
        int e = (int)eid[start + j];
        int src = si[e];
        const ushort4 kv = *(const ushort4*)&kr[(size_t)src * ldkv + lane * 4];
        float p = q0 * bf2f(kv.x) + q1 * bf2f(kv.y) + q2 * bf2f(kv.z) + q3 * bf2f(kv.w);
        p += __shfl_xor(p, 1);
        p += __shfl_xor(p, 2);
        p += __shfl_xor(p, 4);
        const ushort4 vv = *(const ushort4*)&vr[(size_t)src * ldkv + lane * 4];
        float mn = fmaxf(m, p);
        float scale = __expf(m - mn);   // 0 on first iteration (m = -inf)
        float w = __expf(p - mn);
        s = s * scale + w;
        a0 = a0 * scale + w * bf2f(vv.x);
        a1 = a1 * scale + w * bf2f(vv.y);
        a2 = a2 * scale + w * bf2f(vv.z);
        a3 = a3 * scale + w * bf2f(vv.w);
        m = mn;
    }
    float inv = 1.f / (s + 1e-16f);
    float o[4] = {a0 * inv, a1 * inv, a2 * inv, a3 * inv};
    ushort4 ov;
    u16* op = (u16*)&ov;
#pragma unroll
    for (int j = 0; j < 4; ++j) {
        float x = o[j];
        float g = 0.5f * x * (1.f + erff(x * 0.70710678118654752f));
        op[j] = f2bf(g);
    }
    *(ushort4*)&agg[(size_t)n * 256 + lane * 4] = ov;
}

// ------------------------- misc -------------------------
__global__ __launch_bounds__(256) void norm_rows(float* __restrict__ y, int M) {
    int row = blockIdx.x * 4 + (threadIdx.x >> 6);
    int lane = threadIdx.x & 63;
    if (row >= M) return;
    float v = y[(size_t)row * 64 + lane];
    float s = v * v;
#pragma unroll
    for (int off = 1; off < 64; off <<= 1) s += __shfl_xor(s, off);
    float n = sqrtf(s);
    y[(size_t)row * 64 + lane] = v / fmaxf(n, 1e-12f);
}

// ------------------------- launch -------------------------
extern "C" void kernel_launch(void* const* d_in, const int* in_sizes, int n_in,
                              void* d_out, int out_size, void* d_ws, size_t ws_size,
                              hipStream_t stream)
{
    const float* x_trans = (const float*)d_in[0];
    const float* x_cc    = (const float*)d_in[1];
    const int* src_c2t   = (const int*)d_in[2];
    const int* dst_c2t   = (const int*)d_in[3];
    const int* src_t2c   = (const int*)d_in[4];
    const int* dst_t2c   = (const int*)d_in[5];
    const float* W_in = (const float*)d_in[6];
    const float* b_in = (const float*)d_in[7];
    const float* Wk   = (const float*)d_in[8];
    const float* bk   = (const float*)d_in[9];
    const float* Wq   = (const float*)d_in[10];
    const float* bq   = (const float*)d_in[11];
    const float* Wv   = (const float*)d_in[12];
    const float* bv   = (const float*)d_in[13];
    const float* Wa   = (const float*)d_in[14];
    const float* ba   = (const float*)d_in[15];
    const float* a_rel = (const float*)d_in[16];
    const float* m_rel = (const float*)d_in[17];
    const float* p_rel = (const float*)d_in[18];
    const float* skip  = (const float*)d_in[19];
    const float* W_out = (const float*)d_in[20];
    const float* b_out = (const float*)d_in[21];

    // ---------- workspace layout (~186 MB) ----------
    char* w = (char*)d_ws;
    auto alloc = [&](size_t bytes) { char* p = w; w += (bytes + 255) & ~(size_t)255; return p; };
    u16* xs0  = (u16*)alloc((size_t)NTN * 256 * 2);
    u16* xs1  = (u16*)alloc((size_t)NCN * 256 * 2);
    u16* xin0 = (u16*)alloc((size_t)NTN * 64 * 2);
    u16* xin1 = (u16*)alloc((size_t)NCN * 64 * 2);
    u16* qb   = (u16*)alloc((size_t)NTN * 256 * 2);
    u16* kvb  = (u16*)alloc((size_t)NTN * 512 * 2);   // cat kr|vr, ld 512
    u16* agg  = (u16*)alloc((size_t)NTN * 256 * 2);
    u16* WinT = (u16*)alloc((size_t)2 * 16384 * 2);
    u16* WqT  = (u16*)alloc((size_t)4 * 65536 * 2);
    u16* WaT  = (u16*)alloc((size_t)4 * 65536 * 2);
    u16* WkvT = (u16*)alloc((size_t)4 * 131072 * 2);
    u16* WoutT= (u16*)alloc((size_t)16384 * 2);
    float* Wf2 = (float*)alloc((size_t)2 * 65536 * 4);
    float* bfb = (float*)alloc((size_t)4 * 512 * 4);
    unsigned* countsT   = (unsigned*)alloc((size_t)NTN * 4);
    unsigned* rowstartT = (unsigned*)alloc((size_t)NTN * 4);
    unsigned* cursorT   = (unsigned*)alloc((size_t)NTN * 4);
    unsigned* eidT      = (unsigned*)alloc((size_t)NED * 4);
    unsigned* countsC   = (unsigned*)alloc((size_t)NCN * 4);
    unsigned* rowstartC = (unsigned*)alloc((size_t)NCN * 4);
    unsigned* cursorC   = (unsigned*)alloc((size_t)NCN * 4);
    unsigned* eidC      = (unsigned*)alloc((size_t)NED * 4);
    unsigned* bsum      = (unsigned*)alloc((size_t)256 * 4);
    (void)ws_size; (void)in_sizes; (void)n_in; (void)out_size;

    // ---------- CSR builds (shared by both layers) ----------
    {
        const int EB = (NED + 255) / 256;
        int NBt = (NTN + 255) / 256;
        fill_u32<<<256, 256, 0, stream>>>(countsT, 0u, NTN);
        hist_kernel<<<EB, 256, 0, stream>>>(dst_c2t, countsT, NED);
        scan_blocks<<<NBt, 256, 0, stream>>>(countsT, rowstartT, bsum, NTN);
        scan_top<<<1, 256, 0, stream>>>(bsum, NBt);
        scan_add<<<NBt, 256, 0, stream>>>(rowstartT, bsum, cursorT, NTN);
        place_kernel<<<EB, 256, 0, stream>>>(dst_c2t, cursorT, eidT, NED);
        int NBc = (NCN + 255) / 256;
        fill_u32<<<256, 256, 0, stream>>>(countsC, 0u, NCN);
        hist_kernel<<<EB, 256, 0, stream>>>(dst_t2c, countsC, NED);
        scan_blocks<<<NBc, 256, 0, stream>>>(countsC, rowstartC, bsum, NCN);
        scan_top<<<1, 256, 0, stream>>>(bsum, NBc);
        scan_add<<<NBc, 256, 0, stream>>>(rowstartC, bsum, cursorC, NCN);
        place_kernel<<<EB, 256, 0, stream>>>(dst_t2c, cursorC, eidC, NED);
    }

    // ---------- weight prep: fuse + convert/transpose to bf16 ----------
    for (int l = 0; l < 2; ++l)
        for (int t = 0; t < 2; ++t) {
            int r = (t == 1) ? 0 : 1;           // relation where type t is the SOURCE
            int lt = l * 2 + t, lr = l * 2 + r;
            fuse_weights<<<256, 256, 0, stream>>>(
                Wk + (size_t)lt * 65536, bk + (size_t)lt * 256,
                Wv + (size_t)lt * 65536, bv + (size_t)lt * 256,
                a_rel + (size_t)lr * 8192, m_rel + (size_t)lr * 8192, p_rel + (size_t)lr * 8,
                Wf2, bfb + lt * 512, Wf2 + 65536, bfb + lt * 512 + 256);
            convT<<<64, 256, 0, stream>>>(Wf2,         WkvT + (size_t)lt * 131072,          256, 256);
            convT<<<64, 256, 0, stream>>>(Wf2 + 65536, WkvT + (size_t)lt * 131072 + 65536,  256, 256);
            convT<<<64, 256, 0, stream>>>(Wq + (size_t)lt * 65536, WqT + (size_t)lt * 65536, 256, 256);
            convT<<<64, 256, 0, stream>>>(Wa + (size_t)lt * 65536, WaT + (size_t)lt * 65536, 256, 256);
        }
    convT<<<16, 256, 0, stream>>>(W_in,         WinT,         64, 256);
    convT<<<16, 256, 0, stream>>>(W_in + 16384, WinT + 16384, 64, 256);
    convT<<<16, 256, 0, stream>>>(W_out, WoutT, 256, 64);
    f32_to_bf16<<<1024, 256, 0, stream>>>(x_trans, xin0, NTN * 64 / 4);
    f32_to_bf16<<<1024, 256, 0, stream>>>(x_cc,    xin1, NCN * 64 / 4);

    const int GT = (NTN + 127) / 128, GC = (NCN + 127) / 128;

    // ---------- input projections + relu ----------
    gemm_mfma<1, 128, true><<<GT * 2, 256, 0, stream>>>(xin0, WinT, b_in, xs0, NTN, 64, 256, 2, nullptr, nullptr);
    gemm_mfma<1, 128, true><<<GC * 2, 256, 0, stream>>>(xin1, WinT + 16384, b_in + 256, xs1, NCN, 64, 256, 2, nullptr, nullptr);

    for (int l = 0; l < 2; ++l) {
        size_t lt0 = (size_t)(l * 2 + 0), lt1 = (size_t)(l * 2 + 1);

        // step 1: relation-0 operands (q of type0; fused k|v cat of type1)
        gemm_mfma<0, 128, true><<<GT * 2, 256, 0, stream>>>(xs0, WqT + lt0 * 65536, bq + lt0 * 256, qb, NTN, 256, 256, 2, nullptr, nullptr);
        gemm_mfma<0, 128, true><<<GC * 4, 256, 0, stream>>>(xs1, WkvT + lt1 * 131072, bfb + lt1 * 512, kvb, NCN, 256, 512, 4, nullptr, nullptr);

        // step 2: edge phase relation 0 (cc -> trans), dst = type0
        edge_gather<<<(NTN + 3) / 4, 256, 0, stream>>>(qb, kvb, kvb + 256, 512, src_c2t,
                                                       rowstartT, countsT, eidT, agg, NTN);

        // step 3: relation-1 operands (from OLD xs0/xs1, before xs0 update)
        gemm_mfma<0, 128, true><<<GT * 4, 256, 0, stream>>>(xs0, WkvT + lt0 * 131072, bfb + lt0 * 512, kvb, NTN, 256, 512, 4, nullptr, nullptr);
        gemm_mfma<0, 128, true><<<GC * 2, 256, 0, stream>>>(xs1, WqT + lt1 * 65536, bq + lt1 * 256, qb, NCN, 256, 256, 2, nullptr, nullptr);

        // step 4: xs0 = blend(agg @ Wa + ba, xs0)   (agg already gelu'd, bf16)
        gemm_mfma<2, 128, true><<<GT * 2, 256, 0, stream>>>(agg, WaT + lt0 * 65536, ba + lt0 * 256, xs0, NTN, 256, 256, 2, xs0, skip + l * 2 + 0);

        // step 5: edge phase relation 1 (trans -> cc), dst = type1
        edge_gather<<<(NCN + 3) / 4, 256, 0, stream>>>(qb, kvb, kvb + 256, 512, src_t2c,
                                                       rowstartC, countsC, eidC, agg, NCN);

        // step 6: xs1 update
        gemm_mfma<2, 128, true><<<GC * 2, 256, 0, stream>>>(agg, WaT + lt1 * 65536, ba + lt1 * 256, xs1, NCN, 256, 256, 2, xs1, skip + l * 2 + 1);
    }

    // ---------- final projection + leakyrelu + row L2 normalize ----------
    {
        float* y = (float*)d_out;
        gemm_mfma<3, 64, false><<<GT, 256, 0, stream>>>(xs0, WoutT, b_out, y, NTN, 256, 64, 1, nullptr, nullptr);
        norm_rows<<<NTN / 4, 256, 0, stream>>>(y, NTN);
    }
}

// Round 7
// 648.991 us; speedup vs baseline: 6.6729x; 1.0344x over previous
//
#include <hip/hip_runtime.h>
#include <hip/hip_bf16.h>
#include <math.h>

#define NTN 60000
#define NCN 30000
#define NED 200000
// H=8, D=32, HID=256, FIN=64

typedef unsigned short u16;
typedef __attribute__((ext_vector_type(8))) u16 u16x8;
typedef __attribute__((ext_vector_type(8))) __bf16 bf16x8;
typedef __attribute__((ext_vector_type(4))) float f32x4;

static __device__ __forceinline__ float bf2f(u16 u) {
    return __uint_as_float(((unsigned)u) << 16);
}
static __device__ __forceinline__ u16 f2bf(float f) {
    unsigned u = __float_as_uint(f);
    unsigned r = (u + 0x7fffu + ((u >> 16) & 1u)) >> 16;  // RNE
    return (u16)r;
}

// ------------------------- fill / copy -------------------------
__global__ void fill_u32(unsigned* __restrict__ p, unsigned v, int n) {
    int i = blockIdx.x * blockDim.x + threadIdx.x;
    int stride = gridDim.x * blockDim.x;
    for (; i < n; i += stride) p[i] = v;
}

__global__ void copy256(const float* __restrict__ in, float* __restrict__ out) {
    out[threadIdx.x] = in[threadIdx.x];
}

// ------------------------- conversions -------------------------
__global__ void f32_to_bf16(const float* __restrict__ in, u16* __restrict__ out, int n4) {
    int i = blockIdx.x * blockDim.x + threadIdx.x;
    int stride = gridDim.x * blockDim.x;
    for (; i < n4; i += stride) {
        float4 v = ((const float4*)in)[i];
        ushort4 o;
        o.x = f2bf(v.x); o.y = f2bf(v.y); o.z = f2bf(v.z); o.w = f2bf(v.w);
        ((ushort4*)out)[i] = o;
    }
}

// out[n][k] = bf16(in[k][n]); coalesced reads across n.
__global__ void convT(const float* __restrict__ in, u16* __restrict__ out, int K, int N) {
    int idx = blockIdx.x * blockDim.x + threadIdx.x;
    int total = N * (K >> 2);
    if (idx >= total) return;
    int k4 = idx / N, n = idx - k4 * N;
    int k = k4 * 4;
    ushort4 o;
    o.x = f2bf(in[(size_t)(k + 0) * N + n]);
    o.y = f2bf(in[(size_t)(k + 1) * N + n]);
    o.z = f2bf(in[(size_t)(k + 2) * N + n]);
    o.w = f2bf(in[(size_t)(k + 3) * N + n]);
    *(ushort4*)(out + (size_t)n * K + k) = o;
}

// --------------------- weight fusion ---------------------
__global__ __launch_bounds__(256) void fuse_weights(
    const float* __restrict__ Wk, const float* __restrict__ bk,
    const float* __restrict__ Wv, const float* __restrict__ bv,
    const float* __restrict__ ar, const float* __restrict__ mr,
    const float* __restrict__ pr,
    float* __restrict__ Wkf, float* __restrict__ bkf,
    float* __restrict__ Wvf, float* __restrict__ bvf)
{
    __shared__ float kw[256], vw[256];
    const int c = blockIdx.x, tid = threadIdx.x;
    kw[tid] = Wk[c * 256 + tid];
    vw[tid] = Wv[c * 256 + tid];
    __syncthreads();
    const int h = tid >> 5, e = tid & 31;
    const float s = pr[h] * 0.17677669529663687f;  // 1/sqrt(32)
    float ak = 0.f, av = 0.f;
#pragma unroll 8
    for (int d = 0; d < 32; ++d) {
        ak += kw[h * 32 + d] * ar[h * 1024 + d * 32 + e];
        av += vw[h * 32 + d] * mr[h * 1024 + d * 32 + e];
    }
    Wkf[c * 256 + tid] = ak * s;
    Wvf[c * 256 + tid] = av;
    if (c == 0) {
        float bka = 0.f, bva = 0.f;
#pragma unroll 8
        for (int d = 0; d < 32; ++d) {
            bka += bk[h * 32 + d] * ar[h * 1024 + d * 32 + e];
            bva += bv[h * 32 + d] * mr[h * 1024 + d * 32 + e];
        }
        bkf[tid] = bka * s;
        bvf[tid] = bva;
    }
}

// ------------------------- MFMA GEMM -------------------------
// C[M, NY*BN] = epi(A[M,K](bf16) @ WT[.,K]^T(bf16) + bias).
// 64 x BN tile, BK=64, 4 waves (2x2), double-buffered LDS, counted vmcnt.
// Raw-barrier pipeline fenced with sched_barrier(0) on BOTH sides of every
// s_barrier; epilogue cross-wave LDS handoff uses __syncthreads() (lgkm drain).
template <int EPI, int BN, bool OBF>
__global__ __launch_bounds__(256) void gemm_mfma(
    const u16* __restrict__ A, const u16* __restrict__ WT,
    const float* __restrict__ bias, void* __restrict__ Cv,
    int M, int K, int ldC, int NY,
    const u16* __restrict__ xres, const float* __restrict__ skipPtr)
{
    constexpr int ASZ = 64 * 64;
    constexpr int BSZ = BN * 64;
    constexpr int NF = BN / 32;          // n-frags per wave (and B stage insts per wave)
    __shared__ u16 smem[2 * (ASZ + BSZ)];
    u16* As0 = smem;             u16* Bs0 = smem + ASZ;
    u16* As1 = smem + ASZ + BSZ; u16* Bs1 = As1 + ASZ;

    // bijective XCD swizzle (m204), then y-inner decode
    const int nwg = gridDim.x;
    const int bid = blockIdx.x;
    const int q8 = nwg >> 3, r8 = nwg & 7;
    const int xcd = bid & 7, pos = bid >> 3;
    const int lbid = (xcd < r8) ? xcd * (q8 + 1) + pos
                                : r8 * (q8 + 1) + (xcd - r8) * q8 + pos;
    const int bx = lbid / NY, by = lbid - bx * NY;
    const int m0 = bx * 64, n0 = by * BN;

    const int tid = threadIdx.x;
    const int wave = tid >> 6, lane = tid & 63;
    const int wm = (wave >> 1) * 32, wn = (wave & 1) * (BN / 2);
    f32x4 acc[2][NF];
#pragma unroll
    for (int i = 0; i < 2; ++i)
#pragma unroll
        for (int j = 0; j < NF; ++j) acc[i][j] = (f32x4){0.f, 0.f, 0.f, 0.f};

    const int sr = lane >> 3;   // row within 8-row staging group
    const int sl = lane & 7;    // linear 16B slot

    auto stage = [&](int k0, u16* Ad, u16* Bd) {
#pragma unroll
        for (int i = 0; i < 2; ++i) {
            int rb = wave * 16 + i * 8;
            int r = rb + sr;
            int gr = m0 + r; gr = gr < M ? gr : M - 1;
            const u16* gp = A + (size_t)gr * K + k0 + ((sl ^ sr) << 3);
            __builtin_amdgcn_global_load_lds(
                (const __attribute__((address_space(1))) void*)gp,
                (__attribute__((address_space(3))) void*)(Ad + rb * 64), 16, 0, 0);
        }
#pragma unroll
        for (int i = 0; i < NF; ++i) {
            int rb = wave * (BN / 4) + i * 8;
            int r = rb + sr;
            const u16* gp = WT + (size_t)(n0 + r) * K + k0 + ((sl ^ sr) << 3);
            __builtin_amdgcn_global_load_lds(
                (const __attribute__((address_space(1))) void*)gp,
                (__attribute__((address_space(3))) void*)(Bd + rb * 64), 16, 0, 0);
        }
    };

    auto compute = [&](const u16* Ab, const u16* Bb) {
#pragma unroll
        for (int kx = 0; kx < 2; ++kx) {
            bf16x8 af[2], bfr[NF];
#pragma unroll
            for (int mf = 0; mf < 2; ++mf) {
                int r = wm + mf * 16 + (lane & 15);
                int slot = (lane >> 4) + kx * 4;
                af[mf] = __builtin_bit_cast(bf16x8,
                    *(const u16x8*)(Ab + r * 64 + ((slot ^ (r & 7)) << 3)));
            }
#pragma unroll
            for (int nf = 0; nf < NF; ++nf) {
                int r = wn + nf * 16 + (lane & 15);
                int slot = (lane >> 4) + kx * 4;
                bfr[nf] = __builtin_bit_cast(bf16x8,
                    *(const u16x8*)(Bb + r * 64 + ((slot ^ (r & 7)) << 3)));
            }
#pragma unroll
            for (int mf = 0; mf < 2; ++mf)
#pragma unroll
                for (int nf = 0; nf < NF; ++nf)
                    acc[mf][nf] = __builtin_amdgcn_mfma_f32_16x16x32_bf16(
                        af[mf], bfr[nf], acc[mf][nf], 0, 0, 0);
        }
    };

    const int nt = K >> 6;
    stage(0, As0, Bs0);
    for (int t = 0; t < nt; ++t) {
        const bool pb = t & 1;
        if (t + 1 < nt) {
            stage((t + 1) << 6, pb ? As0 : As1, pb ? Bs0 : Bs1);
            __builtin_amdgcn_sched_barrier(0);
            if constexpr (BN == 128) asm volatile("s_waitcnt vmcnt(6)" ::: "memory");
            else                     asm volatile("s_waitcnt vmcnt(4)" ::: "memory");
        } else {
            asm volatile("s_waitcnt vmcnt(0)" ::: "memory");
        }
        __builtin_amdgcn_s_barrier();
        __builtin_amdgcn_sched_barrier(0);
        compute(pb ? As1 : As0, pb ? Bs1 : Bs0);
        __builtin_amdgcn_sched_barrier(0);
        __builtin_amdgcn_s_barrier();
        __builtin_amdgcn_sched_barrier(0);   // fence: next stage must not hoist above
    }

    float beta = 0.f;
    if (EPI == 2) beta = 1.f / (1.f + expf(-skipPtr[0]));

    if constexpr (OBF) {
        constexpr int CLD = BN + 8;
        u16* Ct = smem;
#pragma unroll
        for (int nf = 0; nf < NF; ++nf) {
            int col = wn + nf * 16 + (lane & 15);
            int gcol = n0 + col;
            float bs = bias[gcol];
#pragma unroll
            for (int mf = 0; mf < 2; ++mf) {
#pragma unroll
                for (int j = 0; j < 4; ++j) {
                    int row = wm + mf * 16 + (lane >> 4) * 4 + j;
                    int grow = m0 + row;
                    int gr2 = grow < M ? grow : 0;
                    float c = acc[mf][nf][j] + bs;
                    if (EPI == 1) c = fmaxf(c, 0.f);
                    if (EPI == 2) c = beta * c + (1.f - beta) * bf2f(xres[(size_t)gr2 * ldC + gcol]);
                    if (EPI == 3) c = (c > 0.f) ? c : 0.2f * c;
                    Ct[row * CLD + col] = f2bf(c);
                }
            }
        }
        __syncthreads();   // full lgkm drain + compiler fence: cross-wave LDS handoff
        // coalesced write: 4 threads per row, BN/4 u16 each
        int row = tid >> 2, c0 = (tid & 3) * (BN / 4);
        int grow = m0 + row;
        if (grow < M) {
            u16* dst = (u16*)Cv + (size_t)grow * ldC + n0 + c0;
            const u16* src = Ct + row * CLD + c0;
#pragma unroll
            for (int i = 0; i < BN / 32; ++i)
                *(u16x8*)(dst + i * 8) = *(const u16x8*)(src + i * 8);
        }
    } else {
#pragma unroll
        for (int nf = 0; nf < NF; ++nf) {
            int gcol = n0 + wn + nf * 16 + (lane & 15);
            float bs = bias[gcol];
#pragma unroll
            for (int mf = 0; mf < 2; ++mf) {
#pragma unroll
                for (int j = 0; j < 4; ++j) {
                    int grow = m0 + wm + mf * 16 + (lane >> 4) * 4 + j;
                    if (grow >= M) continue;
                    float c = acc[mf][nf][j] + bs;
                    if (EPI == 1) c = fmaxf(c, 0.f);
                    if (EPI == 3) c = (c > 0.f) ? c : 0.2f * c;
                    ((float*)Cv)[(size_t)grow * ldC + gcol] = c;
                }
            }
        }
    }
}

// ------------------------- CSR build -------------------------
__global__ void hist_kernel(const int* __restrict__ di, unsigned* __restrict__ counts, int E) {
    int e = blockIdx.x * blockDim.x + threadIdx.x;
    if (e < E) atomicAdd(&counts[di[e]], 1u);
}

__global__ __launch_bounds__(256) void scan_blocks(
    const unsigned* __restrict__ counts, unsigned* __restrict__ pref,
    unsigned* __restrict__ bsum, int N)
{
    __shared__ unsigned tmp[256];
    int i = blockIdx.x * 256 + threadIdx.x;
    unsigned v = (i < N) ? counts[i] : 0u;
    tmp[threadIdx.x] = v;
    __syncthreads();
    for (int off = 1; off < 256; off <<= 1) {
        unsigned t = (threadIdx.x >= off) ? tmp[threadIdx.x - off] : 0u;
        __syncthreads();
        tmp[threadIdx.x] += t;
        __syncthreads();
    }
    if (i < N) pref[i] = tmp[threadIdx.x] - v;  // exclusive
    if (threadIdx.x == 255) bsum[blockIdx.x] = tmp[255];
}

__global__ __launch_bounds__(256) void scan_top(unsigned* __restrict__ bsum, int NB) {
    __shared__ unsigned tmp[256];
    unsigned v = (threadIdx.x < NB) ? bsum[threadIdx.x] : 0u;
    tmp[threadIdx.x] = v;
    __syncthreads();
    for (int off = 1; off < 256; off <<= 1) {
        unsigned t = (threadIdx.x >= off) ? tmp[threadIdx.x - off] : 0u;
        __syncthreads();
        tmp[threadIdx.x] += t;
        __syncthreads();
    }
    if (threadIdx.x < NB) bsum[threadIdx.x] = tmp[threadIdx.x] - v;  // exclusive
}

__global__ void scan_add(unsigned* __restrict__ pref, const unsigned* __restrict__ bsum,
                         unsigned* __restrict__ cursor, int N) {
    int i = blockIdx.x * 256 + threadIdx.x;
    if (i < N) {
        unsigned s = pref[i] + bsum[blockIdx.x];
        pref[i] = s;
        cursor[i] = s;
    }
}

__global__ void place_kernel(const int* __restrict__ di, unsigned* __restrict__ cursor,
                             unsigned* __restrict__ eid, int E) {
    int e = blockIdx.x * blockDim.x + threadIdx.x;
    if (e < E) {
        unsigned p = atomicAdd(&cursor[di[e]], 1u);
        eid[p] = (unsigned)e;
    }
}

// ------------------------- fused edge gather (R5-proven dataflow) -------------------------
// One wave per dst node. lane -> (h = lane>>3, d0 = (lane&7)*4); 8-lane head reduce.
// q rows stride ldq (q section of dst qkv); kr/vr rows stride ldkv (sections of src qkv).
__global__ __launch_bounds__(256) void edge_gather(
    const u16* __restrict__ q, int ldq,
    const u16* __restrict__ kr, const u16* __restrict__ vr, int ldkv,
    const int* __restrict__ si, const unsigned* __restrict__ rowstart,
    const unsigned* __restrict__ counts, const unsigned* __restrict__ eid,
    u16* __restrict__ agg, int Ndst)
{
    int n = blockIdx.x * 4 + (threadIdx.x >> 6);
    if (n >= Ndst) return;
    int lane = threadIdx.x & 63;
    unsigned start = rowstart[n], deg = counts[n];

    const ushort4 qv = *(const ushort4*)&q[(size_t)n * ldq + lane * 4];
    float q0 = bf2f(qv.x), q1 = bf2f(qv.y), q2 = bf2f(qv.z), q3 = bf2f(qv.w);

    float m = -INFINITY, s = 0.f;
    float a0 = 0.f, a1 = 0.f, a2 = 0.f, a3 = 0.f;
    for (unsigned j = 0; j < deg; ++j) {
        int e = (int)eid[start + j];
        int src = si[e];
        const ushort4 kv = *(const ushort4*)&kr[(size_t)src * ldkv + lane * 4];
        float p = q0 * bf2f(kv.x) + q1 * bf2f(kv.y) + q2 * bf2f(kv.z) + q3 * bf2f(kv.w);
        p += __shfl_xor(p, 1);
        p += __shfl_xor(p, 2);
        p += __shfl_xor(p, 4);
        const ushort4 vv = *(const ushort4*)&vr[(size_t)src * ldkv + lane * 4];
        float mn = fmaxf(m, p);
        float sc = __expf(m - mn);      // 0 on first iteration
        float wv = __expf(p - mn);
        s = s * sc + wv;
        a0 = a0 * sc + wv * bf2f(vv.x);
        a1 = a1 * sc + wv * bf2f(vv.y);
        a2 = a2 * sc + wv * bf2f(vv.z);
        a3 = a3 * sc + wv * bf2f(vv.w);
        m = mn;
    }
    float inv = 1.f / (s + 1e-16f);
    float o[4] = {a0 * inv, a1 * inv, a2 * inv, a3 * inv};
    ushort4 ov;
    u16* op = (u16*)&ov;
#pragma unroll
    for (int j = 0; j < 4; ++j) {
        float x = o[j];
        float g = 0.5f * x * (1.f + erff(x * 0.70710678118654752f));
        op[j] = f2bf(g);
    }
    *(ushort4*)&agg[(size_t)n * 256 + lane * 4] = ov;
}

// ------------------------- misc -------------------------
__global__ __launch_bounds__(256) void norm_rows(float* __restrict__ y, int M) {
    int row = blockIdx.x * 4 + (threadIdx.x >> 6);
    int lane = threadIdx.x & 63;
    if (row >= M) return;
    float v = y[(size_t)row * 64 + lane];
    float s = v * v;
#pragma unroll
    for (int off = 1; off < 64; off <<= 1) s += __shfl_xor(s, off);
    float n = sqrtf(s);
    y[(size_t)row * 64 + lane] = v / fmaxf(n, 1e-12f);
}

// ------------------------- launch -------------------------
extern "C" void kernel_launch(void* const* d_in, const int* in_sizes, int n_in,
                              void* d_out, int out_size, void* d_ws, size_t ws_size,
                              hipStream_t stream)
{
    const float* x_trans = (const float*)d_in[0];
    const float* x_cc    = (const float*)d_in[1];
    const int* src_c2t   = (const int*)d_in[2];
    const int* dst_c2t   = (const int*)d_in[3];
    const int* src_t2c   = (const int*)d_in[4];
    const int* dst_t2c   = (const int*)d_in[5];
    const float* W_in = (const float*)d_in[6];
    const float* b_in = (const float*)d_in[7];
    const float* Wk   = (const float*)d_in[8];
    const float* bk   = (const float*)d_in[9];
    const float* Wq   = (const float*)d_in[10];
    const float* bq   = (const float*)d_in[11];
    const float* Wv   = (const float*)d_in[12];
    const float* bv   = (const float*)d_in[13];
    const float* Wa   = (const float*)d_in[14];
    const float* ba   = (const float*)d_in[15];
    const float* a_rel = (const float*)d_in[16];
    const float* m_rel = (const float*)d_in[17];
    const float* p_rel = (const float*)d_in[18];
    const float* skip  = (const float*)d_in[19];
    const float* W_out = (const float*)d_in[20];
    const float* b_out = (const float*)d_in[21];

    // ---------- workspace layout (~248 MB) ----------
    char* w = (char*)d_ws;
    auto alloc = [&](size_t bytes) { char* p = w; w += (bytes + 255) & ~(size_t)255; return p; };
    u16* xs0  = (u16*)alloc((size_t)NTN * 256 * 2);
    u16* xs1  = (u16*)alloc((size_t)NCN * 256 * 2);
    u16* xin0 = (u16*)alloc((size_t)NTN * 64 * 2);
    u16* xin1 = (u16*)alloc((size_t)NCN * 64 * 2);
    u16* qkv0 = (u16*)alloc((size_t)NTN * 768 * 2);   // 92.2 MB
    u16* qkv1 = (u16*)alloc((size_t)NCN * 768 * 2);   // 46.1 MB
    u16* agg0 = (u16*)alloc((size_t)NTN * 256 * 2);
    u16* agg1 = (u16*)alloc((size_t)NCN * 256 * 2);
    u16* WinT = (u16*)alloc((size_t)2 * 16384 * 2);
    u16* WqkvT= (u16*)alloc((size_t)4 * 196608 * 2);  // [768][256] per lt
    u16* WaT  = (u16*)alloc((size_t)4 * 65536 * 2);
    u16* WoutT= (u16*)alloc((size_t)16384 * 2);
    float* Wf2 = (float*)alloc((size_t)2 * 65536 * 4);
    float* bqkv = (float*)alloc((size_t)4 * 768 * 4);
    unsigned* countsT   = (unsigned*)alloc((size_t)NTN * 4);
    unsigned* rowstartT = (unsigned*)alloc((size_t)NTN * 4);
    unsigned* cursorT   = (unsigned*)alloc((size_t)NTN * 4);
    unsigned* eidT      = (unsigned*)alloc((size_t)NED * 4);
    unsigned* countsC   = (unsigned*)alloc((size_t)NCN * 4);
    unsigned* rowstartC = (unsigned*)alloc((size_t)NCN * 4);
    unsigned* cursorC   = (unsigned*)alloc((size_t)NCN * 4);
    unsigned* eidC      = (unsigned*)alloc((size_t)NED * 4);
    unsigned* bsum      = (unsigned*)alloc((size_t)256 * 4);
    (void)ws_size; (void)in_sizes; (void)n_in; (void)out_size;

    // ---------- CSR builds (shared by both layers) ----------
    {
        const int EB = (NED + 255) / 256;
        int NBt = (NTN + 255) / 256;
        fill_u32<<<256, 256, 0, stream>>>(countsT, 0u, NTN);
        hist_kernel<<<EB, 256, 0, stream>>>(dst_c2t, countsT, NED);
        scan_blocks<<<NBt, 256, 0, stream>>>(countsT, rowstartT, bsum, NTN);
        scan_top<<<1, 256, 0, stream>>>(bsum, NBt);
        scan_add<<<NBt, 256, 0, stream>>>(rowstartT, bsum, cursorT, NTN);
        place_kernel<<<EB, 256, 0, stream>>>(dst_c2t, cursorT, eidT, NED);
        int NBc = (NCN + 255) / 256;
        fill_u32<<<256, 256, 0, stream>>>(countsC, 0u, NCN);
        hist_kernel<<<EB, 256, 0, stream>>>(dst_t2c, countsC, NED);
        scan_blocks<<<NBc, 256, 0, stream>>>(countsC, rowstartC, bsum, NCN);
        scan_top<<<1, 256, 0, stream>>>(bsum, NBc);
        scan_add<<<NBc, 256, 0, stream>>>(rowstartC, bsum, cursorC, NCN);
        place_kernel<<<EB, 256, 0, stream>>>(dst_t2c, cursorC, eidC, NED);
    }

    // ---------- weight prep: fuse + convert/transpose to bf16 ----------
    // WqkvT[lt] rows: [0,256)=Wq^T, [256,512)=Wkf^T, [512,768)=Wvf^T; bias bqkv[lt*768..]
    for (int l = 0; l < 2; ++l)
        for (int t = 0; t < 2; ++t) {
            int r = (t == 1) ? 0 : 1;           // relation where type t is the SOURCE
            int lt = l * 2 + t, lr = l * 2 + r;
            fuse_weights<<<256, 256, 0, stream>>>(
                Wk + (size_t)lt * 65536, bk + (size_t)lt * 256,
                Wv + (size_t)lt * 65536, bv + (size_t)lt * 256,
                a_rel + (size_t)lr * 8192, m_rel + (size_t)lr * 8192, p_rel + (size_t)lr * 8,
                Wf2, bqkv + lt * 768 + 256, Wf2 + 65536, bqkv + lt * 768 + 512);
            copy256<<<1, 256, 0, stream>>>(bq + (size_t)lt * 256, bqkv + lt * 768);
            convT<<<64, 256, 0, stream>>>(Wq + (size_t)lt * 65536, WqkvT + (size_t)lt * 196608, 256, 256);
            convT<<<64, 256, 0, stream>>>(Wf2,         WqkvT + (size_t)lt * 196608 + 65536,  256, 256);
            convT<<<64, 256, 0, stream>>>(Wf2 + 65536, WqkvT + (size_t)lt * 196608 + 131072, 256, 256);
            convT<<<64, 256, 0, stream>>>(Wa + (size_t)lt * 65536, WaT + (size_t)lt * 65536, 256, 256);
        }
    convT<<<16, 256, 0, stream>>>(W_in,         WinT,         64, 256);
    convT<<<16, 256, 0, stream>>>(W_in + 16384, WinT + 16384, 64, 256);
    convT<<<16, 256, 0, stream>>>(W_out, WoutT, 256, 64);
    f32_to_bf16<<<1024, 256, 0, stream>>>(x_trans, xin0, NTN * 64 / 4);
    f32_to_bf16<<<1024, 256, 0, stream>>>(x_cc,    xin1, NCN * 64 / 4);

    const int GT = (NTN + 63) / 64, GC = (NCN + 63) / 64;   // 938 / 469

    // ---------- input projections + relu ----------
    gemm_mfma<1, 128, true><<<GT * 2, 256, 0, stream>>>(xin0, WinT, b_in, xs0, NTN, 64, 256, 2, nullptr, nullptr);
    gemm_mfma<1, 128, true><<<GC * 2, 256, 0, stream>>>(xin1, WinT + 16384, b_in + 256, xs1, NCN, 64, 256, 2, nullptr, nullptr);

    for (int l = 0; l < 2; ++l) {
        size_t lt0 = (size_t)(l * 2 + 0), lt1 = (size_t)(l * 2 + 1);

        // fused q|k|v projections (one GEMM per node type)
        gemm_mfma<0, 128, true><<<GT * 6, 256, 0, stream>>>(xs0, WqkvT + lt0 * 196608, bqkv + lt0 * 768, qkv0, NTN, 256, 768, 6, nullptr, nullptr);
        gemm_mfma<0, 128, true><<<GC * 6, 256, 0, stream>>>(xs1, WqkvT + lt1 * 196608, bqkv + lt1 * 768, qkv1, NCN, 256, 768, 6, nullptr, nullptr);

        // edge phases (both read pre-update qkv buffers)
        edge_gather<<<(NTN + 3) / 4, 256, 0, stream>>>(qkv0, 768, qkv1 + 256, qkv1 + 512, 768,
                                                       src_c2t, rowstartT, countsT, eidT, agg0, NTN);
        edge_gather<<<(NCN + 3) / 4, 256, 0, stream>>>(qkv1, 768, qkv0 + 256, qkv0 + 512, 768,
                                                       src_t2c, rowstartC, countsC, eidC, agg1, NCN);

        // skip-blend output transforms (in-place xs updates)
        gemm_mfma<2, 128, true><<<GT * 2, 256, 0, stream>>>(agg0, WaT + lt0 * 65536, ba + lt0 * 256, xs0, NTN, 256, 256, 2, xs0, skip + l * 2 + 0);
        gemm_mfma<2, 128, true><<<GC * 2, 256, 0, stream>>>(agg1, WaT + lt1 * 65536, ba + lt1 * 256, xs1, NCN, 256, 256, 2, xs1, skip + l * 2 + 1);
    }

    // ---------- final projection + leakyrelu + row L2 normalize ----------
    {
        float* y = (float*)d_out;
        gemm_mfma<3, 64, false><<<GT, 256, 0, stream>>>(xs0, WoutT, b_out, y, NTN, 256, 64, 1, nullptr, nullptr);
        norm_rows<<<NTN / 4, 256, 0, stream>>>(y, NTN);
    }
}

// Round 8
// 551.655 us; speedup vs baseline: 7.8502x; 1.1764x over previous
//
#include <hip/hip_runtime.h>
#include <hip/hip_bf16.h>
#include <math.h>

#define NTN 60000
#define NCN 30000
#define NED 200000
// H=8, D=32, HID=256, FIN=64

typedef unsigned short u16;
typedef __attribute__((ext_vector_type(8))) u16 u16x8;
typedef __attribute__((ext_vector_type(8))) __bf16 bf16x8;
typedef __attribute__((ext_vector_type(4))) float f32x4;

static __device__ __forceinline__ float bf2f(u16 u) {
    return __uint_as_float(((unsigned)u) << 16);
}
static __device__ __forceinline__ u16 f2bf(float f) {
    unsigned u = __float_as_uint(f);
    unsigned r = (u + 0x7fffu + ((u >> 16) & 1u)) >> 16;  // RNE
    return (u16)r;
}

// ------------------------- fill -------------------------
__global__ void fill_u32(unsigned* __restrict__ p, unsigned v, int n) {
    int i = blockIdx.x * blockDim.x + threadIdx.x;
    int stride = gridDim.x * blockDim.x;
    for (; i < n; i += stride) p[i] = v;
}

// ------------------------- conversions -------------------------
__global__ void f32_to_bf16(const float* __restrict__ in, u16* __restrict__ out, int n4) {
    int i = blockIdx.x * blockDim.x + threadIdx.x;
    int stride = gridDim.x * blockDim.x;
    for (; i < n4; i += stride) {
        float4 v = ((const float4*)in)[i];
        ushort4 o;
        o.x = f2bf(v.x); o.y = f2bf(v.y); o.z = f2bf(v.z); o.w = f2bf(v.w);
        ((ushort4*)out)[i] = o;
    }
}

// batched: out[m][n][k] = bf16(in[m][k][n]) with per-matrix strides.
__global__ void convTb(const float* __restrict__ in, u16* __restrict__ out,
                       int K, int N, int inStride, int outStride, int nm) {
    int idx = blockIdx.x * blockDim.x + threadIdx.x;
    int per = N * (K >> 2);
    int total = per * nm;
    if (idx >= total) return;
    int mat = idx / per, rem = idx - mat * per;
    int k4 = rem / N, n = rem - k4 * N;
    int k = k4 * 4;
    const float* src = in + (size_t)mat * inStride;
    u16* dst = out + (size_t)mat * outStride;
    ushort4 o;
    o.x = f2bf(src[(size_t)(k + 0) * N + n]);
    o.y = f2bf(src[(size_t)(k + 1) * N + n]);
    o.z = f2bf(src[(size_t)(k + 2) * N + n]);
    o.w = f2bf(src[(size_t)(k + 3) * N + n]);
    *(ushort4*)(dst + (size_t)n * K + k) = o;
}

__global__ void copy_bq(const float* __restrict__ bq, float* __restrict__ bqkv) {
    int lt = blockIdx.x;
    bqkv[lt * 768 + threadIdx.x] = bq[lt * 256 + threadIdx.x];
}

// --------------------- weight fusion (all 4 lt in one launch) ---------------------
// Wkf[c, h*32+e] = p[h]/sqrt(32) * sum_d Wk[c,h*32+d]*ar[h,d,e];  Wvf with mr, no scale.
__global__ __launch_bounds__(256) void fuse_weights(
    const float* __restrict__ Wk, const float* __restrict__ bk,
    const float* __restrict__ Wv, const float* __restrict__ bv,
    const float* __restrict__ a_rel, const float* __restrict__ m_rel,
    const float* __restrict__ p_rel,
    float* __restrict__ Wf2, float* __restrict__ bqkv)
{
    __shared__ float kw[256], vw[256];
    const int c = blockIdx.x, lt = blockIdx.y, tid = threadIdx.x;
    const int l = lt >> 1, t = lt & 1;
    const int lr = l * 2 + (t == 1 ? 0 : 1);     // relation where type t is the SOURCE
    const float* WkP = Wk + (size_t)lt * 65536;
    const float* WvP = Wv + (size_t)lt * 65536;
    const float* ar = a_rel + (size_t)lr * 8192;
    const float* mr = m_rel + (size_t)lr * 8192;
    kw[tid] = WkP[c * 256 + tid];
    vw[tid] = WvP[c * 256 + tid];
    __syncthreads();
    const int h = tid >> 5, e = tid & 31;
    const float s = p_rel[lr * 8 + h] * 0.17677669529663687f;  // 1/sqrt(32)
    float ak = 0.f, av = 0.f;
#pragma unroll 8
    for (int d = 0; d < 32; ++d) {
        ak += kw[h * 32 + d] * ar[h * 1024 + d * 32 + e];
        av += vw[h * 32 + d] * mr[h * 1024 + d * 32 + e];
    }
    float* WkfP = Wf2 + (size_t)lt * 131072;
    WkfP[c * 256 + tid] = ak * s;
    WkfP[65536 + c * 256 + tid] = av;
    if (c == 0) {
        const float* bkP = bk + (size_t)lt * 256;
        const float* bvP = bv + (size_t)lt * 256;
        float bka = 0.f, bva = 0.f;
#pragma unroll 8
        for (int d = 0; d < 32; ++d) {
            bka += bkP[h * 32 + d] * ar[h * 1024 + d * 32 + e];
            bva += bvP[h * 32 + d] * mr[h * 1024 + d * 32 + e];
        }
        bqkv[lt * 768 + 256 + tid] = bka * s;
        bqkv[lt * 768 + 512 + tid] = bva;
    }
}

// ------------------------- MFMA GEMM -------------------------
// C[M, NY*BN] = epi(A[M,K](bf16) @ WT[.,K]^T(bf16) + bias).
// 64 x BN tile, BK=64, 4 waves (2x2), double-buffered LDS, counted vmcnt.
// BN=64 -> 32KB LDS -> 5 blocks/CU for latency hiding.
template <int EPI, int BN, bool OBF>
__global__ __launch_bounds__(256) void gemm_mfma(
    const u16* __restrict__ A, const u16* __restrict__ WT,
    const float* __restrict__ bias, void* __restrict__ Cv,
    int M, int K, int ldC, int NY,
    const u16* __restrict__ xres, const float* __restrict__ skipPtr)
{
    constexpr int ASZ = 64 * 64;
    constexpr int BSZ = BN * 64;
    constexpr int NF = BN / 32;          // n-frags per wave (and B stage insts per wave)
    __shared__ u16 smem[2 * (ASZ + BSZ)];
    u16* As0 = smem;             u16* Bs0 = smem + ASZ;
    u16* As1 = smem + ASZ + BSZ; u16* Bs1 = As1 + ASZ;

    // bijective XCD swizzle (m204), then y-inner decode
    const int nwg = gridDim.x;
    const int bid = blockIdx.x;
    const int q8 = nwg >> 3, r8 = nwg & 7;
    const int xcd = bid & 7, pos = bid >> 3;
    const int lbid = (xcd < r8) ? xcd * (q8 + 1) + pos
                                : r8 * (q8 + 1) + (xcd - r8) * q8 + pos;
    const int bx = lbid / NY, by = lbid - bx * NY;
    const int m0 = bx * 64, n0 = by * BN;

    const int tid = threadIdx.x;
    const int wave = tid >> 6, lane = tid & 63;
    const int wm = (wave >> 1) * 32, wn = (wave & 1) * (BN / 2);
    f32x4 acc[2][NF];
#pragma unroll
    for (int i = 0; i < 2; ++i)
#pragma unroll
        for (int j = 0; j < NF; ++j) acc[i][j] = (f32x4){0.f, 0.f, 0.f, 0.f};

    const int sr = lane >> 3;   // row within 8-row staging group
    const int sl = lane & 7;    // linear 16B slot

    auto stage = [&](int k0, u16* Ad, u16* Bd) {
#pragma unroll
        for (int i = 0; i < 2; ++i) {
            int rb = wave * 16 + i * 8;
            int r = rb + sr;
            int gr = m0 + r; gr = gr < M ? gr : M - 1;
            const u16* gp = A + (size_t)gr * K + k0 + ((sl ^ sr) << 3);
            __builtin_amdgcn_global_load_lds(
                (const __attribute__((address_space(1))) void*)gp,
                (__attribute__((address_space(3))) void*)(Ad + rb * 64), 16, 0, 0);
        }
#pragma unroll
        for (int i = 0; i < NF; ++i) {
            int rb = wave * (BN / 4) + i * 8;
            int r = rb + sr;
            const u16* gp = WT + (size_t)(n0 + r) * K + k0 + ((sl ^ sr) << 3);
            __builtin_amdgcn_global_load_lds(
                (const __attribute__((address_space(1))) void*)gp,
                (__attribute__((address_space(3))) void*)(Bd + rb * 64), 16, 0, 0);
        }
    };

    auto compute = [&](const u16* Ab, const u16* Bb) {
#pragma unroll
        for (int kx = 0; kx < 2; ++kx) {
            bf16x8 af[2], bfr[NF];
#pragma unroll
            for (int mf = 0; mf < 2; ++mf) {
                int r = wm + mf * 16 + (lane & 15);
                int slot = (lane >> 4) + kx * 4;
                af[mf] = __builtin_bit_cast(bf16x8,
                    *(const u16x8*)(Ab + r * 64 + ((slot ^ (r & 7)) << 3)));
            }
#pragma unroll
            for (int nf = 0; nf < NF; ++nf) {
                int r = wn + nf * 16 + (lane & 15);
                int slot = (lane >> 4) + kx * 4;
                bfr[nf] = __builtin_bit_cast(bf16x8,
                    *(const u16x8*)(Bb + r * 64 + ((slot ^ (r & 7)) << 3)));
            }
#pragma unroll
            for (int mf = 0; mf < 2; ++mf)
#pragma unroll
                for (int nf = 0; nf < NF; ++nf)
                    acc[mf][nf] = __builtin_amdgcn_mfma_f32_16x16x32_bf16(
                        af[mf], bfr[nf], acc[mf][nf], 0, 0, 0);
        }
    };

    const int nt = K >> 6;
    stage(0, As0, Bs0);
    for (int t = 0; t < nt; ++t) {
        const bool pb = t & 1;
        if (t + 1 < nt) {
            stage((t + 1) << 6, pb ? As0 : As1, pb ? Bs0 : Bs1);
            __builtin_amdgcn_sched_barrier(0);
            if constexpr (BN == 128) asm volatile("s_waitcnt vmcnt(6)" ::: "memory");
            else                     asm volatile("s_waitcnt vmcnt(4)" ::: "memory");
        } else {
            asm volatile("s_waitcnt vmcnt(0)" ::: "memory");
        }
        __builtin_amdgcn_s_barrier();
        __builtin_amdgcn_sched_barrier(0);
        compute(pb ? As1 : As0, pb ? Bs1 : Bs0);
        __builtin_amdgcn_sched_barrier(0);
        __builtin_amdgcn_s_barrier();
        __builtin_amdgcn_sched_barrier(0);   // fence: next stage must not hoist above
    }

    float beta = 0.f;
    if (EPI == 2) beta = 1.f / (1.f + expf(-skipPtr[0]));

    if constexpr (OBF) {
        constexpr int CLD = BN + 8;
        u16* Ct = smem;
#pragma unroll
        for (int nf = 0; nf < NF; ++nf) {
            int col = wn + nf * 16 + (lane & 15);
            int gcol = n0 + col;
            float bs = bias[gcol];
#pragma unroll
            for (int mf = 0; mf < 2; ++mf) {
#pragma unroll
                for (int j = 0; j < 4; ++j) {
                    int row = wm + mf * 16 + (lane >> 4) * 4 + j;
                    int grow = m0 + row;
                    int gr2 = grow < M ? grow : 0;
                    float c = acc[mf][nf][j] + bs;
                    if (EPI == 1) c = fmaxf(c, 0.f);
                    if (EPI == 2) c = beta * c + (1.f - beta) * bf2f(xres[(size_t)gr2 * ldC + gcol]);
                    if (EPI == 3) c = (c > 0.f) ? c : 0.2f * c;
                    Ct[row * CLD + col] = f2bf(c);
                }
            }
        }
        __syncthreads();   // full lgkm drain + compiler fence: cross-wave LDS handoff
        // coalesced write: 4 threads per row, BN/4 u16 each
        int row = tid >> 2, c0 = (tid & 3) * (BN / 4);
        int grow = m0 + row;
        if (grow < M) {
            u16* dst = (u16*)Cv + (size_t)grow * ldC + n0 + c0;
            const u16* src = Ct + row * CLD + c0;
#pragma unroll
            for (int i = 0; i < BN / 32; ++i)
                *(u16x8*)(dst + i * 8) = *(const u16x8*)(src + i * 8);
        }
    } else {
#pragma unroll
        for (int nf = 0; nf < NF; ++nf) {
            int gcol = n0 + wn + nf * 16 + (lane & 15);
            float bs = bias[gcol];
#pragma unroll
            for (int mf = 0; mf < 2; ++mf) {
#pragma unroll
                for (int j = 0; j < 4; ++j) {
                    int grow = m0 + wm + mf * 16 + (lane >> 4) * 4 + j;
                    if (grow >= M) continue;
                    float c = acc[mf][nf][j] + bs;
                    if (EPI == 1) c = fmaxf(c, 0.f);
                    if (EPI == 3) c = (c > 0.f) ? c : 0.2f * c;
                    ((float*)Cv)[(size_t)grow * ldC + gcol] = c;
                }
            }
        }
    }
}

// ------------------------- CSR build -------------------------
__global__ void hist_kernel(const int* __restrict__ di, unsigned* __restrict__ counts, int E) {
    int e = blockIdx.x * blockDim.x + threadIdx.x;
    if (e < E) atomicAdd(&counts[di[e]], 1u);
}

__global__ __launch_bounds__(256) void scan_blocks(
    const unsigned* __restrict__ counts, unsigned* __restrict__ pref,
    unsigned* __restrict__ bsum, int N)
{
    __shared__ unsigned tmp[256];
    int i = blockIdx.x * 256 + threadIdx.x;
    unsigned v = (i < N) ? counts[i] : 0u;
    tmp[threadIdx.x] = v;
    __syncthreads();
    for (int off = 1; off < 256; off <<= 1) {
        unsigned t = (threadIdx.x >= off) ? tmp[threadIdx.x - off] : 0u;
        __syncthreads();
        tmp[threadIdx.x] += t;
        __syncthreads();
    }
    if (i < N) pref[i] = tmp[threadIdx.x] - v;  // exclusive
    if (threadIdx.x == 255) bsum[blockIdx.x] = tmp[255];
}

__global__ __launch_bounds__(256) void scan_top(unsigned* __restrict__ bsum, int NB) {
    __shared__ unsigned tmp[256];
    unsigned v = (threadIdx.x < NB) ? bsum[threadIdx.x] : 0u;
    tmp[threadIdx.x] = v;
    __syncthreads();
    for (int off = 1; off < 256; off <<= 1) {
        unsigned t = (threadIdx.x >= off) ? tmp[threadIdx.x - off] : 0u;
        __syncthreads();
        tmp[threadIdx.x] += t;
        __syncthreads();
    }
    if (threadIdx.x < NB) bsum[threadIdx.x] = tmp[threadIdx.x] - v;  // exclusive
}

__global__ void scan_add(unsigned* __restrict__ pref, const unsigned* __restrict__ bsum,
                         unsigned* __restrict__ cursor, int N) {
    int i = blockIdx.x * 256 + threadIdx.x;
    if (i < N) {
        unsigned s = pref[i] + bsum[blockIdx.x];
        pref[i] = s;
        cursor[i] = s;
    }
}

__global__ void place_kernel(const int* __restrict__ di, unsigned* __restrict__ cursor,
                             unsigned* __restrict__ eid, int E) {
    int e = blockIdx.x * blockDim.x + threadIdx.x;
    if (e < E) {
        unsigned p = atomicAdd(&cursor[di[e]], 1u);
        eid[p] = (unsigned)e;
    }
}

// ------------------------- fused edge gather (both relations, one launch) -------------------------
// One wave per dst node. qkv rows: [q(256) | k(256) | v(256)] u16, ld=768.
// Single u16x8 load per edge covers the contiguous 1KB k|v span: lanes 0-31 K,
// lanes 32-63 V. 4 lanes per head (16B each): quad shfl reduce gives the dot;
// mirror-shfl broadcasts it to the V half. Online softmax in registers;
// upper lanes gelu + store the bf16 agg row. Next edge software-prefetched.
#define TBLK ((NTN + 3) / 4)
__global__ __launch_bounds__(256) void edge_gather2(
    const u16* __restrict__ qkvT, const u16* __restrict__ qkvC,
    const int* __restrict__ siT, const unsigned* __restrict__ rsT,
    const unsigned* __restrict__ cntT, const unsigned* __restrict__ eidT,
    const int* __restrict__ siC, const unsigned* __restrict__ rsC,
    const unsigned* __restrict__ cntC, const unsigned* __restrict__ eidC,
    u16* __restrict__ aggT, u16* __restrict__ aggC)
{
    const int b = blockIdx.x;
    const bool isT = b < TBLK;
    const int n = (isT ? b : b - TBLK) * 4 + (threadIdx.x >> 6);
    const int Ndst = isT ? NTN : NCN;
    if (n >= Ndst) return;
    const u16* qkv_d = isT ? qkvT : qkvC;
    const u16* qkv_s = isT ? qkvC : qkvT;
    const int* si = isT ? siT : siC;
    const unsigned* rs = isT ? rsT : rsC;
    const unsigned* cnt = isT ? cntT : cntC;
    const unsigned* eid = isT ? eidT : eidC;
    u16* agg = isT ? aggT : aggC;

    const int lane = threadIdx.x & 63;
    const int lq = lane & 31;
    const unsigned start = rs[n], deg = cnt[n];

    if (deg == 0) {
        if (lane >= 32)
            *(u16x8*)&agg[(size_t)n * 256 + lq * 8] = (u16x8){0, 0, 0, 0, 0, 0, 0, 0};
        return;
    }

    u16x8 qv = *(const u16x8*)&qkv_d[(size_t)n * 768 + lq * 8];
    float qf[8];
#pragma unroll
    for (int i = 0; i < 8; ++i) qf[i] = bf2f(qv[i]);

    const u16* kvb = qkv_s + 256;  // contiguous k|v span of src rows
    float m = -INFINITY, s = 0.f;
    float acc[8] = {0.f, 0.f, 0.f, 0.f, 0.f, 0.f, 0.f, 0.f};

    int s0 = si[(int)eid[start]];
    u16x8 row = *(const u16x8*)&kvb[(size_t)s0 * 768 + lane * 8];

    for (unsigned j = 0;; ++j) {
        u16x8 row_n;
        if (j + 1 < deg) {
            int s1 = si[(int)eid[start + j + 1]];
            row_n = *(const u16x8*)&kvb[(size_t)s1 * 768 + lane * 8];
        }
        float rf[8];
#pragma unroll
        for (int i = 0; i < 8; ++i) rf[i] = bf2f(row[i]);
        float p = qf[0] * rf[0] + qf[1] * rf[1] + qf[2] * rf[2] + qf[3] * rf[3]
                + qf[4] * rf[4] + qf[5] * rf[5] + qf[6] * rf[6] + qf[7] * rf[7];
        p += __shfl_xor(p, 1);
        p += __shfl_xor(p, 2);
        p = __shfl(p, lq);              // broadcast head-dot to the V half
        float mn = fmaxf(m, p);
        float sc = __expf(m - mn);      // 0 on first iteration (m = -inf)
        float wv = __expf(p - mn);
        s = s * sc + wv;
#pragma unroll
        for (int i = 0; i < 8; ++i) acc[i] = acc[i] * sc + wv * rf[i];
        m = mn;
        if (j + 1 >= deg) break;
        row = row_n;
    }

    if (lane >= 32) {
        float inv = 1.f / (s + 1e-16f);
        u16x8 ov;
#pragma unroll
        for (int i = 0; i < 8; ++i) {
            float x = acc[i] * inv;
            float g = 0.5f * x * (1.f + erff(x * 0.70710678118654752f));
            ov[i] = f2bf(g);
        }
        *(u16x8*)&agg[(size_t)n * 256 + lq * 8] = ov;
    }
}

// ------------------------- misc -------------------------
__global__ __launch_bounds__(256) void norm_rows(float* __restrict__ y, int M) {
    int row = blockIdx.x * 4 + (threadIdx.x >> 6);
    int lane = threadIdx.x & 63;
    if (row >= M) return;
    float v = y[(size_t)row * 64 + lane];
    float s = v * v;
#pragma unroll
    for (int off = 1; off < 64; off <<= 1) s += __shfl_xor(s, off);
    float n = sqrtf(s);
    y[(size_t)row * 64 + lane] = v / fmaxf(n, 1e-12f);
}

// ------------------------- launch -------------------------
extern "C" void kernel_launch(void* const* d_in, const int* in_sizes, int n_in,
                              void* d_out, int out_size, void* d_ws, size_t ws_size,
                              hipStream_t stream)
{
    const float* x_trans = (const float*)d_in[0];
    const float* x_cc    = (const float*)d_in[1];
    const int* src_c2t   = (const int*)d_in[2];
    const int* dst_c2t   = (const int*)d_in[3];
    const int* src_t2c   = (const int*)d_in[4];
    const int* dst_t2c   = (const int*)d_in[5];
    const float* W_in = (const float*)d_in[6];
    const float* b_in = (const float*)d_in[7];
    const float* Wk   = (const float*)d_in[8];
    const float* bk   = (const float*)d_in[9];
    const float* Wq   = (const float*)d_in[10];
    const float* bq   = (const float*)d_in[11];
    const float* Wv   = (const float*)d_in[12];
    const float* bv   = (const float*)d_in[13];
    const float* Wa   = (const float*)d_in[14];
    const float* ba   = (const float*)d_in[15];
    const float* a_rel = (const float*)d_in[16];
    const float* m_rel = (const float*)d_in[17];
    const float* p_rel = (const float*)d_in[18];
    const float* skip  = (const float*)d_in[19];
    const float* W_out = (const float*)d_in[20];
    const float* b_out = (const float*)d_in[21];

    // ---------- workspace layout (~250 MB) ----------
    char* w = (char*)d_ws;
    auto alloc = [&](size_t bytes) { char* p = w; w += (bytes + 255) & ~(size_t)255; return p; };
    u16* xs0  = (u16*)alloc((size_t)NTN * 256 * 2);
    u16* xs1  = (u16*)alloc((size_t)NCN * 256 * 2);
    u16* xin0 = (u16*)alloc((size_t)NTN * 64 * 2);
    u16* xin1 = (u16*)alloc((size_t)NCN * 64 * 2);
    u16* qkv0 = (u16*)alloc((size_t)NTN * 768 * 2);   // 92.2 MB
    u16* qkv1 = (u16*)alloc((size_t)NCN * 768 * 2);   // 46.1 MB
    u16* agg0 = (u16*)alloc((size_t)NTN * 256 * 2);
    u16* agg1 = (u16*)alloc((size_t)NCN * 256 * 2);
    u16* WinT = (u16*)alloc((size_t)2 * 16384 * 2);
    u16* WqkvT= (u16*)alloc((size_t)4 * 196608 * 2);  // [768][256] per lt
    u16* WaT  = (u16*)alloc((size_t)4 * 65536 * 2);
    u16* WoutT= (u16*)alloc((size_t)16384 * 2);
    float* Wf2 = (float*)alloc((size_t)4 * 131072 * 4); // [lt][kf|vf] f32 staging
    float* bqkv = (float*)alloc((size_t)4 * 768 * 4);
    unsigned* countsT   = (unsigned*)alloc((size_t)NTN * 4);
    unsigned* rowstartT = (unsigned*)alloc((size_t)NTN * 4);
    unsigned* cursorT   = (unsigned*)alloc((size_t)NTN * 4);
    unsigned* eidT      = (unsigned*)alloc((size_t)NED * 4);
    unsigned* countsC   = (unsigned*)alloc((size_t)NCN * 4);
    unsigned* rowstartC = (unsigned*)alloc((size_t)NCN * 4);
    unsigned* cursorC   = (unsigned*)alloc((size_t)NCN * 4);
    unsigned* eidC      = (unsigned*)alloc((size_t)NED * 4);
    unsigned* bsum      = (unsigned*)alloc((size_t)256 * 4);
    (void)ws_size; (void)in_sizes; (void)n_in; (void)out_size;

    // ---------- CSR builds (shared by both layers) ----------
    {
        const int EB = (NED + 255) / 256;
        int NBt = (NTN + 255) / 256;
        fill_u32<<<256, 256, 0, stream>>>(countsT, 0u, NTN);
        hist_kernel<<<EB, 256, 0, stream>>>(dst_c2t, countsT, NED);
        scan_blocks<<<NBt, 256, 0, stream>>>(countsT, rowstartT, bsum, NTN);
        scan_top<<<1, 256, 0, stream>>>(bsum, NBt);
        scan_add<<<NBt, 256, 0, stream>>>(rowstartT, bsum, cursorT, NTN);
        place_kernel<<<EB, 256, 0, stream>>>(dst_c2t, cursorT, eidT, NED);
        int NBc = (NCN + 255) / 256;
        fill_u32<<<256, 256, 0, stream>>>(countsC, 0u, NCN);
        hist_kernel<<<EB, 256, 0, stream>>>(dst_t2c, countsC, NED);
        scan_blocks<<<NBc, 256, 0, stream>>>(countsC, rowstartC, bsum, NCN);
        scan_top<<<1, 256, 0, stream>>>(bsum, NBc);
        scan_add<<<NBc, 256, 0, stream>>>(rowstartC, bsum, cursorC, NCN);
        place_kernel<<<EB, 256, 0, stream>>>(dst_t2c, cursorC, eidC, NED);
    }

    // ---------- weight prep: fused + batched transposes ----------
    fuse_weights<<<dim3(256, 4), 256, 0, stream>>>(Wk, bk, Wv, bv, a_rel, m_rel, p_rel, Wf2, bqkv);
    copy_bq<<<4, 256, 0, stream>>>(bq, bqkv);
    // WqkvT[lt] rows: [0,256)=Wq^T, [256,512)=Wkf^T, [512,768)=Wvf^T
    convTb<<<(4 * 16384 + 255) / 256, 256, 0, stream>>>(Wq, WqkvT, 256, 256, 65536, 196608, 4);
    convTb<<<(4 * 16384 + 255) / 256, 256, 0, stream>>>(Wf2, WqkvT + 65536, 256, 256, 131072, 196608, 4);
    convTb<<<(4 * 16384 + 255) / 256, 256, 0, stream>>>(Wf2 + 65536, WqkvT + 131072, 256, 256, 131072, 196608, 4);
    convTb<<<(4 * 16384 + 255) / 256, 256, 0, stream>>>(Wa, WaT, 256, 256, 65536, 65536, 4);
    convTb<<<(2 * 4096 + 255) / 256, 256, 0, stream>>>(W_in, WinT, 64, 256, 16384, 16384, 2);
    convTb<<<(4096 + 255) / 256, 256, 0, stream>>>(W_out, WoutT, 256, 64, 16384, 16384, 1);
    f32_to_bf16<<<1024, 256, 0, stream>>>(x_trans, xin0, NTN * 64 / 4);
    f32_to_bf16<<<1024, 256, 0, stream>>>(x_cc,    xin1, NCN * 64 / 4);

    const int GT = (NTN + 63) / 64, GC = (NCN + 63) / 64;   // 938 / 469

    // ---------- input projections + relu ----------
    gemm_mfma<1, 64, true><<<GT * 4, 256, 0, stream>>>(xin0, WinT, b_in, xs0, NTN, 64, 256, 4, nullptr, nullptr);
    gemm_mfma<1, 64, true><<<GC * 4, 256, 0, stream>>>(xin1, WinT + 16384, b_in + 256, xs1, NCN, 64, 256, 4, nullptr, nullptr);

    for (int l = 0; l < 2; ++l) {
        size_t lt0 = (size_t)(l * 2 + 0), lt1 = (size_t)(l * 2 + 1);

        // fused q|k|v projections (one GEMM per node type)
        gemm_mfma<0, 64, true><<<GT * 12, 256, 0, stream>>>(xs0, WqkvT + lt0 * 196608, bqkv + lt0 * 768, qkv0, NTN, 256, 768, 12, nullptr, nullptr);
        gemm_mfma<0, 64, true><<<GC * 12, 256, 0, stream>>>(xs1, WqkvT + lt1 * 196608, bqkv + lt1 * 768, qkv1, NCN, 256, 768, 12, nullptr, nullptr);

        // both edge phases in one launch (independent; overlap their latency)
        edge_gather2<<<TBLK + (NCN + 3) / 4, 256, 0, stream>>>(
            qkv0, qkv1,
            src_c2t, rowstartT, countsT, eidT,
            src_t2c, rowstartC, countsC, eidC,
            agg0, agg1);

        // skip-blend output transforms (in-place xs updates)
        gemm_mfma<2, 64, true><<<GT * 4, 256, 0, stream>>>(agg0, WaT + lt0 * 65536, ba + lt0 * 256, xs0, NTN, 256, 256, 4, xs0, skip + l * 2 + 0);
        gemm_mfma<2, 64, true><<<GC * 4, 256, 0, stream>>>(agg1, WaT + lt1 * 65536, ba + lt1 * 256, xs1, NCN, 256, 256, 4, xs1, skip + l * 2 + 1);
    }

    // ---------- final projection + leakyrelu + row L2 normalize ----------
    {
        float* y = (float*)d_out;
        gemm_mfma<3, 64, false><<<GT, 256, 0, stream>>>(xs0, WoutT, b_out, y, NTN, 256, 64, 1, nullptr, nullptr);
        norm_rows<<<NTN / 4, 256, 0, stream>>>(y, NTN);
    }
}

// Round 9
// 499.309 us; speedup vs baseline: 8.6732x; 1.1048x over previous
//
#include <hip/hip_runtime.h>
#include <hip/hip_bf16.h>
#include <math.h>

#define NTN 60000
#define NCN 30000
#define NED 200000
// H=8, D=32, HID=256, FIN=64

typedef unsigned short u16;
typedef __attribute__((ext_vector_type(8))) u16 u16x8;
typedef __attribute__((ext_vector_type(8))) __bf16 bf16x8;
typedef __attribute__((ext_vector_type(4))) float f32x4;

static __device__ __forceinline__ float bf2f(u16 u) {
    return __uint_as_float(((unsigned)u) << 16);
}
static __device__ __forceinline__ u16 f2bf(float f) {
    unsigned u = __float_as_uint(f);
    unsigned r = (u + 0x7fffu + ((u >> 16) & 1u)) >> 16;  // RNE
    return (u16)r;
}

// ------------------------- fill -------------------------
__global__ void fill_u32(unsigned* __restrict__ p, unsigned v, int n) {
    int i = blockIdx.x * blockDim.x + threadIdx.x;
    int stride = gridDim.x * blockDim.x;
    for (; i < n; i += stride) p[i] = v;
}

// ------------------------- conversions -------------------------
__global__ void f32_to_bf16(const float* __restrict__ in, u16* __restrict__ out, int n4) {
    int i = blockIdx.x * blockDim.x + threadIdx.x;
    int stride = gridDim.x * blockDim.x;
    for (; i < n4; i += stride) {
        float4 v = ((const float4*)in)[i];
        ushort4 o;
        o.x = f2bf(v.x); o.y = f2bf(v.y); o.z = f2bf(v.z); o.w = f2bf(v.w);
        ((ushort4*)out)[i] = o;
    }
}

// batched: out[m][n][k] = bf16(in[m][k][n]) with per-matrix strides.
__global__ void convTb(const float* __restrict__ in, u16* __restrict__ out,
                       int K, int N, int inStride, int outStride, int nm) {
    int idx = blockIdx.x * blockDim.x + threadIdx.x;
    int per = N * (K >> 2);
    int total = per * nm;
    if (idx >= total) return;
    int mat = idx / per, rem = idx - mat * per;
    int k4 = rem / N, n = rem - k4 * N;
    int k = k4 * 4;
    const float* src = in + (size_t)mat * inStride;
    u16* dst = out + (size_t)mat * outStride;
    ushort4 o;
    o.x = f2bf(src[(size_t)(k + 0) * N + n]);
    o.y = f2bf(src[(size_t)(k + 1) * N + n]);
    o.z = f2bf(src[(size_t)(k + 2) * N + n]);
    o.w = f2bf(src[(size_t)(k + 3) * N + n]);
    *(ushort4*)(dst + (size_t)n * K + k) = o;
}

__global__ void copy_bq(const float* __restrict__ bq, float* __restrict__ bqkv) {
    int lt = blockIdx.x;
    bqkv[lt * 768 + threadIdx.x] = bq[lt * 256 + threadIdx.x];
}

// --------------------- weight fusion (all 4 lt in one launch) ---------------------
__global__ __launch_bounds__(256) void fuse_weights(
    const float* __restrict__ Wk, const float* __restrict__ bk,
    const float* __restrict__ Wv, const float* __restrict__ bv,
    const float* __restrict__ a_rel, const float* __restrict__ m_rel,
    const float* __restrict__ p_rel,
    float* __restrict__ Wf2, float* __restrict__ bqkv)
{
    __shared__ float kw[256], vw[256];
    const int c = blockIdx.x, lt = blockIdx.y, tid = threadIdx.x;
    const int l = lt >> 1, t = lt & 1;
    const int lr = l * 2 + (t == 1 ? 0 : 1);     // relation where type t is the SOURCE
    const float* WkP = Wk + (size_t)lt * 65536;
    const float* WvP = Wv + (size_t)lt * 65536;
    const float* ar = a_rel + (size_t)lr * 8192;
    const float* mr = m_rel + (size_t)lr * 8192;
    kw[tid] = WkP[c * 256 + tid];
    vw[tid] = WvP[c * 256 + tid];
    __syncthreads();
    const int h = tid >> 5, e = tid & 31;
    const float s = p_rel[lr * 8 + h] * 0.17677669529663687f;  // 1/sqrt(32)
    float ak = 0.f, av = 0.f;
#pragma unroll 8
    for (int d = 0; d < 32; ++d) {
        ak += kw[h * 32 + d] * ar[h * 1024 + d * 32 + e];
        av += vw[h * 32 + d] * mr[h * 1024 + d * 32 + e];
    }
    float* WkfP = Wf2 + (size_t)lt * 131072;
    WkfP[c * 256 + tid] = ak * s;
    WkfP[65536 + c * 256 + tid] = av;
    if (c == 0) {
        const float* bkP = bk + (size_t)lt * 256;
        const float* bvP = bv + (size_t)lt * 256;
        float bka = 0.f, bva = 0.f;
#pragma unroll 8
        for (int d = 0; d < 32; ++d) {
            bka += bkP[h * 32 + d] * ar[h * 1024 + d * 32 + e];
            bva += bvP[h * 32 + d] * mr[h * 1024 + d * 32 + e];
        }
        bqkv[lt * 768 + 256 + tid] = bka * s;
        bqkv[lt * 768 + 512 + tid] = bva;
    }
}

// ------------------------- MFMA GEMM -------------------------
// C[M, NY*BN] = epi(A[M,K](bf16) @ WT[.,K]^T(bf16) + bias).
// 64 x BN tile, BK=64, 4 waves (2x2), double-buffered LDS, counted vmcnt.
// BN=64 -> 32KB LDS -> 5 blocks/CU for latency hiding.
template <int EPI, int BN, bool OBF>
__global__ __launch_bounds__(256) void gemm_mfma(
    const u16* __restrict__ A, const u16* __restrict__ WT,
    const float* __restrict__ bias, void* __restrict__ Cv,
    int M, int K, int ldC, int NY,
    const u16* __restrict__ xres, const float* __restrict__ skipPtr)
{
    constexpr int ASZ = 64 * 64;
    constexpr int BSZ = BN * 64;
    constexpr int NF = BN / 32;          // n-frags per wave (and B stage insts per wave)
    __shared__ u16 smem[2 * (ASZ + BSZ)];
    u16* As0 = smem;             u16* Bs0 = smem + ASZ;
    u16* As1 = smem + ASZ + BSZ; u16* Bs1 = As1 + ASZ;

    // bijective XCD swizzle (m204), then y-inner decode
    const int nwg = gridDim.x;
    const int bid = blockIdx.x;
    const int q8 = nwg >> 3, r8 = nwg & 7;
    const int xcd = bid & 7, pos = bid >> 3;
    const int lbid = (xcd < r8) ? xcd * (q8 + 1) + pos
                                : r8 * (q8 + 1) + (xcd - r8) * q8 + pos;
    const int bx = lbid / NY, by = lbid - bx * NY;
    const int m0 = bx * 64, n0 = by * BN;

    const int tid = threadIdx.x;
    const int wave = tid >> 6, lane = tid & 63;
    const int wm = (wave >> 1) * 32, wn = (wave & 1) * (BN / 2);
    f32x4 acc[2][NF];
#pragma unroll
    for (int i = 0; i < 2; ++i)
#pragma unroll
        for (int j = 0; j < NF; ++j) acc[i][j] = (f32x4){0.f, 0.f, 0.f, 0.f};

    const int sr = lane >> 3;   // row within 8-row staging group
    const int sl = lane & 7;    // linear 16B slot

    auto stage = [&](int k0, u16* Ad, u16* Bd) {
#pragma unroll
        for (int i = 0; i < 2; ++i) {
            int rb = wave * 16 + i * 8;
            int r = rb + sr;
            int gr = m0 + r; gr = gr < M ? gr : M - 1;
            const u16* gp = A + (size_t)gr * K + k0 + ((sl ^ sr) << 3);
            __builtin_amdgcn_global_load_lds(
                (const __attribute__((address_space(1))) void*)gp,
                (__attribute__((address_space(3))) void*)(Ad + rb * 64), 16, 0, 0);
        }
#pragma unroll
        for (int i = 0; i < NF; ++i) {
            int rb = wave * (BN / 4) + i * 8;
            int r = rb + sr;
            const u16* gp = WT + (size_t)(n0 + r) * K + k0 + ((sl ^ sr) << 3);
            __builtin_amdgcn_global_load_lds(
                (const __attribute__((address_space(1))) void*)gp,
                (__attribute__((address_space(3))) void*)(Bd + rb * 64), 16, 0, 0);
        }
    };

    auto compute = [&](const u16* Ab, const u16* Bb) {
#pragma unroll
        for (int kx = 0; kx < 2; ++kx) {
            bf16x8 af[2], bfr[NF];
#pragma unroll
            for (int mf = 0; mf < 2; ++mf) {
                int r = wm + mf * 16 + (lane & 15);
                int slot = (lane >> 4) + kx * 4;
                af[mf] = __builtin_bit_cast(bf16x8,
                    *(const u16x8*)(Ab + r * 64 + ((slot ^ (r & 7)) << 3)));
            }
#pragma unroll
            for (int nf = 0; nf < NF; ++nf) {
                int r = wn + nf * 16 + (lane & 15);
                int slot = (lane >> 4) + kx * 4;
                bfr[nf] = __builtin_bit_cast(bf16x8,
                    *(const u16x8*)(Bb + r * 64 + ((slot ^ (r & 7)) << 3)));
            }
#pragma unroll
            for (int mf = 0; mf < 2; ++mf)
#pragma unroll
                for (int nf = 0; nf < NF; ++nf)
                    acc[mf][nf] = __builtin_amdgcn_mfma_f32_16x16x32_bf16(
                        af[mf], bfr[nf], acc[mf][nf], 0, 0, 0);
        }
    };

    const int nt = K >> 6;
    stage(0, As0, Bs0);
    for (int t = 0; t < nt; ++t) {
        const bool pb = t & 1;
        if (t + 1 < nt) {
            stage((t + 1) << 6, pb ? As0 : As1, pb ? Bs0 : Bs1);
            __builtin_amdgcn_sched_barrier(0);
            if constexpr (BN == 128) asm volatile("s_waitcnt vmcnt(6)" ::: "memory");
            else                     asm volatile("s_waitcnt vmcnt(4)" ::: "memory");
        } else {
            asm volatile("s_waitcnt vmcnt(0)" ::: "memory");
        }
        __builtin_amdgcn_s_barrier();
        __builtin_amdgcn_sched_barrier(0);
        compute(pb ? As1 : As0, pb ? Bs1 : Bs0);
        __builtin_amdgcn_sched_barrier(0);
        __builtin_amdgcn_s_barrier();
        __builtin_amdgcn_sched_barrier(0);   // fence: next stage must not hoist above
    }

    float beta = 0.f;
    if (EPI == 2) beta = 1.f / (1.f + expf(-skipPtr[0]));

    if constexpr (OBF) {
        constexpr int CLD = BN + 8;
        u16* Ct = smem;
#pragma unroll
        for (int nf = 0; nf < NF; ++nf) {
            int col = wn + nf * 16 + (lane & 15);
            int gcol = n0 + col;
            float bs = bias[gcol];
#pragma unroll
            for (int mf = 0; mf < 2; ++mf) {
#pragma unroll
                for (int j = 0; j < 4; ++j) {
                    int row = wm + mf * 16 + (lane >> 4) * 4 + j;
                    int grow = m0 + row;
                    int gr2 = grow < M ? grow : 0;
                    float c = acc[mf][nf][j] + bs;
                    if (EPI == 1) c = fmaxf(c, 0.f);
                    if (EPI == 2) c = beta * c + (1.f - beta) * bf2f(xres[(size_t)gr2 * ldC + gcol]);
                    if (EPI == 3) c = (c > 0.f) ? c : 0.2f * c;
                    Ct[row * CLD + col] = f2bf(c);
                }
            }
        }
        __syncthreads();   // full lgkm drain + compiler fence: cross-wave LDS handoff
        // coalesced write: 4 threads per row, BN/4 u16 each
        int row = tid >> 2, c0 = (tid & 3) * (BN / 4);
        int grow = m0 + row;
        if (grow < M) {
            u16* dst = (u16*)Cv + (size_t)grow * ldC + n0 + c0;
            const u16* src = Ct + row * CLD + c0;
#pragma unroll
            for (int i = 0; i < BN / 32; ++i)
                *(u16x8*)(dst + i * 8) = *(const u16x8*)(src + i * 8);
        }
    } else {
#pragma unroll
        for (int nf = 0; nf < NF; ++nf) {
            int gcol = n0 + wn + nf * 16 + (lane & 15);
            float bs = bias[gcol];
#pragma unroll
            for (int mf = 0; mf < 2; ++mf) {
#pragma unroll
                for (int j = 0; j < 4; ++j) {
                    int grow = m0 + wm + mf * 16 + (lane >> 4) * 4 + j;
                    if (grow >= M) continue;
                    float c = acc[mf][nf][j] + bs;
                    if (EPI == 1) c = fmaxf(c, 0.f);
                    if (EPI == 3) c = (c > 0.f) ? c : 0.2f * c;
                    ((float*)Cv)[(size_t)grow * ldC + gcol] = c;
                }
            }
        }
    }
}

// ------------------------- CSR build -------------------------
__global__ void hist_kernel(const int* __restrict__ di, unsigned* __restrict__ counts, int E) {
    int e = blockIdx.x * blockDim.x + threadIdx.x;
    if (e < E) atomicAdd(&counts[di[e]], 1u);
}

__global__ __launch_bounds__(256) void scan_blocks(
    const unsigned* __restrict__ counts, unsigned* __restrict__ pref,
    unsigned* __restrict__ bsum, int N)
{
    __shared__ unsigned tmp[256];
    int i = blockIdx.x * 256 + threadIdx.x;
    unsigned v = (i < N) ? counts[i] : 0u;
    tmp[threadIdx.x] = v;
    __syncthreads();
    for (int off = 1; off < 256; off <<= 1) {
        unsigned t = (threadIdx.x >= off) ? tmp[threadIdx.x - off] : 0u;
        __syncthreads();
        tmp[threadIdx.x] += t;
        __syncthreads();
    }
    if (i < N) pref[i] = tmp[threadIdx.x] - v;  // exclusive
    if (threadIdx.x == 255) bsum[blockIdx.x] = tmp[255];
}

__global__ __launch_bounds__(256) void scan_top(unsigned* __restrict__ bsum, int NB) {
    __shared__ unsigned tmp[256];
    unsigned v = (threadIdx.x < NB) ? bsum[threadIdx.x] : 0u;
    tmp[threadIdx.x] = v;
    __syncthreads();
    for (int off = 1; off < 256; off <<= 1) {
        unsigned t = (threadIdx.x >= off) ? tmp[threadIdx.x - off] : 0u;
        __syncthreads();
        tmp[threadIdx.x] += t;
        __syncthreads();
    }
    if (threadIdx.x < NB) bsum[threadIdx.x] = tmp[threadIdx.x] - v;  // exclusive
}

__global__ void scan_add(unsigned* __restrict__ pref, const unsigned* __restrict__ bsum,
                         unsigned* __restrict__ cursor, int N) {
    int i = blockIdx.x * 256 + threadIdx.x;
    if (i < N) {
        unsigned s = pref[i] + bsum[blockIdx.x];
        pref[i] = s;
        cursor[i] = s;
    }
}

// stores the SRC NODE INDEX (not edge id) in CSR order: kills one dependent load per edge.
__global__ void place_kernel(const int* __restrict__ di, const int* __restrict__ si,
                             unsigned* __restrict__ cursor, unsigned* __restrict__ srcout, int E) {
    int e = blockIdx.x * blockDim.x + threadIdx.x;
    if (e < E) {
        unsigned p = atomicAdd(&cursor[di[e]], 1u);
        srcout[p] = (unsigned)si[e];
    }
}

// ------------------------- fused edge gather (both relations, one launch) -------------------------
// One wave per dst node; each 32-lane HALF processes its own edge substream
// (j = half, half+2, ...). Per edge a half loads the 512B K row (u16x8/lane),
// does an 8-FMA dot + 2 quad shfl_xor (head dot stays in the owning quad),
// loads the 512B V row and online-softmax accumulates. One cross-half merge
// (shfl_xor 32 of m/s/acc) per node, then gelu + bf16 store from lanes 0-31.
#define TBLK ((NTN + 3) / 4)
__global__ __launch_bounds__(256) void edge_gather2(
    const u16* __restrict__ qkvT, const u16* __restrict__ qkvC,
    const unsigned* __restrict__ rsT, const unsigned* __restrict__ cntT,
    const unsigned* __restrict__ srcT,
    const unsigned* __restrict__ rsC, const unsigned* __restrict__ cntC,
    const unsigned* __restrict__ srcC,
    u16* __restrict__ aggT, u16* __restrict__ aggC)
{
    const int b = blockIdx.x;
    const bool isT = b < TBLK;
    const int n = (isT ? b : b - TBLK) * 4 + (threadIdx.x >> 6);
    const int Ndst = isT ? NTN : NCN;
    if (n >= Ndst) return;
    const u16* qkv_d = isT ? qkvT : qkvC;
    const u16* qkv_s = isT ? qkvC : qkvT;
    const unsigned* rs = isT ? rsT : rsC;
    const unsigned* cnt = isT ? cntT : cntC;
    const unsigned* srcarr = isT ? srcT : srcC;
    u16* agg = isT ? aggT : aggC;

    const int lane = threadIdx.x & 63;
    const int lq = lane & 31;
    const int h = lane >> 5;
    const unsigned start = rs[n], deg = cnt[n];

    if (deg == 0) {
        if (lane < 32)
            *(u16x8*)&agg[(size_t)n * 256 + lq * 8] = (u16x8){0, 0, 0, 0, 0, 0, 0, 0};
        return;
    }

    u16x8 qv = *(const u16x8*)&qkv_d[(size_t)n * 768 + lq * 8];
    float qf[8];
#pragma unroll
    for (int i = 0; i < 8; ++i) qf[i] = bf2f(qv[i]);

    const u16* kvb = qkv_s + 256;  // k section; v section at +256 more
    float m = -INFINITY, s = 0.f;
    float acc[8] = {0.f, 0.f, 0.f, 0.f, 0.f, 0.f, 0.f, 0.f};

    unsigned j = (unsigned)h;
    if (j < deg) {
        unsigned src = srcarr[start + j];
        const u16* rp = kvb + (size_t)src * 768 + lq * 8;
        u16x8 kr = *(const u16x8*)rp;
        u16x8 vr = *(const u16x8*)(rp + 256);
        for (;;) {
            u16x8 kr_n, vr_n;
            const bool more = (j + 2 < deg);
            if (more) {
                unsigned s2 = srcarr[start + j + 2];
                const u16* rp2 = kvb + (size_t)s2 * 768 + lq * 8;
                kr_n = *(const u16x8*)rp2;
                vr_n = *(const u16x8*)(rp2 + 256);
            }
            float kf[8], vf[8];
#pragma unroll
            for (int i = 0; i < 8; ++i) { kf[i] = bf2f(kr[i]); vf[i] = bf2f(vr[i]); }
            float p = qf[0] * kf[0] + qf[1] * kf[1] + qf[2] * kf[2] + qf[3] * kf[3]
                    + qf[4] * kf[4] + qf[5] * kf[5] + qf[6] * kf[6] + qf[7] * kf[7];
            p += __shfl_xor(p, 1);
            p += __shfl_xor(p, 2);      // quad = the 4 lanes of this head
            float mn = fmaxf(m, p);
            float sc = __expf(m - mn);  // 0 on first iteration (m = -inf)
            float wv = __expf(p - mn);
            s = s * sc + wv;
#pragma unroll
            for (int i = 0; i < 8; ++i) acc[i] = acc[i] * sc + wv * vf[i];
            m = mn;
            if (!more) break;
            kr = kr_n; vr = vr_n; j += 2;
        }
    }

    // cross-half merge: deg>=1 guarantees half 0 ran, so mt is finite.
    float mo = __shfl_xor(m, 32);
    float so = __shfl_xor(s, 32);
    float mt = fmaxf(m, mo);
    float sc0 = __expf(m - mt);
    float sco = __expf(mo - mt);
    float st = s * sc0 + so * sco;
    float inv = 1.f / (st + 1e-16f);
    u16x8 ov;
#pragma unroll
    for (int i = 0; i < 8; ++i) {
        float ao = __shfl_xor(acc[i], 32);
        float x = (acc[i] * sc0 + ao * sco) * inv;
        float g = 0.5f * x * (1.f + erff(x * 0.70710678118654752f));
        ov[i] = f2bf(g);
    }
    if (lane < 32)
        *(u16x8*)&agg[(size_t)n * 256 + lq * 8] = ov;
}

// ------------------------- misc -------------------------
__global__ __launch_bounds__(256) void norm_rows(float* __restrict__ y, int M) {
    int row = blockIdx.x * 4 + (threadIdx.x >> 6);
    int lane = threadIdx.x & 63;
    if (row >= M) return;
    float v = y[(size_t)row * 64 + lane];
    float s = v * v;
#pragma unroll
    for (int off = 1; off < 64; off <<= 1) s += __shfl_xor(s, off);
    float n = sqrtf(s);
    y[(size_t)row * 64 + lane] = v / fmaxf(n, 1e-12f);
}

// ------------------------- launch -------------------------
extern "C" void kernel_launch(void* const* d_in, const int* in_sizes, int n_in,
                              void* d_out, int out_size, void* d_ws, size_t ws_size,
                              hipStream_t stream)
{
    const float* x_trans = (const float*)d_in[0];
    const float* x_cc    = (const float*)d_in[1];
    const int* src_c2t   = (const int*)d_in[2];
    const int* dst_c2t   = (const int*)d_in[3];
    const int* src_t2c   = (const int*)d_in[4];
    const int* dst_t2c   = (const int*)d_in[5];
    const float* W_in = (const float*)d_in[6];
    const float* b_in = (const float*)d_in[7];
    const float* Wk   = (const float*)d_in[8];
    const float* bk   = (const float*)d_in[9];
    const float* Wq   = (const float*)d_in[10];
    const float* bq   = (const float*)d_in[11];
    const float* Wv   = (const float*)d_in[12];
    const float* bv   = (const float*)d_in[13];
    const float* Wa   = (const float*)d_in[14];
    const float* ba   = (const float*)d_in[15];
    const float* a_rel = (const float*)d_in[16];
    const float* m_rel = (const float*)d_in[17];
    const float* p_rel = (const float*)d_in[18];
    const float* skip  = (const float*)d_in[19];
    const float* W_out = (const float*)d_in[20];
    const float* b_out = (const float*)d_in[21];

    // ---------- workspace layout (~250 MB) ----------
    char* w = (char*)d_ws;
    auto alloc = [&](size_t bytes) { char* p = w; w += (bytes + 255) & ~(size_t)255; return p; };
    u16* xs0  = (u16*)alloc((size_t)NTN * 256 * 2);
    u16* xs1  = (u16*)alloc((size_t)NCN * 256 * 2);
    u16* xin0 = (u16*)alloc((size_t)NTN * 64 * 2);
    u16* xin1 = (u16*)alloc((size_t)NCN * 64 * 2);
    u16* qkv0 = (u16*)alloc((size_t)NTN * 768 * 2);   // 92.2 MB
    u16* qkv1 = (u16*)alloc((size_t)NCN * 768 * 2);   // 46.1 MB
    u16* agg0 = (u16*)alloc((size_t)NTN * 256 * 2);
    u16* agg1 = (u16*)alloc((size_t)NCN * 256 * 2);
    u16* WinT = (u16*)alloc((size_t)2 * 16384 * 2);
    u16* WqkvT= (u16*)alloc((size_t)4 * 196608 * 2);  // [768][256] per lt
    u16* WaT  = (u16*)alloc((size_t)4 * 65536 * 2);
    u16* WoutT= (u16*)alloc((size_t)16384 * 2);
    float* Wf2 = (float*)alloc((size_t)4 * 131072 * 4); // [lt][kf|vf] f32 staging
    float* bqkv = (float*)alloc((size_t)4 * 768 * 4);
    unsigned* countsT   = (unsigned*)alloc((size_t)NTN * 4);
    unsigned* rowstartT = (unsigned*)alloc((size_t)NTN * 4);
    unsigned* cursorT   = (unsigned*)alloc((size_t)NTN * 4);
    unsigned* srcAT     = (unsigned*)alloc((size_t)NED * 4);
    unsigned* countsC   = (unsigned*)alloc((size_t)NCN * 4);
    unsigned* rowstartC = (unsigned*)alloc((size_t)NCN * 4);
    unsigned* cursorC   = (unsigned*)alloc((size_t)NCN * 4);
    unsigned* srcAC     = (unsigned*)alloc((size_t)NED * 4);
    unsigned* bsum      = (unsigned*)alloc((size_t)256 * 4);
    (void)ws_size; (void)in_sizes; (void)n_in; (void)out_size;

    // ---------- CSR builds (shared by both layers) ----------
    {
        const int EB = (NED + 255) / 256;
        int NBt = (NTN + 255) / 256;
        fill_u32<<<256, 256, 0, stream>>>(countsT, 0u, NTN);
        hist_kernel<<<EB, 256, 0, stream>>>(dst_c2t, countsT, NED);
        scan_blocks<<<NBt, 256, 0, stream>>>(countsT, rowstartT, bsum, NTN);
        scan_top<<<1, 256, 0, stream>>>(bsum, NBt);
        scan_add<<<NBt, 256, 0, stream>>>(rowstartT, bsum, cursorT, NTN);
        place_kernel<<<EB, 256, 0, stream>>>(dst_c2t, src_c2t, cursorT, srcAT, NED);
        int NBc = (NCN + 255) / 256;
        fill_u32<<<256, 256, 0, stream>>>(countsC, 0u, NCN);
        hist_kernel<<<EB, 256, 0, stream>>>(dst_t2c, countsC, NED);
        scan_blocks<<<NBc, 256, 0, stream>>>(countsC, rowstartC, bsum, NCN);
        scan_top<<<1, 256, 0, stream>>>(bsum, NBc);
        scan_add<<<NBc, 256, 0, stream>>>(rowstartC, bsum, cursorC, NCN);
        place_kernel<<<EB, 256, 0, stream>>>(dst_t2c, src_t2c, cursorC, srcAC, NED);
    }

    // ---------- weight prep: fused + batched transposes ----------
    fuse_weights<<<dim3(256, 4), 256, 0, stream>>>(Wk, bk, Wv, bv, a_rel, m_rel, p_rel, Wf2, bqkv);
    copy_bq<<<4, 256, 0, stream>>>(bq, bqkv);
    // WqkvT[lt] rows: [0,256)=Wq^T, [256,512)=Wkf^T, [512,768)=Wvf^T
    convTb<<<(4 * 16384 + 255) / 256, 256, 0, stream>>>(Wq, WqkvT, 256, 256, 65536, 196608, 4);
    convTb<<<(4 * 16384 + 255) / 256, 256, 0, stream>>>(Wf2, WqkvT + 65536, 256, 256, 131072, 196608, 4);
    convTb<<<(4 * 16384 + 255) / 256, 256, 0, stream>>>(Wf2 + 65536, WqkvT + 131072, 256, 256, 131072, 196608, 4);
    convTb<<<(4 * 16384 + 255) / 256, 256, 0, stream>>>(Wa, WaT, 256, 256, 65536, 65536, 4);
    convTb<<<(2 * 4096 + 255) / 256, 256, 0, stream>>>(W_in, WinT, 64, 256, 16384, 16384, 2);
    convTb<<<(4096 + 255) / 256, 256, 0, stream>>>(W_out, WoutT, 256, 64, 16384, 16384, 1);
    f32_to_bf16<<<1024, 256, 0, stream>>>(x_trans, xin0, NTN * 64 / 4);
    f32_to_bf16<<<1024, 256, 0, stream>>>(x_cc,    xin1, NCN * 64 / 4);

    const int GT = (NTN + 63) / 64, GC = (NCN + 63) / 64;   // 938 / 469

    // ---------- input projections + relu ----------
    gemm_mfma<1, 64, true><<<GT * 4, 256, 0, stream>>>(xin0, WinT, b_in, xs0, NTN, 64, 256, 4, nullptr, nullptr);
    gemm_mfma<1, 64, true><<<GC * 4, 256, 0, stream>>>(xin1, WinT + 16384, b_in + 256, xs1, NCN, 64, 256, 4, nullptr, nullptr);

    for (int l = 0; l < 2; ++l) {
        size_t lt0 = (size_t)(l * 2 + 0), lt1 = (size_t)(l * 2 + 1);

        // fused q|k|v projections (one GEMM per node type)
        gemm_mfma<0, 64, true><<<GT * 12, 256, 0, stream>>>(xs0, WqkvT + lt0 * 196608, bqkv + lt0 * 768, qkv0, NTN, 256, 768, 12, nullptr, nullptr);
        gemm_mfma<0, 64, true><<<GC * 12, 256, 0, stream>>>(xs1, WqkvT + lt1 * 196608, bqkv + lt1 * 768, qkv1, NCN, 256, 768, 12, nullptr, nullptr);

        // both edge phases in one launch (independent; overlap their latency)
        edge_gather2<<<TBLK + (NCN + 3) / 4, 256, 0, stream>>>(
            qkv0, qkv1,
            rowstartT, countsT, srcAT,
            rowstartC, countsC, srcAC,
            agg0, agg1);

        // skip-blend output transforms (in-place xs updates)
        gemm_mfma<2, 64, true><<<GT * 4, 256, 0, stream>>>(agg0, WaT + lt0 * 65536, ba + lt0 * 256, xs0, NTN, 256, 256, 4, xs0, skip + l * 2 + 0);
        gemm_mfma<2, 64, true><<<GC * 4, 256, 0, stream>>>(agg1, WaT + lt1 * 65536, ba + lt1 * 256, xs1, NCN, 256, 256, 4, xs1, skip + l * 2 + 1);
    }

    // ---------- final projection + leakyrelu + row L2 normalize ----------
    {
        float* y = (float*)d_out;
        gemm_mfma<3, 64, false><<<GT, 256, 0, stream>>>(xs0, WoutT, b_out, y, NTN, 256, 64, 1, nullptr, nullptr);
        norm_rows<<<NTN / 4, 256, 0, stream>>>(y, NTN);
    }
}

// Round 10
// 481.697 us; speedup vs baseline: 8.9903x; 1.0366x over previous
//
#include <hip/hip_runtime.h>
#include <hip/hip_bf16.h>
#include <math.h>

#define NTN 60000
#define NCN 30000
#define NED 200000
// H=8, D=32, HID=256, FIN=64

typedef unsigned short u16;
typedef unsigned long long u64;
typedef __attribute__((ext_vector_type(8))) u16 u16x8;
typedef __attribute__((ext_vector_type(8))) __bf16 bf16x8;
typedef __attribute__((ext_vector_type(4))) float f32x4;

static __device__ __forceinline__ float bf2f(u16 u) {
    return __uint_as_float(((unsigned)u) << 16);
}
static __device__ __forceinline__ u16 f2bf(float f) {
    unsigned u = __float_as_uint(f);
    unsigned r = (u + 0x7fffu + ((u >> 16) & 1u)) >> 16;  // RNE
    return (u16)r;
}

// ------------------------- fill -------------------------
__global__ void fill_u32(unsigned* __restrict__ p, unsigned v, int n) {
    int i = blockIdx.x * blockDim.x + threadIdx.x;
    int stride = gridDim.x * blockDim.x;
    for (; i < n; i += stride) p[i] = v;
}

// ------------------------- conversions -------------------------
__global__ void f32_to_bf16(const float* __restrict__ in, u16* __restrict__ out, int n4) {
    int i = blockIdx.x * blockDim.x + threadIdx.x;
    int stride = gridDim.x * blockDim.x;
    for (; i < n4; i += stride) {
        float4 v = ((const float4*)in)[i];
        ushort4 o;
        o.x = f2bf(v.x); o.y = f2bf(v.y); o.z = f2bf(v.z); o.w = f2bf(v.w);
        ((ushort4*)out)[i] = o;
    }
}

// batched: out[m][n][k] = bf16(in[m][k][n]) with per-matrix strides.
__global__ void convTb(const float* __restrict__ in, u16* __restrict__ out,
                       int K, int N, int inStride, int outStride, int nm) {
    int idx = blockIdx.x * blockDim.x + threadIdx.x;
    int per = N * (K >> 2);
    int total = per * nm;
    if (idx >= total) return;
    int mat = idx / per, rem = idx - mat * per;
    int k4 = rem / N, n = rem - k4 * N;
    int k = k4 * 4;
    const float* src = in + (size_t)mat * inStride;
    u16* dst = out + (size_t)mat * outStride;
    ushort4 o;
    o.x = f2bf(src[(size_t)(k + 0) * N + n]);
    o.y = f2bf(src[(size_t)(k + 1) * N + n]);
    o.z = f2bf(src[(size_t)(k + 2) * N + n]);
    o.w = f2bf(src[(size_t)(k + 3) * N + n]);
    *(ushort4*)(dst + (size_t)n * K + k) = o;
}

__global__ void copy_bq(const float* __restrict__ bq, float* __restrict__ bqkv) {
    int lt = blockIdx.x;
    bqkv[lt * 768 + threadIdx.x] = bq[lt * 256 + threadIdx.x];
}

// --------------------- weight fusion (all 4 lt in one launch) ---------------------
__global__ __launch_bounds__(256) void fuse_weights(
    const float* __restrict__ Wk, const float* __restrict__ bk,
    const float* __restrict__ Wv, const float* __restrict__ bv,
    const float* __restrict__ a_rel, const float* __restrict__ m_rel,
    const float* __restrict__ p_rel,
    float* __restrict__ Wf2, float* __restrict__ bqkv)
{
    __shared__ float kw[256], vw[256];
    const int c = blockIdx.x, lt = blockIdx.y, tid = threadIdx.x;
    const int l = lt >> 1, t = lt & 1;
    const int lr = l * 2 + (t == 1 ? 0 : 1);     // relation where type t is the SOURCE
    const float* WkP = Wk + (size_t)lt * 65536;
    const float* WvP = Wv + (size_t)lt * 65536;
    const float* ar = a_rel + (size_t)lr * 8192;
    const float* mr = m_rel + (size_t)lr * 8192;
    kw[tid] = WkP[c * 256 + tid];
    vw[tid] = WvP[c * 256 + tid];
    __syncthreads();
    const int h = tid >> 5, e = tid & 31;
    const float s = p_rel[lr * 8 + h] * 0.17677669529663687f;  // 1/sqrt(32)
    float ak = 0.f, av = 0.f;
#pragma unroll 8
    for (int d = 0; d < 32; ++d) {
        ak += kw[h * 32 + d] * ar[h * 1024 + d * 32 + e];
        av += vw[h * 32 + d] * mr[h * 1024 + d * 32 + e];
    }
    float* WkfP = Wf2 + (size_t)lt * 131072;
    WkfP[c * 256 + tid] = ak * s;
    WkfP[65536 + c * 256 + tid] = av;
    if (c == 0) {
        const float* bkP = bk + (size_t)lt * 256;
        const float* bvP = bv + (size_t)lt * 256;
        float bka = 0.f, bva = 0.f;
#pragma unroll 8
        for (int d = 0; d < 32; ++d) {
            bka += bkP[h * 32 + d] * ar[h * 1024 + d * 32 + e];
            bva += bvP[h * 32 + d] * mr[h * 1024 + d * 32 + e];
        }
        bqkv[lt * 768 + 256 + tid] = bka * s;
        bqkv[lt * 768 + 512 + tid] = bva;
    }
}

// ------------------------- MFMA GEMM (pair-merged) -------------------------
// Two back-to-back GEMMs in one grid: blocks [0,nblk0) run set 0, rest set 1.
// Per set: C[M, NY*BN] = epi(A[M,K](bf16) @ WT^T(bf16) + bias).
// 64 x BN tile, BK=64, 4 waves, double-buffered LDS, counted vmcnt; 32KB LDS.
template <int EPI, int BN, bool OBF>
__global__ __launch_bounds__(256) void gemm_mfma2(
    int nblk0,
    const u16* __restrict__ A0, const u16* __restrict__ W0, const float* __restrict__ b0,
    void* __restrict__ C0, int M0, int ldC0, int NY0,
    const u16* __restrict__ xr0, const float* __restrict__ sk0,
    const u16* __restrict__ A1, const u16* __restrict__ W1, const float* __restrict__ b1,
    void* __restrict__ C1, int M1, int ldC1, int NY1,
    const u16* __restrict__ xr1, const float* __restrict__ sk1,
    int K)
{
    constexpr int ASZ = 64 * 64;
    constexpr int BSZ = BN * 64;
    constexpr int NF = BN / 32;
    __shared__ u16 smem[2 * (ASZ + BSZ)];
    u16* As0 = smem;             u16* Bs0 = smem + ASZ;
    u16* As1 = smem + ASZ + BSZ; u16* Bs1 = As1 + ASZ;

    // bijective XCD swizzle (m204) over the merged grid
    const int nwg = gridDim.x;
    const int bid = blockIdx.x;
    const int q8 = nwg >> 3, r8 = nwg & 7;
    const int xcd = bid & 7, pos = bid >> 3;
    const int lbid = (xcd < r8) ? xcd * (q8 + 1) + pos
                                : r8 * (q8 + 1) + (xcd - r8) * q8 + pos;

    const u16* A; const u16* WT; const float* bias; void* Cv;
    int M, ldC, NY, sb; const u16* xres; const float* skipPtr;
    if (lbid < nblk0) {
        A = A0; WT = W0; bias = b0; Cv = C0; M = M0; ldC = ldC0; NY = NY0;
        xres = xr0; skipPtr = sk0; sb = lbid;
    } else {
        A = A1; WT = W1; bias = b1; Cv = C1; M = M1; ldC = ldC1; NY = NY1;
        xres = xr1; skipPtr = sk1; sb = lbid - nblk0;
    }
    const int bx = sb / NY, by = sb - bx * NY;
    const int m0 = bx * 64, n0 = by * BN;

    const int tid = threadIdx.x;
    const int wave = tid >> 6, lane = tid & 63;
    const int wm = (wave >> 1) * 32, wn = (wave & 1) * (BN / 2);
    f32x4 acc[2][NF];
#pragma unroll
    for (int i = 0; i < 2; ++i)
#pragma unroll
        for (int j = 0; j < NF; ++j) acc[i][j] = (f32x4){0.f, 0.f, 0.f, 0.f};

    const int sr = lane >> 3;
    const int sl = lane & 7;

    auto stage = [&](int k0, u16* Ad, u16* Bd) {
#pragma unroll
        for (int i = 0; i < 2; ++i) {
            int rb = wave * 16 + i * 8;
            int r = rb + sr;
            int gr = m0 + r; gr = gr < M ? gr : M - 1;
            const u16* gp = A + (size_t)gr * K + k0 + ((sl ^ sr) << 3);
            __builtin_amdgcn_global_load_lds(
                (const __attribute__((address_space(1))) void*)gp,
                (__attribute__((address_space(3))) void*)(Ad + rb * 64), 16, 0, 0);
        }
#pragma unroll
        for (int i = 0; i < NF; ++i) {
            int rb = wave * (BN / 4) + i * 8;
            int r = rb + sr;
            const u16* gp = WT + (size_t)(n0 + r) * K + k0 + ((sl ^ sr) << 3);
            __builtin_amdgcn_global_load_lds(
                (const __attribute__((address_space(1))) void*)gp,
                (__attribute__((address_space(3))) void*)(Bd + rb * 64), 16, 0, 0);
        }
    };

    auto compute = [&](const u16* Ab, const u16* Bb) {
#pragma unroll
        for (int kx = 0; kx < 2; ++kx) {
            bf16x8 af[2], bfr[NF];
#pragma unroll
            for (int mf = 0; mf < 2; ++mf) {
                int r = wm + mf * 16 + (lane & 15);
                int slot = (lane >> 4) + kx * 4;
                af[mf] = __builtin_bit_cast(bf16x8,
                    *(const u16x8*)(Ab + r * 64 + ((slot ^ (r & 7)) << 3)));
            }
#pragma unroll
            for (int nf = 0; nf < NF; ++nf) {
                int r = wn + nf * 16 + (lane & 15);
                int slot = (lane >> 4) + kx * 4;
                bfr[nf] = __builtin_bit_cast(bf16x8,
                    *(const u16x8*)(Bb + r * 64 + ((slot ^ (r & 7)) << 3)));
            }
#pragma unroll
            for (int mf = 0; mf < 2; ++mf)
#pragma unroll
                for (int nf = 0; nf < NF; ++nf)
                    acc[mf][nf] = __builtin_amdgcn_mfma_f32_16x16x32_bf16(
                        af[mf], bfr[nf], acc[mf][nf], 0, 0, 0);
        }
    };

    const int nt = K >> 6;
    stage(0, As0, Bs0);
    for (int t = 0; t < nt; ++t) {
        const bool pb = t & 1;
        if (t + 1 < nt) {
            stage((t + 1) << 6, pb ? As0 : As1, pb ? Bs0 : Bs1);
            __builtin_amdgcn_sched_barrier(0);
            if constexpr (BN == 128) asm volatile("s_waitcnt vmcnt(6)" ::: "memory");
            else                     asm volatile("s_waitcnt vmcnt(4)" ::: "memory");
        } else {
            asm volatile("s_waitcnt vmcnt(0)" ::: "memory");
        }
        __builtin_amdgcn_s_barrier();
        __builtin_amdgcn_sched_barrier(0);
        compute(pb ? As1 : As0, pb ? Bs1 : Bs0);
        __builtin_amdgcn_sched_barrier(0);
        __builtin_amdgcn_s_barrier();
        __builtin_amdgcn_sched_barrier(0);   // fence: next stage must not hoist above
    }

    float beta = 0.f;
    if (EPI == 2) beta = 1.f / (1.f + expf(-skipPtr[0]));

    if constexpr (OBF) {
        constexpr int CLD = BN + 8;
        u16* Ct = smem;
#pragma unroll
        for (int nf = 0; nf < NF; ++nf) {
            int col = wn + nf * 16 + (lane & 15);
            int gcol = n0 + col;
            float bs = bias[gcol];
#pragma unroll
            for (int mf = 0; mf < 2; ++mf) {
#pragma unroll
                for (int j = 0; j < 4; ++j) {
                    int row = wm + mf * 16 + (lane >> 4) * 4 + j;
                    int grow = m0 + row;
                    int gr2 = grow < M ? grow : 0;
                    float c = acc[mf][nf][j] + bs;
                    if (EPI == 1) c = fmaxf(c, 0.f);
                    if (EPI == 2) c = beta * c + (1.f - beta) * bf2f(xres[(size_t)gr2 * ldC + gcol]);
                    if (EPI == 3) c = (c > 0.f) ? c : 0.2f * c;
                    Ct[row * CLD + col] = f2bf(c);
                }
            }
        }
        __syncthreads();   // full lgkm drain + fence: cross-wave LDS handoff
        int row = tid >> 2, c0 = (tid & 3) * (BN / 4);
        int grow = m0 + row;
        if (grow < M) {
            u16* dst = (u16*)Cv + (size_t)grow * ldC + n0 + c0;
            const u16* src = Ct + row * CLD + c0;
#pragma unroll
            for (int i = 0; i < BN / 32; ++i)
                *(u16x8*)(dst + i * 8) = *(const u16x8*)(src + i * 8);
        }
    } else {
#pragma unroll
        for (int nf = 0; nf < NF; ++nf) {
            int gcol = n0 + wn + nf * 16 + (lane & 15);
            float bs = bias[gcol];
#pragma unroll
            for (int mf = 0; mf < 2; ++mf) {
#pragma unroll
                for (int j = 0; j < 4; ++j) {
                    int grow = m0 + wm + mf * 16 + (lane >> 4) * 4 + j;
                    if (grow >= M) continue;
                    float c = acc[mf][nf][j] + bs;
                    if (EPI == 1) c = fmaxf(c, 0.f);
                    if (EPI == 3) c = (c > 0.f) ? c : 0.2f * c;
                    ((float*)Cv)[(size_t)grow * ldC + gcol] = c;
                }
            }
        }
    }
}

// ------------------------- CSR build -------------------------
__global__ void hist_kernel(const int* __restrict__ di, unsigned* __restrict__ counts, int E) {
    int e = blockIdx.x * blockDim.x + threadIdx.x;
    if (e < E) atomicAdd(&counts[di[e]], 1u);
}

__global__ __launch_bounds__(256) void scan_blocks(
    const unsigned* __restrict__ counts, unsigned* __restrict__ pref,
    unsigned* __restrict__ bsum, int N)
{
    __shared__ unsigned tmp[256];
    int i = blockIdx.x * 256 + threadIdx.x;
    unsigned v = (i < N) ? counts[i] : 0u;
    tmp[threadIdx.x] = v;
    __syncthreads();
    for (int off = 1; off < 256; off <<= 1) {
        unsigned t = (threadIdx.x >= off) ? tmp[threadIdx.x - off] : 0u;
        __syncthreads();
        tmp[threadIdx.x] += t;
        __syncthreads();
    }
    if (i < N) pref[i] = tmp[threadIdx.x] - v;  // exclusive
    if (threadIdx.x == 255) bsum[blockIdx.x] = tmp[255];
}

__global__ __launch_bounds__(256) void scan_top(unsigned* __restrict__ bsum, int NB) {
    __shared__ unsigned tmp[256];
    unsigned v = (threadIdx.x < NB) ? bsum[threadIdx.x] : 0u;
    tmp[threadIdx.x] = v;
    __syncthreads();
    for (int off = 1; off < 256; off <<= 1) {
        unsigned t = (threadIdx.x >= off) ? tmp[threadIdx.x - off] : 0u;
        __syncthreads();
        tmp[threadIdx.x] += t;
        __syncthreads();
    }
    if (threadIdx.x < NB) bsum[threadIdx.x] = tmp[threadIdx.x] - v;  // exclusive
}

// also packs rowstart|deg into one u64 per node (single load in edge kernel)
__global__ void scan_add(unsigned* __restrict__ pref, const unsigned* __restrict__ bsum,
                         const unsigned* __restrict__ counts,
                         unsigned* __restrict__ cursor, u64* __restrict__ rowinfo, int N) {
    int i = blockIdx.x * 256 + threadIdx.x;
    if (i < N) {
        unsigned s = pref[i] + bsum[blockIdx.x];
        cursor[i] = s;
        rowinfo[i] = (u64)s | ((u64)counts[i] << 32);
    }
}

// stores PRE-MULTIPLIED row offset (src*768, u16 units): kills a mul per edge load pair.
__global__ void place_kernel(const int* __restrict__ di, const int* __restrict__ si,
                             unsigned* __restrict__ cursor, unsigned* __restrict__ srcout, int E) {
    int e = blockIdx.x * blockDim.x + threadIdx.x;
    if (e < E) {
        unsigned p = atomicAdd(&cursor[di[e]], 1u);
        srcout[p] = (unsigned)si[e] * 768u;
    }
}

// ------------------------- fused edge gather (both relations, one launch) -------------------------
// One wave per dst node; each 32-lane HALF owns its own edge substream (j = half, half+2, ...).
// Per edge: K row load (u16x8/lane), 8-FMA dot + 2 quad shfl_xor, V row load, online-softmax.
// Defer-max fast path: if no lane's max grew (wave-uniform ballot), skip the rescale.
// Cross-half merge via shfl_xor 32, then gelu + bf16 store from lanes 0-31.
#define TBLK ((NTN + 3) / 4)
__global__ __launch_bounds__(256) void edge_gather2(
    const u16* __restrict__ qkvT, const u16* __restrict__ qkvC,
    const u64* __restrict__ riT, const unsigned* __restrict__ srcT,
    const u64* __restrict__ riC, const unsigned* __restrict__ srcC,
    u16* __restrict__ aggT, u16* __restrict__ aggC)
{
    const int b = blockIdx.x;
    const bool isT = b < TBLK;
    const int n = (isT ? b : b - TBLK) * 4 + (threadIdx.x >> 6);
    const int Ndst = isT ? NTN : NCN;
    if (n >= Ndst) return;
    const u16* qkv_d = isT ? qkvT : qkvC;
    const u16* qkv_s = isT ? qkvC : qkvT;
    const u64* ri = isT ? riT : riC;
    const unsigned* srcarr = isT ? srcT : srcC;
    u16* agg = isT ? aggT : aggC;

    const int lane = threadIdx.x & 63;
    const int lq = lane & 31;
    const int h = lane >> 5;
    const u64 rinfo = ri[n];
    const unsigned start = (unsigned)rinfo;
    const unsigned deg = (unsigned)(rinfo >> 32);

    if (deg == 0) {
        if (lane < 32)
            *(u16x8*)&agg[(size_t)n * 256 + lq * 8] = (u16x8){0, 0, 0, 0, 0, 0, 0, 0};
        return;
    }

    u16x8 qv = *(const u16x8*)&qkv_d[(size_t)n * 768 + lq * 8];
    float qf[8];
#pragma unroll
    for (int i = 0; i < 8; ++i) qf[i] = bf2f(qv[i]);

    const u16* kvb = qkv_s + 256 + lq * 8;   // k section base (lane term folded); v at +256
    float m = -INFINITY, s = 0.f;
    float acc[8] = {0.f, 0.f, 0.f, 0.f, 0.f, 0.f, 0.f, 0.f};

    unsigned j = (unsigned)h;
    if (j < deg) {
        unsigned off = srcarr[start + j];
        u16x8 kr = *(const u16x8*)(kvb + off);
        u16x8 vr = *(const u16x8*)(kvb + off + 256);
        for (;;) {
            u16x8 kr_n, vr_n;
            const bool more = (j + 2 < deg);
            if (more) {
                unsigned off2 = srcarr[start + j + 2];
                kr_n = *(const u16x8*)(kvb + off2);
                vr_n = *(const u16x8*)(kvb + off2 + 256);
            }
            float kf[8];
#pragma unroll
            for (int i = 0; i < 8; ++i) kf[i] = bf2f(kr[i]);
            float p = qf[0] * kf[0] + qf[1] * kf[1] + qf[2] * kf[2] + qf[3] * kf[3]
                    + qf[4] * kf[4] + qf[5] * kf[5] + qf[6] * kf[6] + qf[7] * kf[7];
            p += __shfl_xor(p, 1);
            p += __shfl_xor(p, 2);      // quad = the 4 lanes of this head
            float vf[8];
#pragma unroll
            for (int i = 0; i < 8; ++i) vf[i] = bf2f(vr[i]);
            if (__ballot(p > m) == 0ull) {
                // fast path: no quad's max grew — no rescale needed
                float wv = __expf(p - m);
                s += wv;
#pragma unroll
                for (int i = 0; i < 8; ++i) acc[i] += wv * vf[i];
            } else {
                float mn = fmaxf(m, p);
                float sc = __expf(m - mn);  // 0 on first iteration (m = -inf)
                float wv = __expf(p - mn);
                s = s * sc + wv;
#pragma unroll
                for (int i = 0; i < 8; ++i) acc[i] = acc[i] * sc + wv * vf[i];
                m = mn;
            }
            if (!more) break;
            kr = kr_n; vr = vr_n; j += 2;
        }
    }

    // cross-half merge: deg>=1 guarantees half 0 ran, so mt is finite.
    float mo = __shfl_xor(m, 32);
    float so = __shfl_xor(s, 32);
    float mt = fmaxf(m, mo);
    float sc0 = __expf(m - mt);
    float sco = __expf(mo - mt);
    float st = s * sc0 + so * sco;
    float inv = 1.f / (st + 1e-16f);
    u16x8 ov;
#pragma unroll
    for (int i = 0; i < 8; ++i) {
        float ao = __shfl_xor(acc[i], 32);
        float x = (acc[i] * sc0 + ao * sco) * inv;
        float g = 0.5f * x * (1.f + erff(x * 0.70710678118654752f));
        ov[i] = f2bf(g);
    }
    if (lane < 32)
        *(u16x8*)&agg[(size_t)n * 256 + lq * 8] = ov;
}

// ------------------------- misc -------------------------
__global__ __launch_bounds__(256) void norm_rows(float* __restrict__ y, int M) {
    int row = blockIdx.x * 4 + (threadIdx.x >> 6);
    int lane = threadIdx.x & 63;
    if (row >= M) return;
    float v = y[(size_t)row * 64 + lane];
    float s = v * v;
#pragma unroll
    for (int off = 1; off < 64; off <<= 1) s += __shfl_xor(s, off);
    float n = sqrtf(s);
    y[(size_t)row * 64 + lane] = v / fmaxf(n, 1e-12f);
}

// ------------------------- launch -------------------------
extern "C" void kernel_launch(void* const* d_in, const int* in_sizes, int n_in,
                              void* d_out, int out_size, void* d_ws, size_t ws_size,
                              hipStream_t stream)
{
    const float* x_trans = (const float*)d_in[0];
    const float* x_cc    = (const float*)d_in[1];
    const int* src_c2t   = (const int*)d_in[2];
    const int* dst_c2t   = (const int*)d_in[3];
    const int* src_t2c   = (const int*)d_in[4];
    const int* dst_t2c   = (const int*)d_in[5];
    const float* W_in = (const float*)d_in[6];
    const float* b_in = (const float*)d_in[7];
    const float* Wk   = (const float*)d_in[8];
    const float* bk   = (const float*)d_in[9];
    const float* Wq   = (const float*)d_in[10];
    const float* bq   = (const float*)d_in[11];
    const float* Wv   = (const float*)d_in[12];
    const float* bv   = (const float*)d_in[13];
    const float* Wa   = (const float*)d_in[14];
    const float* ba   = (const float*)d_in[15];
    const float* a_rel = (const float*)d_in[16];
    const float* m_rel = (const float*)d_in[17];
    const float* p_rel = (const float*)d_in[18];
    const float* skip  = (const float*)d_in[19];
    const float* W_out = (const float*)d_in[20];
    const float* b_out = (const float*)d_in[21];

    // ---------- workspace layout (~251 MB) ----------
    char* w = (char*)d_ws;
    auto alloc = [&](size_t bytes) { char* p = w; w += (bytes + 255) & ~(size_t)255; return p; };
    u16* xs0  = (u16*)alloc((size_t)NTN * 256 * 2);
    u16* xs1  = (u16*)alloc((size_t)NCN * 256 * 2);
    u16* xin0 = (u16*)alloc((size_t)NTN * 64 * 2);
    u16* xin1 = (u16*)alloc((size_t)NCN * 64 * 2);
    u16* qkv0 = (u16*)alloc((size_t)NTN * 768 * 2);   // 92.2 MB
    u16* qkv1 = (u16*)alloc((size_t)NCN * 768 * 2);   // 46.1 MB
    u16* agg0 = (u16*)alloc((size_t)NTN * 256 * 2);
    u16* agg1 = (u16*)alloc((size_t)NCN * 256 * 2);
    u16* WinT = (u16*)alloc((size_t)2 * 16384 * 2);
    u16* WqkvT= (u16*)alloc((size_t)4 * 196608 * 2);  // [768][256] per lt
    u16* WaT  = (u16*)alloc((size_t)4 * 65536 * 2);
    u16* WoutT= (u16*)alloc((size_t)16384 * 2);
    float* Wf2 = (float*)alloc((size_t)4 * 131072 * 4); // [lt][kf|vf] f32 staging
    float* bqkv = (float*)alloc((size_t)4 * 768 * 4);
    unsigned* countsT   = (unsigned*)alloc((size_t)NTN * 4);
    unsigned* prefT     = (unsigned*)alloc((size_t)NTN * 4);
    unsigned* cursorT   = (unsigned*)alloc((size_t)NTN * 4);
    u64* rowinfoT       = (u64*)alloc((size_t)NTN * 8);
    unsigned* srcAT     = (unsigned*)alloc((size_t)NED * 4);
    unsigned* countsC   = (unsigned*)alloc((size_t)NCN * 4);
    unsigned* prefC     = (unsigned*)alloc((size_t)NCN * 4);
    unsigned* cursorC   = (unsigned*)alloc((size_t)NCN * 4);
    u64* rowinfoC       = (u64*)alloc((size_t)NCN * 8);
    unsigned* srcAC     = (unsigned*)alloc((size_t)NED * 4);
    unsigned* bsum      = (unsigned*)alloc((size_t)256 * 4);
    (void)ws_size; (void)in_sizes; (void)n_in; (void)out_size;

    // ---------- CSR builds (shared by both layers) ----------
    {
        const int EB = (NED + 255) / 256;
        int NBt = (NTN + 255) / 256;
        fill_u32<<<256, 256, 0, stream>>>(countsT, 0u, NTN);
        hist_kernel<<<EB, 256, 0, stream>>>(dst_c2t, countsT, NED);
        scan_blocks<<<NBt, 256, 0, stream>>>(countsT, prefT, bsum, NTN);
        scan_top<<<1, 256, 0, stream>>>(bsum, NBt);
        scan_add<<<NBt, 256, 0, stream>>>(prefT, bsum, countsT, cursorT, rowinfoT, NTN);
        place_kernel<<<EB, 256, 0, stream>>>(dst_c2t, src_c2t, cursorT, srcAT, NED);
        int NBc = (NCN + 255) / 256;
        fill_u32<<<256, 256, 0, stream>>>(countsC, 0u, NCN);
        hist_kernel<<<EB, 256, 0, stream>>>(dst_t2c, countsC, NED);
        scan_blocks<<<NBc, 256, 0, stream>>>(countsC, prefC, bsum, NCN);
        scan_top<<<1, 256, 0, stream>>>(bsum, NBc);
        scan_add<<<NBc, 256, 0, stream>>>(prefC, bsum, countsC, cursorC, rowinfoC, NCN);
        place_kernel<<<EB, 256, 0, stream>>>(dst_t2c, src_t2c, cursorC, srcAC, NED);
    }

    // ---------- weight prep: fused + batched transposes ----------
    fuse_weights<<<dim3(256, 4), 256, 0, stream>>>(Wk, bk, Wv, bv, a_rel, m_rel, p_rel, Wf2, bqkv);
    copy_bq<<<4, 256, 0, stream>>>(bq, bqkv);
    // WqkvT[lt] rows: [0,256)=Wq^T, [256,512)=Wkf^T, [512,768)=Wvf^T
    convTb<<<(4 * 16384 + 255) / 256, 256, 0, stream>>>(Wq, WqkvT, 256, 256, 65536, 196608, 4);
    convTb<<<(4 * 16384 + 255) / 256, 256, 0, stream>>>(Wf2, WqkvT + 65536, 256, 256, 131072, 196608, 4);
    convTb<<<(4 * 16384 + 255) / 256, 256, 0, stream>>>(Wf2 + 65536, WqkvT + 131072, 256, 256, 131072, 196608, 4);
    convTb<<<(4 * 16384 + 255) / 256, 256, 0, stream>>>(Wa, WaT, 256, 256, 65536, 65536, 4);
    convTb<<<(2 * 4096 + 255) / 256, 256, 0, stream>>>(W_in, WinT, 64, 256, 16384, 16384, 2);
    convTb<<<(4096 + 255) / 256, 256, 0, stream>>>(W_out, WoutT, 256, 64, 16384, 16384, 1);
    f32_to_bf16<<<1024, 256, 0, stream>>>(x_trans, xin0, NTN * 64 / 4);
    f32_to_bf16<<<1024, 256, 0, stream>>>(x_cc,    xin1, NCN * 64 / 4);

    const int GT = (NTN + 63) / 64, GC = (NCN + 63) / 64;   // 938 / 469

    // ---------- input projections + relu (pair-merged) ----------
    gemm_mfma2<1, 64, true><<<GT * 4 + GC * 4, 256, 0, stream>>>(
        GT * 4,
        xin0, WinT, b_in, xs0, NTN, 256, 4, nullptr, nullptr,
        xin1, WinT + 16384, b_in + 256, xs1, NCN, 256, 4, nullptr, nullptr,
        64);

    for (int l = 0; l < 2; ++l) {
        size_t lt0 = (size_t)(l * 2 + 0), lt1 = (size_t)(l * 2 + 1);

        // fused q|k|v projections, both node types in one launch
        gemm_mfma2<0, 64, true><<<GT * 12 + GC * 12, 256, 0, stream>>>(
            GT * 12,
            xs0, WqkvT + lt0 * 196608, bqkv + lt0 * 768, qkv0, NTN, 768, 12, nullptr, nullptr,
            xs1, WqkvT + lt1 * 196608, bqkv + lt1 * 768, qkv1, NCN, 768, 12, nullptr, nullptr,
            256);

        // both edge phases in one launch
        edge_gather2<<<TBLK + (NCN + 3) / 4, 256, 0, stream>>>(
            qkv0, qkv1,
            rowinfoT, srcAT,
            rowinfoC, srcAC,
            agg0, agg1);

        // skip-blend output transforms, both node types in one launch
        gemm_mfma2<2, 64, true><<<GT * 4 + GC * 4, 256, 0, stream>>>(
            GT * 4,
            agg0, WaT + lt0 * 65536, ba + lt0 * 256, xs0, NTN, 256, 4, xs0, skip + l * 2 + 0,
            agg1, WaT + lt1 * 65536, ba + lt1 * 256, xs1, NCN, 256, 4, xs1, skip + l * 2 + 1,
            256);
    }

    // ---------- final projection + leakyrelu + row L2 normalize ----------
    {
        float* y = (float*)d_out;
        gemm_mfma2<3, 64, false><<<GT, 256, 0, stream>>>(
            GT,
            xs0, WoutT, b_out, y, NTN, 64, 1, nullptr, nullptr,
            xs0, WoutT, b_out, y, NTN, 64, 1, nullptr, nullptr,
            256);
        norm_rows<<<NTN / 4, 256, 0, stream>>>(y, NTN);
    }
}

// Round 11
// 469.230 us; speedup vs baseline: 9.2292x; 1.0266x over previous
//
#include <hip/hip_runtime.h>
#include <hip/hip_bf16.h>
#include <math.h>

#define NTN 60000
#define NCN 30000
#define NED 200000
// H=8, D=32, HID=256, FIN=64

typedef unsigned short u16;
typedef unsigned long long u64;
typedef __attribute__((ext_vector_type(8))) u16 u16x8;
typedef __attribute__((ext_vector_type(8))) __bf16 bf16x8;
typedef __attribute__((ext_vector_type(4))) float f32x4;

static __device__ __forceinline__ float bf2f(u16 u) {
    return __uint_as_float(((unsigned)u) << 16);
}
static __device__ __forceinline__ u16 f2bf(float f) {
    unsigned u = __float_as_uint(f);
    unsigned r = (u + 0x7fffu + ((u >> 16) & 1u)) >> 16;  // RNE
    return (u16)r;
}

// ------------------------- fill -------------------------
__global__ void fill2(unsigned* __restrict__ a, int na, unsigned* __restrict__ b, int nb) {
    int i = blockIdx.x * blockDim.x + threadIdx.x;
    int st = gridDim.x * blockDim.x;
    for (int k = i; k < na; k += st) a[k] = 0u;
    for (int k = i; k < nb; k += st) b[k] = 0u;
}

// ------------------------- conversions -------------------------
__global__ void f32_to_bf16(const float* __restrict__ in, u16* __restrict__ out, int n4) {
    int i = blockIdx.x * blockDim.x + threadIdx.x;
    int stride = gridDim.x * blockDim.x;
    for (; i < n4; i += stride) {
        float4 v = ((const float4*)in)[i];
        ushort4 o;
        o.x = f2bf(v.x); o.y = f2bf(v.y); o.z = f2bf(v.z); o.w = f2bf(v.w);
        ((ushort4*)out)[i] = o;
    }
}

// batched: out[m][n][k] = bf16(in[m][k][n]) with per-matrix strides.
__global__ void convTb(const float* __restrict__ in, u16* __restrict__ out,
                       int K, int N, int inStride, int outStride, int nm) {
    int idx = blockIdx.x * blockDim.x + threadIdx.x;
    int per = N * (K >> 2);
    int total = per * nm;
    if (idx >= total) return;
    int mat = idx / per, rem = idx - mat * per;
    int k4 = rem / N, n = rem - k4 * N;
    int k = k4 * 4;
    const float* src = in + (size_t)mat * inStride;
    u16* dst = out + (size_t)mat * outStride;
    ushort4 o;
    o.x = f2bf(src[(size_t)(k + 0) * N + n]);
    o.y = f2bf(src[(size_t)(k + 1) * N + n]);
    o.z = f2bf(src[(size_t)(k + 2) * N + n]);
    o.w = f2bf(src[(size_t)(k + 3) * N + n]);
    *(ushort4*)(dst + (size_t)n * K + k) = o;
}

__global__ void copy_bq(const float* __restrict__ bq, float* __restrict__ bqkv) {
    int lt = blockIdx.x;
    bqkv[lt * 768 + threadIdx.x] = bq[lt * 256 + threadIdx.x];
}

// --------------------- weight fusion (all 4 lt in one launch) ---------------------
__global__ __launch_bounds__(256) void fuse_weights(
    const float* __restrict__ Wk, const float* __restrict__ bk,
    const float* __restrict__ Wv, const float* __restrict__ bv,
    const float* __restrict__ a_rel, const float* __restrict__ m_rel,
    const float* __restrict__ p_rel,
    float* __restrict__ Wf2, float* __restrict__ bqkv)
{
    __shared__ float kw[256], vw[256];
    const int c = blockIdx.x, lt = blockIdx.y, tid = threadIdx.x;
    const int l = lt >> 1, t = lt & 1;
    const int lr = l * 2 + (t == 1 ? 0 : 1);     // relation where type t is the SOURCE
    const float* WkP = Wk + (size_t)lt * 65536;
    const float* WvP = Wv + (size_t)lt * 65536;
    const float* ar = a_rel + (size_t)lr * 8192;
    const float* mr = m_rel + (size_t)lr * 8192;
    kw[tid] = WkP[c * 256 + tid];
    vw[tid] = WvP[c * 256 + tid];
    __syncthreads();
    const int h = tid >> 5, e = tid & 31;
    const float s = p_rel[lr * 8 + h] * 0.17677669529663687f;  // 1/sqrt(32)
    float ak = 0.f, av = 0.f;
#pragma unroll 8
    for (int d = 0; d < 32; ++d) {
        ak += kw[h * 32 + d] * ar[h * 1024 + d * 32 + e];
        av += vw[h * 32 + d] * mr[h * 1024 + d * 32 + e];
    }
    float* WkfP = Wf2 + (size_t)lt * 131072;
    WkfP[c * 256 + tid] = ak * s;
    WkfP[65536 + c * 256 + tid] = av;
    if (c == 0) {
        const float* bkP = bk + (size_t)lt * 256;
        const float* bvP = bv + (size_t)lt * 256;
        float bka = 0.f, bva = 0.f;
#pragma unroll 8
        for (int d = 0; d < 32; ++d) {
            bka += bkP[h * 32 + d] * ar[h * 1024 + d * 32 + e];
            bva += bvP[h * 32 + d] * mr[h * 1024 + d * 32 + e];
        }
        bqkv[lt * 768 + 256 + tid] = bka * s;
        bqkv[lt * 768 + 512 + tid] = bva;
    }
}

// ------------------------- MFMA GEMM (pair-merged) -------------------------
// Two back-to-back GEMMs in one grid: blocks [0,nblk0) run set 0, rest set 1.
// Per set: C[M, NY*BN] = epi(A[M,K](bf16) @ WT^T(bf16) + bias).
// 64 x BN tile, BK=64, 4 waves, double-buffered LDS, counted vmcnt; 32KB LDS.
template <int EPI, int BN, bool OBF>
__global__ __launch_bounds__(256) void gemm_mfma2(
    int nblk0,
    const u16* __restrict__ A0, const u16* __restrict__ W0, const float* __restrict__ b0,
    void* __restrict__ C0, int M0, int ldC0, int NY0,
    const u16* __restrict__ xr0, const float* __restrict__ sk0,
    const u16* __restrict__ A1, const u16* __restrict__ W1, const float* __restrict__ b1,
    void* __restrict__ C1, int M1, int ldC1, int NY1,
    const u16* __restrict__ xr1, const float* __restrict__ sk1,
    int K)
{
    constexpr int ASZ = 64 * 64;
    constexpr int BSZ = BN * 64;
    constexpr int NF = BN / 32;
    __shared__ u16 smem[2 * (ASZ + BSZ)];
    u16* As0 = smem;             u16* Bs0 = smem + ASZ;
    u16* As1 = smem + ASZ + BSZ; u16* Bs1 = As1 + ASZ;

    // bijective XCD swizzle (m204) over the merged grid
    const int nwg = gridDim.x;
    const int bid = blockIdx.x;
    const int q8 = nwg >> 3, r8 = nwg & 7;
    const int xcd = bid & 7, pos = bid >> 3;
    const int lbid = (xcd < r8) ? xcd * (q8 + 1) + pos
                                : r8 * (q8 + 1) + (xcd - r8) * q8 + pos;

    const u16* A; const u16* WT; const float* bias; void* Cv;
    int M, ldC, NY, sb; const u16* xres; const float* skipPtr;
    if (lbid < nblk0) {
        A = A0; WT = W0; bias = b0; Cv = C0; M = M0; ldC = ldC0; NY = NY0;
        xres = xr0; skipPtr = sk0; sb = lbid;
    } else {
        A = A1; WT = W1; bias = b1; Cv = C1; M = M1; ldC = ldC1; NY = NY1;
        xres = xr1; skipPtr = sk1; sb = lbid - nblk0;
    }
    const int bx = sb / NY, by = sb - bx * NY;
    const int m0 = bx * 64, n0 = by * BN;

    const int tid = threadIdx.x;
    const int wave = tid >> 6, lane = tid & 63;
    const int wm = (wave >> 1) * 32, wn = (wave & 1) * (BN / 2);
    f32x4 acc[2][NF];
#pragma unroll
    for (int i = 0; i < 2; ++i)
#pragma unroll
        for (int j = 0; j < NF; ++j) acc[i][j] = (f32x4){0.f, 0.f, 0.f, 0.f};

    const int sr = lane >> 3;
    const int sl = lane & 7;

    auto stage = [&](int k0, u16* Ad, u16* Bd) {
#pragma unroll
        for (int i = 0; i < 2; ++i) {
            int rb = wave * 16 + i * 8;
            int r = rb + sr;
            int gr = m0 + r; gr = gr < M ? gr : M - 1;
            const u16* gp = A + (size_t)gr * K + k0 + ((sl ^ sr) << 3);
            __builtin_amdgcn_global_load_lds(
                (const __attribute__((address_space(1))) void*)gp,
                (__attribute__((address_space(3))) void*)(Ad + rb * 64), 16, 0, 0);
        }
#pragma unroll
        for (int i = 0; i < NF; ++i) {
            int rb = wave * (BN / 4) + i * 8;
            int r = rb + sr;
            const u16* gp = WT + (size_t)(n0 + r) * K + k0 + ((sl ^ sr) << 3);
            __builtin_amdgcn_global_load_lds(
                (const __attribute__((address_space(1))) void*)gp,
                (__attribute__((address_space(3))) void*)(Bd + rb * 64), 16, 0, 0);
        }
    };

    auto compute = [&](const u16* Ab, const u16* Bb) {
#pragma unroll
        for (int kx = 0; kx < 2; ++kx) {
            bf16x8 af[2], bfr[NF];
#pragma unroll
            for (int mf = 0; mf < 2; ++mf) {
                int r = wm + mf * 16 + (lane & 15);
                int slot = (lane >> 4) + kx * 4;
                af[mf] = __builtin_bit_cast(bf16x8,
                    *(const u16x8*)(Ab + r * 64 + ((slot ^ (r & 7)) << 3)));
            }
#pragma unroll
            for (int nf = 0; nf < NF; ++nf) {
                int r = wn + nf * 16 + (lane & 15);
                int slot = (lane >> 4) + kx * 4;
                bfr[nf] = __builtin_bit_cast(bf16x8,
                    *(const u16x8*)(Bb + r * 64 + ((slot ^ (r & 7)) << 3)));
            }
#pragma unroll
            for (int mf = 0; mf < 2; ++mf)
#pragma unroll
                for (int nf = 0; nf < NF; ++nf)
                    acc[mf][nf] = __builtin_amdgcn_mfma_f32_16x16x32_bf16(
                        af[mf], bfr[nf], acc[mf][nf], 0, 0, 0);
        }
    };

    const int nt = K >> 6;
    stage(0, As0, Bs0);
    for (int t = 0; t < nt; ++t) {
        const bool pb = t & 1;
        if (t + 1 < nt) {
            stage((t + 1) << 6, pb ? As0 : As1, pb ? Bs0 : Bs1);
            __builtin_amdgcn_sched_barrier(0);
            if constexpr (BN == 128) asm volatile("s_waitcnt vmcnt(6)" ::: "memory");
            else                     asm volatile("s_waitcnt vmcnt(4)" ::: "memory");
        } else {
            asm volatile("s_waitcnt vmcnt(0)" ::: "memory");
        }
        __builtin_amdgcn_s_barrier();
        __builtin_amdgcn_sched_barrier(0);
        compute(pb ? As1 : As0, pb ? Bs1 : Bs0);
        __builtin_amdgcn_sched_barrier(0);
        __builtin_amdgcn_s_barrier();
        __builtin_amdgcn_sched_barrier(0);   // fence: next stage must not hoist above
    }

    float beta = 0.f;
    if (EPI == 2) beta = 1.f / (1.f + expf(-skipPtr[0]));

    if constexpr (OBF) {
        constexpr int CLD = BN + 8;
        u16* Ct = smem;
#pragma unroll
        for (int nf = 0; nf < NF; ++nf) {
            int col = wn + nf * 16 + (lane & 15);
            int gcol = n0 + col;
            float bs = bias[gcol];
#pragma unroll
            for (int mf = 0; mf < 2; ++mf) {
#pragma unroll
                for (int j = 0; j < 4; ++j) {
                    int row = wm + mf * 16 + (lane >> 4) * 4 + j;
                    int grow = m0 + row;
                    int gr2 = grow < M ? grow : 0;
                    float c = acc[mf][nf][j] + bs;
                    if (EPI == 1) c = fmaxf(c, 0.f);
                    if (EPI == 2) c = beta * c + (1.f - beta) * bf2f(xres[(size_t)gr2 * ldC + gcol]);
                    if (EPI == 3) c = (c > 0.f) ? c : 0.2f * c;
                    Ct[row * CLD + col] = f2bf(c);
                }
            }
        }
        __syncthreads();   // full lgkm drain + fence: cross-wave LDS handoff
        int row = tid >> 2, c0 = (tid & 3) * (BN / 4);
        int grow = m0 + row;
        if (grow < M) {
            u16* dst = (u16*)Cv + (size_t)grow * ldC + n0 + c0;
            const u16* src = Ct + row * CLD + c0;
#pragma unroll
            for (int i = 0; i < BN / 32; ++i)
                *(u16x8*)(dst + i * 8) = *(const u16x8*)(src + i * 8);
        }
    } else {
#pragma unroll
        for (int nf = 0; nf < NF; ++nf) {
            int gcol = n0 + wn + nf * 16 + (lane & 15);
            float bs = bias[gcol];
#pragma unroll
            for (int mf = 0; mf < 2; ++mf) {
#pragma unroll
                for (int j = 0; j < 4; ++j) {
                    int grow = m0 + wm + mf * 16 + (lane >> 4) * 4 + j;
                    if (grow >= M) continue;
                    float c = acc[mf][nf][j] + bs;
                    if (EPI == 1) c = fmaxf(c, 0.f);
                    if (EPI == 3) c = (c > 0.f) ? c : 0.2f * c;
                    ((float*)Cv)[(size_t)grow * ldC + gcol] = c;
                }
            }
        }
    }
}

// ------------------------- CSR build (both relations per launch) -------------------------
__global__ void hist2(const int* __restrict__ d0, unsigned* __restrict__ c0,
                      const int* __restrict__ d1, unsigned* __restrict__ c1, int E) {
    int e = blockIdx.x * blockDim.x + threadIdx.x;
    if (e < E) {
        atomicAdd(&c0[d0[e]], 1u);
        atomicAdd(&c1[d1[e]], 1u);
    }
}

__global__ __launch_bounds__(256) void scan_blocks2(
    const unsigned* __restrict__ c0, unsigned* __restrict__ p0, unsigned* __restrict__ bs0, int N0,
    const unsigned* __restrict__ c1, unsigned* __restrict__ p1, unsigned* __restrict__ bs1, int N1)
{
    const unsigned* counts = blockIdx.y ? c1 : c0;
    unsigned* pref = blockIdx.y ? p1 : p0;
    unsigned* bsum = blockIdx.y ? bs1 : bs0;
    int N = blockIdx.y ? N1 : N0;
    if ((int)blockIdx.x * 256 >= N) return;   // block-uniform early-out
    __shared__ unsigned tmp[256];
    int i = blockIdx.x * 256 + threadIdx.x;
    unsigned v = (i < N) ? counts[i] : 0u;
    tmp[threadIdx.x] = v;
    __syncthreads();
    for (int off = 1; off < 256; off <<= 1) {
        unsigned t = (threadIdx.x >= off) ? tmp[threadIdx.x - off] : 0u;
        __syncthreads();
        tmp[threadIdx.x] += t;
        __syncthreads();
    }
    if (i < N) pref[i] = tmp[threadIdx.x] - v;  // exclusive
    if (threadIdx.x == 255) bsum[blockIdx.x] = tmp[255];
}

__global__ __launch_bounds__(256) void scan_top2(
    unsigned* __restrict__ bs0, int NB0, unsigned* __restrict__ bs1, int NB1)
{
    unsigned* bsum = blockIdx.x ? bs1 : bs0;
    int NB = blockIdx.x ? NB1 : NB0;
    __shared__ unsigned tmp[256];
    unsigned v = ((int)threadIdx.x < NB) ? bsum[threadIdx.x] : 0u;
    tmp[threadIdx.x] = v;
    __syncthreads();
    for (int off = 1; off < 256; off <<= 1) {
        unsigned t = (threadIdx.x >= off) ? tmp[threadIdx.x - off] : 0u;
        __syncthreads();
        tmp[threadIdx.x] += t;
        __syncthreads();
    }
    if ((int)threadIdx.x < NB) bsum[threadIdx.x] = tmp[threadIdx.x] - v;  // exclusive
}

// packs rowstart|deg into one u64 per node (single load in edge kernel)
__global__ void scan_add2(
    const unsigned* __restrict__ p0, const unsigned* __restrict__ bs0,
    const unsigned* __restrict__ c0, unsigned* __restrict__ cur0, u64* __restrict__ ri0, int N0,
    const unsigned* __restrict__ p1, const unsigned* __restrict__ bs1,
    const unsigned* __restrict__ c1, unsigned* __restrict__ cur1, u64* __restrict__ ri1, int N1)
{
    const unsigned* pref = blockIdx.y ? p1 : p0;
    const unsigned* bsum = blockIdx.y ? bs1 : bs0;
    const unsigned* counts = blockIdx.y ? c1 : c0;
    unsigned* cursor = blockIdx.y ? cur1 : cur0;
    u64* rowinfo = blockIdx.y ? ri1 : ri0;
    int N = blockIdx.y ? N1 : N0;
    int i = blockIdx.x * 256 + threadIdx.x;
    if (i < N) {
        unsigned s = pref[i] + bsum[blockIdx.x];
        cursor[i] = s;
        rowinfo[i] = (u64)s | ((u64)counts[i] << 32);
    }
}

// stores PRE-MULTIPLIED row offset (src*768, u16 units).
__global__ void place2(const int* __restrict__ d0, const int* __restrict__ s0,
                       unsigned* __restrict__ cur0, unsigned* __restrict__ o0,
                       const int* __restrict__ d1, const int* __restrict__ s1,
                       unsigned* __restrict__ cur1, unsigned* __restrict__ o1, int E) {
    int e = blockIdx.x * blockDim.x + threadIdx.x;
    if (e < E) {
        unsigned p = atomicAdd(&cur0[d0[e]], 1u);
        o0[p] = (unsigned)s0[e] * 768u;
        unsigned q = atomicAdd(&cur1[d1[e]], 1u);
        o1[q] = (unsigned)s1[e] * 768u;
    }
}

// ------------------------- fused edge gather (2 nodes per wave) -------------------------
// Each 32-lane HALF owns ONE dst node (32 lanes x 16B = full 256-wide row):
// no cross-half merge, and q-prep/softmax-finish/gelu/store serve 2 nodes per
// wave instruction. Per edge: K row load, 8-FMA dot + 2 quad shfl_xor (stays
// within the half), V row load, online softmax w/ defer-max ballot fast path.
// GeLU: branchless tanh-form via __expf (~1e-3 max err, within threshold).
#define TBLK8 ((NTN + 7) / 8)
__global__ __launch_bounds__(256) void edge_gather2(
    const u16* __restrict__ qkvT, const u16* __restrict__ qkvC,
    const u64* __restrict__ riT, const unsigned* __restrict__ srcT,
    const u64* __restrict__ riC, const unsigned* __restrict__ srcC,
    u16* __restrict__ aggT, u16* __restrict__ aggC)
{
    const int b = blockIdx.x;
    const bool isT = b < TBLK8;
    const int lane = threadIdx.x & 63;
    const int lq = lane & 31;
    // 8 nodes per block: wave w handles nodes {base+2w, base+2w+1}, half h -> +h
    const int n = (((isT ? b : b - TBLK8) << 2) + (int)(threadIdx.x >> 6)) * 2 + (lane >> 5);

    const u16* qkv_d = isT ? qkvT : qkvC;
    const u16* qkv_s = isT ? qkvC : qkvT;
    const u64* ri = isT ? riT : riC;
    const unsigned* srcarr = isT ? srcT : srcC;
    u16* agg = isT ? aggT : aggC;

    const u64 rinfo = ri[n];
    const unsigned start = (unsigned)rinfo;
    const unsigned deg = (unsigned)(rinfo >> 32);
    u16* outp = &agg[(size_t)n * 256 + lq * 8];

    if (deg == 0) {
        *(u16x8*)outp = (u16x8){0, 0, 0, 0, 0, 0, 0, 0};
        return;
    }

    u16x8 qv = *(const u16x8*)&qkv_d[(size_t)n * 768 + lq * 8];
    float qf[8];
#pragma unroll
    for (int i = 0; i < 8; ++i) qf[i] = bf2f(qv[i]);

    const u16* kvb = qkv_s + 256 + lq * 8;   // k section base (lane folded); v at +256
    float m = -INFINITY, s = 0.f;
    float acc[8] = {0.f, 0.f, 0.f, 0.f, 0.f, 0.f, 0.f, 0.f};

    unsigned off = srcarr[start];
    u16x8 kr = *(const u16x8*)(kvb + off);
    u16x8 vr = *(const u16x8*)(kvb + off + 256);
    for (unsigned j = 0;;) {
        const bool more = (j + 1 < deg);
        u16x8 kr_n, vr_n;
        if (more) {
            unsigned off2 = srcarr[start + j + 1];
            kr_n = *(const u16x8*)(kvb + off2);
            vr_n = *(const u16x8*)(kvb + off2 + 256);
        }
        float kf[8];
#pragma unroll
        for (int i = 0; i < 8; ++i) kf[i] = bf2f(kr[i]);
        float p = qf[0] * kf[0] + qf[1] * kf[1] + qf[2] * kf[2] + qf[3] * kf[3]
                + qf[4] * kf[4] + qf[5] * kf[5] + qf[6] * kf[6] + qf[7] * kf[7];
        p += __shfl_xor(p, 1);
        p += __shfl_xor(p, 2);          // quad = the 4 lanes of this head (within half)
        float vf[8];
#pragma unroll
        for (int i = 0; i < 8; ++i) vf[i] = bf2f(vr[i]);
        if (__ballot(p > m) == 0ull) {
            // fast path: no lane's max grew anywhere in the wave — no rescale
            float wv = __expf(p - m);
            s += wv;
#pragma unroll
            for (int i = 0; i < 8; ++i) acc[i] += wv * vf[i];
        } else {
            float mn = fmaxf(m, p);
            float sc = __expf(m - mn);  // 0 on first iteration (m = -inf)
            float wv = __expf(p - mn);
            s = s * sc + wv;
#pragma unroll
            for (int i = 0; i < 8; ++i) acc[i] = acc[i] * sc + wv * vf[i];
            m = mn;
        }
        if (!more) break;
        kr = kr_n; vr = vr_n; ++j;
    }

    float inv = 1.f / (s + 1e-16f);
    u16x8 ov;
#pragma unroll
    for (int i = 0; i < 8; ++i) {
        float x = acc[i] * inv;
        // gelu(x) ~= 0.5x(1+tanh(0.79788456(x+0.044715x^3))), tanh via expf
        float y2 = 1.5957691216f * x + 0.0713548163f * x * x * x;  // 2*y
        float e = __expf(y2);
        float t = 1.f - 2.f / (e + 1.f);
        ov[i] = f2bf(0.5f * x * (1.f + t));
    }
    *(u16x8*)outp = ov;
}

// ------------------------- misc -------------------------
__global__ __launch_bounds__(256) void norm_rows(float* __restrict__ y, int M) {
    int row = blockIdx.x * 4 + (threadIdx.x >> 6);
    int lane = threadIdx.x & 63;
    if (row >= M) return;
    float v = y[(size_t)row * 64 + lane];
    float s = v * v;
#pragma unroll
    for (int off = 1; off < 64; off <<= 1) s += __shfl_xor(s, off);
    float n = sqrtf(s);
    y[(size_t)row * 64 + lane] = v / fmaxf(n, 1e-12f);
}

// ------------------------- launch -------------------------
extern "C" void kernel_launch(void* const* d_in, const int* in_sizes, int n_in,
                              void* d_out, int out_size, void* d_ws, size_t ws_size,
                              hipStream_t stream)
{
    const float* x_trans = (const float*)d_in[0];
    const float* x_cc    = (const float*)d_in[1];
    const int* src_c2t   = (const int*)d_in[2];
    const int* dst_c2t   = (const int*)d_in[3];
    const int* src_t2c   = (const int*)d_in[4];
    const int* dst_t2c   = (const int*)d_in[5];
    const float* W_in = (const float*)d_in[6];
    const float* b_in = (const float*)d_in[7];
    const float* Wk   = (const float*)d_in[8];
    const float* bk   = (const float*)d_in[9];
    const float* Wq   = (const float*)d_in[10];
    const float* bq   = (const float*)d_in[11];
    const float* Wv   = (const float*)d_in[12];
    const float* bv   = (const float*)d_in[13];
    const float* Wa   = (const float*)d_in[14];
    const float* ba   = (const float*)d_in[15];
    const float* a_rel = (const float*)d_in[16];
    const float* m_rel = (const float*)d_in[17];
    const float* p_rel = (const float*)d_in[18];
    const float* skip  = (const float*)d_in[19];
    const float* W_out = (const float*)d_in[20];
    const float* b_out = (const float*)d_in[21];

    // ---------- workspace layout (~251 MB) ----------
    char* w = (char*)d_ws;
    auto alloc = [&](size_t bytes) { char* p = w; w += (bytes + 255) & ~(size_t)255; return p; };
    u16* xs0  = (u16*)alloc((size_t)NTN * 256 * 2);
    u16* xs1  = (u16*)alloc((size_t)NCN * 256 * 2);
    u16* xin0 = (u16*)alloc((size_t)NTN * 64 * 2);
    u16* xin1 = (u16*)alloc((size_t)NCN * 64 * 2);
    u16* qkv0 = (u16*)alloc((size_t)NTN * 768 * 2);   // 92.2 MB
    u16* qkv1 = (u16*)alloc((size_t)NCN * 768 * 2);   // 46.1 MB
    u16* agg0 = (u16*)alloc((size_t)NTN * 256 * 2);
    u16* agg1 = (u16*)alloc((size_t)NCN * 256 * 2);
    u16* WinT = (u16*)alloc((size_t)2 * 16384 * 2);
    u16* WqkvT= (u16*)alloc((size_t)4 * 196608 * 2);  // [768][256] per lt
    u16* WaT  = (u16*)alloc((size_t)4 * 65536 * 2);
    u16* WoutT= (u16*)alloc((size_t)16384 * 2);
    float* Wf2 = (float*)alloc((size_t)4 * 131072 * 4); // [lt][kf|vf] f32 staging
    float* bqkv = (float*)alloc((size_t)4 * 768 * 4);
    unsigned* countsT   = (unsigned*)alloc((size_t)NTN * 4);
    unsigned* prefT     = (unsigned*)alloc((size_t)NTN * 4);
    unsigned* cursorT   = (unsigned*)alloc((size_t)NTN * 4);
    u64* rowinfoT       = (u64*)alloc((size_t)NTN * 8);
    unsigned* srcAT     = (unsigned*)alloc((size_t)NED * 4);
    unsigned* countsC   = (unsigned*)alloc((size_t)NCN * 4);
    unsigned* prefC     = (unsigned*)alloc((size_t)NCN * 4);
    unsigned* cursorC   = (unsigned*)alloc((size_t)NCN * 4);
    u64* rowinfoC       = (u64*)alloc((size_t)NCN * 8);
    unsigned* srcAC     = (unsigned*)alloc((size_t)NED * 4);
    unsigned* bsum      = (unsigned*)alloc((size_t)2 * 256 * 4);
    (void)ws_size; (void)in_sizes; (void)n_in; (void)out_size;

    // ---------- CSR builds (both relations per launch; shared by both layers) ----------
    {
        const int EB = (NED + 255) / 256;
        const int NBt = (NTN + 255) / 256, NBc = (NCN + 255) / 256;
        fill2<<<256, 256, 0, stream>>>(countsT, NTN, countsC, NCN);
        hist2<<<EB, 256, 0, stream>>>(dst_c2t, countsT, dst_t2c, countsC, NED);
        scan_blocks2<<<dim3(NBt, 2), 256, 0, stream>>>(countsT, prefT, bsum, NTN,
                                                       countsC, prefC, bsum + 256, NCN);
        scan_top2<<<2, 256, 0, stream>>>(bsum, NBt, bsum + 256, NBc);
        scan_add2<<<dim3(NBt, 2), 256, 0, stream>>>(
            prefT, bsum, countsT, cursorT, rowinfoT, NTN,
            prefC, bsum + 256, countsC, cursorC, rowinfoC, NCN);
        place2<<<EB, 256, 0, stream>>>(dst_c2t, src_c2t, cursorT, srcAT,
                                       dst_t2c, src_t2c, cursorC, srcAC, NED);
    }

    // ---------- weight prep: fused + batched transposes ----------
    fuse_weights<<<dim3(256, 4), 256, 0, stream>>>(Wk, bk, Wv, bv, a_rel, m_rel, p_rel, Wf2, bqkv);
    copy_bq<<<4, 256, 0, stream>>>(bq, bqkv);
    // WqkvT[lt] rows: [0,256)=Wq^T, [256,512)=Wkf^T, [512,768)=Wvf^T
    convTb<<<(4 * 16384 + 255) / 256, 256, 0, stream>>>(Wq, WqkvT, 256, 256, 65536, 196608, 4);
    convTb<<<(4 * 16384 + 255) / 256, 256, 0, stream>>>(Wf2, WqkvT + 65536, 256, 256, 131072, 196608, 4);
    convTb<<<(4 * 16384 + 255) / 256, 256, 0, stream>>>(Wf2 + 65536, WqkvT + 131072, 256, 256, 131072, 196608, 4);
    convTb<<<(4 * 16384 + 255) / 256, 256, 0, stream>>>(Wa, WaT, 256, 256, 65536, 65536, 4);
    convTb<<<(2 * 4096 + 255) / 256, 256, 0, stream>>>(W_in, WinT, 64, 256, 16384, 16384, 2);
    convTb<<<(4096 + 255) / 256, 256, 0, stream>>>(W_out, WoutT, 256, 64, 16384, 16384, 1);
    f32_to_bf16<<<1024, 256, 0, stream>>>(x_trans, xin0, NTN * 64 / 4);
    f32_to_bf16<<<1024, 256, 0, stream>>>(x_cc,    xin1, NCN * 64 / 4);

    const int GT = (NTN + 63) / 64, GC = (NCN + 63) / 64;   // 938 / 469

    // ---------- input projections + relu (pair-merged) ----------
    gemm_mfma2<1, 64, true><<<GT * 4 + GC * 4, 256, 0, stream>>>(
        GT * 4,
        xin0, WinT, b_in, xs0, NTN, 256, 4, nullptr, nullptr,
        xin1, WinT + 16384, b_in + 256, xs1, NCN, 256, 4, nullptr, nullptr,
        64);

    for (int l = 0; l < 2; ++l) {
        size_t lt0 = (size_t)(l * 2 + 0), lt1 = (size_t)(l * 2 + 1);

        // fused q|k|v projections, both node types in one launch
        gemm_mfma2<0, 64, true><<<GT * 12 + GC * 12, 256, 0, stream>>>(
            GT * 12,
            xs0, WqkvT + lt0 * 196608, bqkv + lt0 * 768, qkv0, NTN, 768, 12, nullptr, nullptr,
            xs1, WqkvT + lt1 * 196608, bqkv + lt1 * 768, qkv1, NCN, 768, 12, nullptr, nullptr,
            256);

        // both edge phases in one launch, 2 nodes per wave
        edge_gather2<<<TBLK8 + (NCN + 7) / 8, 256, 0, stream>>>(
            qkv0, qkv1,
            rowinfoT, srcAT,
            rowinfoC, srcAC,
            agg0, agg1);

        // skip-blend output transforms, both node types in one launch
        gemm_mfma2<2, 64, true><<<GT * 4 + GC * 4, 256, 0, stream>>>(
            GT * 4,
            agg0, WaT + lt0 * 65536, ba + lt0 * 256, xs0, NTN, 256, 4, xs0, skip + l * 2 + 0,
            agg1, WaT + lt1 * 65536, ba + lt1 * 256, xs1, NCN, 256, 4, xs1, skip + l * 2 + 1,
            256);
    }

    // ---------- final projection + leakyrelu + row L2 normalize ----------
    {
        float* y = (float*)d_out;
        gemm_mfma2<3, 64, false><<<GT, 256, 0, stream>>>(
            GT,
            xs0, WoutT, b_out, y, NTN, 64, 1, nullptr, nullptr,
            xs0, WoutT, b_out, y, NTN, 64, 1, nullptr, nullptr,
            256);
        norm_rows<<<NTN / 4, 256, 0, stream>>>(y, NTN);
    }
}